// Round 1
// baseline (3229.284 us; speedup 1.0000x reference)
//
#include <hip/hip_runtime.h>
#include <hip/hip_bf16.h>

// Problem constants
#define BB 4
#define TT 1024
#define DD 1024
#define HH 16
#define KK 64
#define VV 64
#define WIN 256
#define MARKER_ID 50251

// ---------------------------------------------------------------------------
// RMSNorm: xn = x / sqrt(mean(x^2)+eps) * norm_w. One block per row (1024).
// ---------------------------------------------------------------------------
__global__ __launch_bounds__(256) void rmsnorm_kernel(
    const float* __restrict__ x, const float* __restrict__ nw,
    float* __restrict__ xn) {
  int row = blockIdx.x;
  int tid = threadIdx.x;
  const float4* xr = (const float4*)(x + (size_t)row * DD);
  float4 v = xr[tid];
  float ss = v.x * v.x + v.y * v.y + v.z * v.z + v.w * v.w;
#pragma unroll
  for (int off = 32; off; off >>= 1) ss += __shfl_xor(ss, off);
  __shared__ float red[4];
  int wid = tid >> 6;
  if ((tid & 63) == 0) red[wid] = ss;
  __syncthreads();
  float tot = red[0] + red[1] + red[2] + red[3];
  float inv = 1.0f / sqrtf(tot * (1.0f / DD) + 1e-6f);
  const float4* wr = (const float4*)nw;
  float4 wv = wr[tid];
  float4 o;
  o.x = v.x * inv * wv.x;
  o.y = v.y * inv * wv.y;
  o.z = v.z * inv * wv.z;
  o.w = v.w * inv * wv.w;
  ((float4*)(xn + (size_t)row * DD))[tid] = o;
}

// ---------------------------------------------------------------------------
// fp32 tiled GEMM: C[m][n] = add[m][n] + scale*rowscale[m]*sum_k A[m][k]B[k][n]
// 64x64 tile, BK=16, 256 threads, 4x4 per thread.
// ---------------------------------------------------------------------------
__global__ __launch_bounds__(256) void gemm64_kernel(
    const float* __restrict__ A, const float* __restrict__ Bw,
    float* __restrict__ C, const float* __restrict__ addp,
    const float* __restrict__ rowscale, float scale, int M, int N, int Kd) {
  __shared__ float As[16][68];
  __shared__ float Bs[16][68];
  int tid = threadIdx.x;
  int tx = tid & 15, ty = tid >> 4;
  int nb = blockIdx.x, mb = blockIdx.y;
  float acc[4][4];
#pragma unroll
  for (int i = 0; i < 4; ++i)
#pragma unroll
    for (int j = 0; j < 4; ++j) acc[i][j] = 0.f;

  for (int kt = 0; kt < Kd; kt += 16) {
#pragma unroll
    for (int p = 0; p < 4; ++p) {
      int r = (tid >> 4) + p * 16;  // row in tile 0..63
      As[tid & 15][r] = A[(size_t)(mb * 64 + r) * Kd + kt + (tid & 15)];
    }
#pragma unroll
    for (int p = 0; p < 4; ++p) {
      int r = (tid >> 6) + p * 4;  // row in tile 0..15
      Bs[r][tid & 63] = Bw[(size_t)(kt + r) * N + nb * 64 + (tid & 63)];
    }
    __syncthreads();
#pragma unroll
    for (int k = 0; k < 16; ++k) {
      float4 av = *(const float4*)&As[k][ty * 4];
      float4 bv = *(const float4*)&Bs[k][tx * 4];
      acc[0][0] = fmaf(av.x, bv.x, acc[0][0]);
      acc[0][1] = fmaf(av.x, bv.y, acc[0][1]);
      acc[0][2] = fmaf(av.x, bv.z, acc[0][2]);
      acc[0][3] = fmaf(av.x, bv.w, acc[0][3]);
      acc[1][0] = fmaf(av.y, bv.x, acc[1][0]);
      acc[1][1] = fmaf(av.y, bv.y, acc[1][1]);
      acc[1][2] = fmaf(av.y, bv.z, acc[1][2]);
      acc[1][3] = fmaf(av.y, bv.w, acc[1][3]);
      acc[2][0] = fmaf(av.z, bv.x, acc[2][0]);
      acc[2][1] = fmaf(av.z, bv.y, acc[2][1]);
      acc[2][2] = fmaf(av.z, bv.z, acc[2][2]);
      acc[2][3] = fmaf(av.z, bv.w, acc[2][3]);
      acc[3][0] = fmaf(av.w, bv.x, acc[3][0]);
      acc[3][1] = fmaf(av.w, bv.y, acc[3][1]);
      acc[3][2] = fmaf(av.w, bv.z, acc[3][2]);
      acc[3][3] = fmaf(av.w, bv.w, acc[3][3]);
    }
    __syncthreads();
  }
  int rowb = mb * 64 + ty * 4;
  int colb = nb * 64 + tx * 4;
#pragma unroll
  for (int i = 0; i < 4; ++i) {
    size_t m = rowb + i;
    float rs = scale * (rowscale ? rowscale[m] : 1.f);
    size_t idx = m * (size_t)N + colb;
    float4 base = addp ? *(const float4*)&addp[idx] : make_float4(0.f, 0.f, 0.f, 0.f);
    float4 res;
    res.x = base.x + rs * acc[i][0];
    res.y = base.y + rs * acc[i][1];
    res.z = base.z + rs * acc[i][2];
    res.w = base.w + rs * acc[i][3];
    *(float4*)&C[idx] = res;
  }
}

// ---------------------------------------------------------------------------
// L2-normalize rows of 64 (k_shared). One wave per row, 4 waves per block.
// ---------------------------------------------------------------------------
__global__ __launch_bounds__(256) void knorm_kernel(float* __restrict__ ksh) {
  int w = blockIdx.x * 4 + (threadIdx.x >> 6);
  int lane = threadIdx.x & 63;
  float v = ksh[(size_t)w * 64 + lane];
  float ss = v * v;
#pragma unroll
  for (int off = 32; off; off >>= 1) ss += __shfl_xor(ss, off);
  float n = sqrtf(ss);
  n = fmaxf(n, 1e-12f);
  ksh[(size_t)w * 64 + lane] = v / n;
}

// ---------------------------------------------------------------------------
// Small projections: beta, g, gate (sigmoid + bias), beta marker mask,
// and mean over heads of gate. One block per (b,t) row.
// ---------------------------------------------------------------------------
__global__ __launch_bounds__(256) void smallproj_kernel(
    const float* __restrict__ xn, const float* __restrict__ Wb,
    const float* __restrict__ bb, const float* __restrict__ Wg,
    const float* __restrict__ bg, const float* __restrict__ Wgate,
    const float* __restrict__ bgate, const int* __restrict__ ids,
    float* __restrict__ beta, float* __restrict__ g, float* __restrict__ mg) {
  int row = blockIdx.x;
  int tid = threadIdx.x;
  __shared__ float xr[DD];
  __shared__ float gl[16];
  ((float4*)xr)[tid] = ((const float4*)(xn + (size_t)row * DD))[tid];
  __syncthreads();
  if (tid < 48) {
    int h = tid & 15;
    const float* W = (tid < 16) ? Wb : ((tid < 32) ? Wg : Wgate);
    float acc = 0.f;
    for (int d = 0; d < DD; ++d) acc = fmaf(xr[d], W[d * 16 + h], acc);
    if (tid < 16) {
      float s = 1.f / (1.f + __expf(-(acc + bb[h])));
      float mk = (ids[row] == MARKER_ID) ? 1.0f : 0.1f;
      beta[(size_t)row * 16 + h] = s * mk;
    } else if (tid < 32) {
      g[(size_t)row * 16 + h] = 1.f / (1.f + __expf(-(acc + bg[h])));
    } else {
      gl[h] = 1.f / (1.f + __expf(-(acc + bgate[h])));
    }
  }
  __syncthreads();
  if (tid == 0) {
    float s = 0.f;
#pragma unroll
    for (int h = 0; h < 16; ++h) s += gl[h];
    mg[row] = s * (1.f / 16.f);
  }
}

// ---------------------------------------------------------------------------
// Sliding-window attention. One wave per (b,h,i) query row. Layouts (B,T,D)
// with head h occupying cols h*64..h*64+63. Output into Lout (B,T,D).
// ---------------------------------------------------------------------------
__global__ __launch_bounds__(256) void attn_kernel(
    const float* __restrict__ Q, const float* __restrict__ KL,
    const float* __restrict__ VL, float* __restrict__ Lout) {
  __shared__ float sc[4][320];
  int widx = blockIdx.x * 4 + (threadIdx.x >> 6);  // (b*H+h)*T + i
  int lane = threadIdx.x & 63;
  int i = widx & (TT - 1);
  int bh = widx >> 10;
  int h = bh & 15;
  int b = bh >> 4;
  float qd = Q[((size_t)(b * TT + i)) * DD + h * 64 + lane];
  int jlo = i - WIN;
  if (jlo < 0) jlo = 0;
  int count = i - jlo + 1;  // <= 257
  float* mysc = sc[threadIdx.x >> 6];
  const float* klbase = KL + (size_t)b * TT * DD + h * 64 + lane;
  float m = -1e30f;
  for (int n = 0; n < count; ++n) {
    float kv = klbase[(size_t)(jlo + n) * DD];
    float s = qd * kv;
#pragma unroll
    for (int off = 32; off; off >>= 1) s += __shfl_xor(s, off);
    s *= 0.125f;  // K^-0.5
    if (lane == (n & 63)) mysc[n] = s;
    m = fmaxf(m, s);
  }
  float esum = 0.f;
#pragma unroll
  for (int c = 0; c < 5; ++c) {
    int idx = c * 64 + lane;
    if (idx < count) {
      float e = __expf(mysc[idx] - m);
      mysc[idx] = e;
      esum += e;
    }
  }
#pragma unroll
  for (int off = 32; off; off >>= 1) esum += __shfl_xor(esum, off);
  __syncthreads();
  float o = 0.f;
  const float* vlbase = VL + (size_t)b * TT * DD + h * 64 + lane;
  for (int n = 0; n < count; ++n) o = fmaf(mysc[n], vlbase[(size_t)(jlo + n) * DD], o);
  o /= esum;
  Lout[((size_t)(b * TT + i)) * DD + h * 64 + lane] = o;
}

// ---------------------------------------------------------------------------
// Gated delta scan. One wave per (b,h). S[64][64] distributed: lane=v holds
// column v across 64 registers. 1023 sequential steps.
// ---------------------------------------------------------------------------
__global__ __launch_bounds__(64, 1) void scan_kernel(
    const float* __restrict__ ksh, const float* __restrict__ vfull,
    const float* __restrict__ beta, const float* __restrict__ g,
    const float* __restrict__ S0, float* __restrict__ gdnin,
    float* __restrict__ Sf) {
  int bh = blockIdx.x;
  int b = bh >> 4, h = bh & 15;
  int lane = threadIdx.x;  // v index
  float S[64];
  const float* s0p = S0 + (size_t)bh * 64 * 64;
#pragma unroll
  for (int k = 0; k < 64; ++k) S[k] = s0p[k * 64 + lane];
  // zero gdn row t=0 for this (b,h)
  gdnin[((size_t)b * TT) * DD + h * 64 + lane] = 0.f;

  __shared__ float sk[64];
  // prefetch t=0
  float kv = ksh[(((size_t)b * TT + 0) * HH + h) * 64 + lane];
  float vv = vfull[(((size_t)b * TT + 1) * HH + h) * 64 + lane];
  float bt = beta[((size_t)b * TT + 0) * HH + h];
  float gt = g[((size_t)b * TT + 0) * HH + h];

  for (int t = 0; t < TT - 1; ++t) {
    __syncthreads();
    sk[lane] = kv;
    __syncthreads();
    float ka[64];
#pragma unroll
    for (int k = 0; k < 64; ++k) ka[k] = sk[k];
    // prefetch next step
    float kvn = 0.f, vvn = 0.f, btn = 0.f, gtn = 0.f;
    if (t < TT - 2) {
      kvn = ksh[(((size_t)b * TT + (t + 1)) * HH + h) * 64 + lane];
      vvn = vfull[(((size_t)b * TT + (t + 2)) * HH + h) * 64 + lane];
      btn = beta[((size_t)b * TT + (t + 1)) * HH + h];
      gtn = g[((size_t)b * TT + (t + 1)) * HH + h];
    }
    // dot = sum_k ka[k]*S[k]
    float d0 = 0.f, d1 = 0.f, d2 = 0.f, d3 = 0.f;
#pragma unroll
    for (int k = 0; k < 64; k += 4) {
      d0 = fmaf(ka[k + 0], S[k + 0], d0);
      d1 = fmaf(ka[k + 1], S[k + 1], d1);
      d2 = fmaf(ka[k + 2], S[k + 2], d2);
      d3 = fmaf(ka[k + 3], S[k + 3], d3);
    }
    float dot = (d0 + d1) + (d2 + d3);
    float err = vv - gt * dot;
    float c = bt * err;
    float o0 = 0.f, o1 = 0.f, o2 = 0.f, o3 = 0.f;
#pragma unroll
    for (int k = 0; k < 64; k += 4) {
      float t0 = fmaf(gt, S[k + 0], c * ka[k + 0]);
      float t1 = fmaf(gt, S[k + 1], c * ka[k + 1]);
      float t2 = fmaf(gt, S[k + 2], c * ka[k + 2]);
      float t3 = fmaf(gt, S[k + 3], c * ka[k + 3]);
      S[k + 0] = t0; S[k + 1] = t1; S[k + 2] = t2; S[k + 3] = t3;
      o0 = fmaf(ka[k + 0], t0, o0);
      o1 = fmaf(ka[k + 1], t1, o1);
      o2 = fmaf(ka[k + 2], t2, o2);
      o3 = fmaf(ka[k + 3], t3, o3);
    }
    float o = (o0 + o1) + (o2 + o3);
    gdnin[((size_t)b * TT + (t + 1)) * DD + h * 64 + lane] = o;
    kv = kvn; vv = vvn; bt = btn; gt = gtn;
  }
  float* sfp = Sf + (size_t)bh * 64 * 64;
#pragma unroll
  for (int k = 0; k < 64; ++k) sfp[k * 64 + lane] = S[k];
}

// ---------------------------------------------------------------------------
// retrieved[b,t,h,:] = k_shared[b,t,h,:] @ Sf[b,h,:,:]. One wave per (b,t,h).
// ---------------------------------------------------------------------------
__global__ __launch_bounds__(256) void retrieve_kernel(
    const float* __restrict__ ksh, const float* __restrict__ Sf,
    float* __restrict__ retr) {
  int w = blockIdx.x * 4 + (threadIdx.x >> 6);  // (b*T+t)*H + h
  int lane = threadIdx.x & 63;                  // v index
  float kl = ksh[(size_t)w * 64 + lane];
  int bt = w >> 4;
  int b = bt >> 10;
  int bh = b * 16 + (w & 15);
  const float* sfp = Sf + (size_t)bh * 64 * 64;
  float acc = 0.f;
#pragma unroll
  for (int k = 0; k < 64; ++k) {
    float kk = __shfl(kl, k);
    acc = fmaf(kk, sfp[k * 64 + lane], acc);
  }
  retr[(size_t)bt * DD + (w & 15) * 64 + lane] = acc;
}

// ---------------------------------------------------------------------------
extern "C" void kernel_launch(void* const* d_in, const int* in_sizes, int n_in,
                              void* d_out, int out_size, void* d_ws,
                              size_t ws_size, hipStream_t stream) {
  (void)in_sizes; (void)n_in; (void)out_size; (void)ws_size;
  const float* x       = (const float*)d_in[0];
  const float* S0      = (const float*)d_in[1];
  const float* W_k     = (const float*)d_in[2];
  const float* W_v     = (const float*)d_in[3];
  const float* W_gdn_o = (const float*)d_in[4];
  const float* W_beta  = (const float*)d_in[5];
  const float* b_beta  = (const float*)d_in[6];
  const float* W_g     = (const float*)d_in[7];
  const float* b_g     = (const float*)d_in[8];
  const float* W_lq    = (const float*)d_in[9];
  const float* W_lk    = (const float*)d_in[10];
  const float* W_lv    = (const float*)d_in[11];
  const float* W_swa_o = (const float*)d_in[12];
  const float* W_ret_o = (const float*)d_in[13];
  const float* W_gate  = (const float*)d_in[14];
  const float* b_gate  = (const float*)d_in[15];
  const float* norm_w  = (const float*)d_in[16];
  const int*   ids     = (const int*)d_in[17];
  float* out = (float*)d_out;

  char* ws = (char*)d_ws;
  size_t off = 0;
  auto alloc = [&](size_t nfloats) {
    float* p = (float*)(ws + off);
    off += nfloats * sizeof(float);
    return p;
  };
  const size_t BTD = (size_t)BB * TT * DD;  // 4M
  float* XN   = alloc(BTD);
  float* KSH  = alloc(BTD);
  float* VF   = alloc(BTD);
  float* Qb   = alloc(BTD);
  float* KLb  = alloc(BTD);
  float* VLb  = alloc(BTD);
  float* BETA = alloc((size_t)BB * TT * HH);
  float* Gg   = alloc((size_t)BB * TT * HH);
  float* MG   = alloc((size_t)BB * TT);
  float* SF   = alloc((size_t)BB * HH * KK * VV);
  float* LOCAL = XN;   // reuse after smallproj consumed XN
  float* GDN   = KLb;  // reuse after attention consumed KLb
  float* RETR  = Qb;   // reuse after attention consumed Qb

  const int M = BB * TT;  // 4096
  dim3 gemmGrid(DD / 64, M / 64);

  rmsnorm_kernel<<<M, 256, 0, stream>>>(x, norm_w, XN);

  gemm64_kernel<<<gemmGrid, 256, 0, stream>>>(XN, W_k, KSH, nullptr, nullptr, 1.f, M, DD, DD);
  gemm64_kernel<<<gemmGrid, 256, 0, stream>>>(XN, W_v, VF, nullptr, nullptr, 1.f, M, DD, DD);
  gemm64_kernel<<<gemmGrid, 256, 0, stream>>>(XN, W_lq, Qb, nullptr, nullptr, 1.f, M, DD, DD);
  gemm64_kernel<<<gemmGrid, 256, 0, stream>>>(XN, W_lk, KLb, nullptr, nullptr, 1.f, M, DD, DD);
  gemm64_kernel<<<gemmGrid, 256, 0, stream>>>(XN, W_lv, VLb, nullptr, nullptr, 1.f, M, DD, DD);

  knorm_kernel<<<(BB * TT * HH) / 4, 256, 0, stream>>>(KSH);
  smallproj_kernel<<<M, 256, 0, stream>>>(XN, W_beta, b_beta, W_g, b_g, W_gate,
                                          b_gate, ids, BETA, Gg, MG);

  attn_kernel<<<(BB * HH * TT) / 4, 256, 0, stream>>>(Qb, KLb, VLb, LOCAL);

  scan_kernel<<<BB * HH, 64, 0, stream>>>(KSH, VF, BETA, Gg, S0, GDN, SF);

  retrieve_kernel<<<(BB * TT * HH) / 4, 256, 0, stream>>>(KSH, SF, RETR);

  // out = x + GDN @ W_gdn_o
  gemm64_kernel<<<gemmGrid, 256, 0, stream>>>(GDN, W_gdn_o, out, x, nullptr, 1.f, M, DD, DD);
  // out += 0.3 * LOCAL @ W_swa_o
  gemm64_kernel<<<gemmGrid, 256, 0, stream>>>(LOCAL, W_swa_o, out, out, nullptr, 0.3f, M, DD, DD);
  // out += mg[m] * RETR @ W_ret_o
  gemm64_kernel<<<gemmGrid, 256, 0, stream>>>(RETR, W_ret_o, out, out, MG, 1.f, M, DD, DD);
}

// Round 2
// 2104.279 us; speedup vs baseline: 1.5346x; 1.5346x over previous
//
#include <hip/hip_runtime.h>
#include <hip/hip_bf16.h>

// Problem constants
#define BB 4
#define TT 1024
#define DD 1024
#define HH 16
#define KK 64
#define VV 64
#define WIN 256
#define MARKER_ID 50251

// ---------------------------------------------------------------------------
// RMSNorm: xn = x / sqrt(mean(x^2)+eps) * norm_w. One block per row (1024).
// ---------------------------------------------------------------------------
__global__ __launch_bounds__(256) void rmsnorm_kernel(
    const float* __restrict__ x, const float* __restrict__ nw,
    float* __restrict__ xn) {
  int row = blockIdx.x;
  int tid = threadIdx.x;
  const float4* xr = (const float4*)(x + (size_t)row * DD);
  float4 v = xr[tid];
  float ss = v.x * v.x + v.y * v.y + v.z * v.z + v.w * v.w;
#pragma unroll
  for (int off = 32; off; off >>= 1) ss += __shfl_xor(ss, off);
  __shared__ float red[4];
  int wid = tid >> 6;
  if ((tid & 63) == 0) red[wid] = ss;
  __syncthreads();
  float tot = red[0] + red[1] + red[2] + red[3];
  float inv = 1.0f / sqrtf(tot * (1.0f / DD) + 1e-6f);
  const float4* wr = (const float4*)nw;
  float4 wv = wr[tid];
  float4 o;
  o.x = v.x * inv * wv.x;
  o.y = v.y * inv * wv.y;
  o.z = v.z * inv * wv.z;
  o.w = v.w * inv * wv.w;
  ((float4*)(xn + (size_t)row * DD))[tid] = o;
}

// ---------------------------------------------------------------------------
// fp32 tiled GEMM: C[m][n] = add[m][n] + scale*rowscale[m]*sum_k A[m][k]B[k][n]
// 64x64 tile, BK=16, 256 threads, 4x4 per thread.
// ---------------------------------------------------------------------------
__global__ __launch_bounds__(256) void gemm64_kernel(
    const float* __restrict__ A, const float* __restrict__ Bw,
    float* __restrict__ C, const float* __restrict__ addp,
    const float* __restrict__ rowscale, float scale, int M, int N, int Kd) {
  __shared__ float As[16][68];
  __shared__ float Bs[16][68];
  int tid = threadIdx.x;
  int tx = tid & 15, ty = tid >> 4;
  int nb = blockIdx.x, mb = blockIdx.y;
  float acc[4][4];
#pragma unroll
  for (int i = 0; i < 4; ++i)
#pragma unroll
    for (int j = 0; j < 4; ++j) acc[i][j] = 0.f;

  for (int kt = 0; kt < Kd; kt += 16) {
#pragma unroll
    for (int p = 0; p < 4; ++p) {
      int r = (tid >> 4) + p * 16;  // row in tile 0..63
      As[tid & 15][r] = A[(size_t)(mb * 64 + r) * Kd + kt + (tid & 15)];
    }
#pragma unroll
    for (int p = 0; p < 4; ++p) {
      int r = (tid >> 6) + p * 4;  // row in tile 0..15
      Bs[r][tid & 63] = Bw[(size_t)(kt + r) * N + nb * 64 + (tid & 63)];
    }
    __syncthreads();
#pragma unroll
    for (int k = 0; k < 16; ++k) {
      float4 av = *(const float4*)&As[k][ty * 4];
      float4 bv = *(const float4*)&Bs[k][tx * 4];
      acc[0][0] = fmaf(av.x, bv.x, acc[0][0]);
      acc[0][1] = fmaf(av.x, bv.y, acc[0][1]);
      acc[0][2] = fmaf(av.x, bv.z, acc[0][2]);
      acc[0][3] = fmaf(av.x, bv.w, acc[0][3]);
      acc[1][0] = fmaf(av.y, bv.x, acc[1][0]);
      acc[1][1] = fmaf(av.y, bv.y, acc[1][1]);
      acc[1][2] = fmaf(av.y, bv.z, acc[1][2]);
      acc[1][3] = fmaf(av.y, bv.w, acc[1][3]);
      acc[2][0] = fmaf(av.z, bv.x, acc[2][0]);
      acc[2][1] = fmaf(av.z, bv.y, acc[2][1]);
      acc[2][2] = fmaf(av.z, bv.z, acc[2][2]);
      acc[2][3] = fmaf(av.z, bv.w, acc[2][3]);
      acc[3][0] = fmaf(av.w, bv.x, acc[3][0]);
      acc[3][1] = fmaf(av.w, bv.y, acc[3][1]);
      acc[3][2] = fmaf(av.w, bv.z, acc[3][2]);
      acc[3][3] = fmaf(av.w, bv.w, acc[3][3]);
    }
    __syncthreads();
  }
  int rowb = mb * 64 + ty * 4;
  int colb = nb * 64 + tx * 4;
#pragma unroll
  for (int i = 0; i < 4; ++i) {
    size_t m = rowb + i;
    float rs = scale * (rowscale ? rowscale[m] : 1.f);
    size_t idx = m * (size_t)N + colb;
    float4 base = addp ? *(const float4*)&addp[idx] : make_float4(0.f, 0.f, 0.f, 0.f);
    float4 res;
    res.x = base.x + rs * acc[i][0];
    res.y = base.y + rs * acc[i][1];
    res.z = base.z + rs * acc[i][2];
    res.w = base.w + rs * acc[i][3];
    *(float4*)&C[idx] = res;
  }
}

// ---------------------------------------------------------------------------
// L2-normalize rows of 64 (k_shared). One wave per row, 4 waves per block.
// ---------------------------------------------------------------------------
__global__ __launch_bounds__(256) void knorm_kernel(float* __restrict__ ksh) {
  int w = blockIdx.x * 4 + (threadIdx.x >> 6);
  int lane = threadIdx.x & 63;
  float v = ksh[(size_t)w * 64 + lane];
  float ss = v * v;
#pragma unroll
  for (int off = 32; off; off >>= 1) ss += __shfl_xor(ss, off);
  float n = sqrtf(ss);
  n = fmaxf(n, 1e-12f);
  ksh[(size_t)w * 64 + lane] = v / n;
}

// ---------------------------------------------------------------------------
// Small projections: beta, g, gate (sigmoid + bias), beta marker mask,
// and mean over heads of gate. One block per (b,t) row.
// ---------------------------------------------------------------------------
__global__ __launch_bounds__(256) void smallproj_kernel(
    const float* __restrict__ xn, const float* __restrict__ Wb,
    const float* __restrict__ bb, const float* __restrict__ Wg,
    const float* __restrict__ bg, const float* __restrict__ Wgate,
    const float* __restrict__ bgate, const int* __restrict__ ids,
    float* __restrict__ beta, float* __restrict__ g, float* __restrict__ mg) {
  int row = blockIdx.x;
  int tid = threadIdx.x;
  __shared__ float xr[DD];
  __shared__ float gl[16];
  ((float4*)xr)[tid] = ((const float4*)(xn + (size_t)row * DD))[tid];
  __syncthreads();
  if (tid < 48) {
    int h = tid & 15;
    const float* W = (tid < 16) ? Wb : ((tid < 32) ? Wg : Wgate);
    float acc = 0.f;
    for (int d = 0; d < DD; ++d) acc = fmaf(xr[d], W[d * 16 + h], acc);
    if (tid < 16) {
      float s = 1.f / (1.f + __expf(-(acc + bb[h])));
      float mk = (ids[row] == MARKER_ID) ? 1.0f : 0.1f;
      beta[(size_t)row * 16 + h] = s * mk;
    } else if (tid < 32) {
      g[(size_t)row * 16 + h] = 1.f / (1.f + __expf(-(acc + bg[h])));
    } else {
      gl[h] = 1.f / (1.f + __expf(-(acc + bgate[h])));
    }
  }
  __syncthreads();
  if (tid == 0) {
    float s = 0.f;
#pragma unroll
    for (int h = 0; h < 16; ++h) s += gl[h];
    mg[row] = s * (1.f / 16.f);
  }
}

// ---------------------------------------------------------------------------
// Tiled flash-style sliding-window attention.
// Grid: (T/64, B*H). Block: 256 threads. Each block: 64 queries x 64 dims.
// Iterates over up to 5 key tiles of 64 (window 257). Online softmax.
// Thread (tx,ty) owns score rows ty*4..+3 (queries), cols tx*4..+3.
// LDS: Qs/Ks transposed [d][i]; Ps [j][i]; Vs [j][vd]. Stride 68 keeps
// float4 alignment; 2-way bank aliasing is free on gfx950.
// ---------------------------------------------------------------------------
__global__ __launch_bounds__(256) void attn_tile_kernel(
    const float* __restrict__ Q, const float* __restrict__ KL,
    const float* __restrict__ VL, float* __restrict__ Lout) {
  __shared__ float Qs[64][68];
  __shared__ float Ks[64][68];
  __shared__ float Ps[64][68];
  __shared__ float Vs[64][68];
  int qb = blockIdx.x * 64;
  int bh = blockIdx.y;
  int h = bh & 15, b = bh >> 4;
  int tid = threadIdx.x;
  int tx = tid & 15, ty = tid >> 4;

  const float* Qg = Q + (size_t)b * TT * DD + h * 64;
  const float* Kg = KL + (size_t)b * TT * DD + h * 64;
  const float* Vg = VL + (size_t)b * TT * DD + h * 64;

  // Stage Q transposed: Qs[d][i] = Q[qb+i][d]
#pragma unroll
  for (int p = 0; p < 4; ++p) {
    int e = p * 1024 + tid * 4;
    int i = e >> 6, d = e & 63;
    float4 qv = *(const float4*)&Qg[(size_t)(qb + i) * DD + d];
    Qs[d + 0][i] = qv.x;
    Qs[d + 1][i] = qv.y;
    Qs[d + 2][i] = qv.z;
    Qs[d + 3][i] = qv.w;
  }

  float O[4][4];
  float m[4], l[4];
#pragma unroll
  for (int r = 0; r < 4; ++r) {
    m[r] = -1e30f;
    l[r] = 0.f;
#pragma unroll
    for (int c = 0; c < 4; ++c) O[r][c] = 0.f;
  }

  int kt_start = qb - (int)WIN;
  if (kt_start < 0) kt_start = 0;

  for (int kt = kt_start; kt <= qb; kt += 64) {
    __syncthreads();  // previous PV reads done before restaging
    // Stage K transposed + V normal
#pragma unroll
    for (int p = 0; p < 4; ++p) {
      int e = p * 1024 + tid * 4;
      int i = e >> 6, d = e & 63;
      float4 kv = *(const float4*)&Kg[(size_t)(kt + i) * DD + d];
      Ks[d + 0][i] = kv.x;
      Ks[d + 1][i] = kv.y;
      Ks[d + 2][i] = kv.z;
      Ks[d + 3][i] = kv.w;
      float4 vv = *(const float4*)&Vg[(size_t)(kt + i) * DD + d];
      *(float4*)&Vs[i][d] = vv;
    }
    __syncthreads();

    // S = Q K^T (4x4 per thread)
    float s[4][4];
#pragma unroll
    for (int r = 0; r < 4; ++r)
#pragma unroll
      for (int c = 0; c < 4; ++c) s[r][c] = 0.f;
#pragma unroll 4
    for (int d = 0; d < 64; ++d) {
      float4 qv = *(const float4*)&Qs[d][ty * 4];
      float4 kv = *(const float4*)&Ks[d][tx * 4];
      s[0][0] = fmaf(qv.x, kv.x, s[0][0]);
      s[0][1] = fmaf(qv.x, kv.y, s[0][1]);
      s[0][2] = fmaf(qv.x, kv.z, s[0][2]);
      s[0][3] = fmaf(qv.x, kv.w, s[0][3]);
      s[1][0] = fmaf(qv.y, kv.x, s[1][0]);
      s[1][1] = fmaf(qv.y, kv.y, s[1][1]);
      s[1][2] = fmaf(qv.y, kv.z, s[1][2]);
      s[1][3] = fmaf(qv.y, kv.w, s[1][3]);
      s[2][0] = fmaf(qv.z, kv.x, s[2][0]);
      s[2][1] = fmaf(qv.z, kv.y, s[2][1]);
      s[2][2] = fmaf(qv.z, kv.z, s[2][2]);
      s[2][3] = fmaf(qv.z, kv.w, s[2][3]);
      s[3][0] = fmaf(qv.w, kv.x, s[3][0]);
      s[3][1] = fmaf(qv.w, kv.y, s[3][1]);
      s[3][2] = fmaf(qv.w, kv.z, s[3][2]);
      s[3][3] = fmaf(qv.w, kv.w, s[3][3]);
    }
    bool oldest = (kt == qb - (int)WIN);
    bool newest = (kt == qb);
#pragma unroll
    for (int r = 0; r < 4; ++r) {
      int il = ty * 4 + r;
#pragma unroll
      for (int c = 0; c < 4; ++c) {
        int jl = tx * 4 + c;
        float v = s[r][c] * 0.125f;
        if (oldest && jl < il) v = -1e30f;
        if (newest && jl > il) v = -1e30f;
        s[r][c] = v;
      }
    }
    // online softmax update
#pragma unroll
    for (int r = 0; r < 4; ++r) {
      float rm = fmaxf(fmaxf(s[r][0], s[r][1]), fmaxf(s[r][2], s[r][3]));
#pragma unroll
      for (int off = 1; off < 16; off <<= 1) rm = fmaxf(rm, __shfl_xor(rm, off));
      float mn = fmaxf(m[r], rm);
      float alpha = __expf(m[r] - mn);
      m[r] = mn;
      float rs = 0.f;
#pragma unroll
      for (int c = 0; c < 4; ++c) {
        float p = __expf(s[r][c] - mn);
        s[r][c] = p;
        rs += p;
      }
#pragma unroll
      for (int off = 1; off < 16; off <<= 1) rs += __shfl_xor(rs, off);
      l[r] = l[r] * alpha + rs;
#pragma unroll
      for (int c = 0; c < 4; ++c) O[r][c] *= alpha;
    }
    // write P transposed: Ps[j][i]
#pragma unroll
    for (int r = 0; r < 4; ++r)
#pragma unroll
      for (int c = 0; c < 4; ++c) Ps[tx * 4 + c][ty * 4 + r] = s[r][c];
    __syncthreads();
    // O += P @ V
#pragma unroll 4
    for (int j = 0; j < 64; ++j) {
      float4 pv = *(const float4*)&Ps[j][ty * 4];
      float4 vv = *(const float4*)&Vs[j][tx * 4];
      O[0][0] = fmaf(pv.x, vv.x, O[0][0]);
      O[0][1] = fmaf(pv.x, vv.y, O[0][1]);
      O[0][2] = fmaf(pv.x, vv.z, O[0][2]);
      O[0][3] = fmaf(pv.x, vv.w, O[0][3]);
      O[1][0] = fmaf(pv.y, vv.x, O[1][0]);
      O[1][1] = fmaf(pv.y, vv.y, O[1][1]);
      O[1][2] = fmaf(pv.y, vv.z, O[1][2]);
      O[1][3] = fmaf(pv.y, vv.w, O[1][3]);
      O[2][0] = fmaf(pv.z, vv.x, O[2][0]);
      O[2][1] = fmaf(pv.z, vv.y, O[2][1]);
      O[2][2] = fmaf(pv.z, vv.z, O[2][2]);
      O[2][3] = fmaf(pv.z, vv.w, O[2][3]);
      O[3][0] = fmaf(pv.w, vv.x, O[3][0]);
      O[3][1] = fmaf(pv.w, vv.y, O[3][1]);
      O[3][2] = fmaf(pv.w, vv.z, O[3][2]);
      O[3][3] = fmaf(pv.w, vv.w, O[3][3]);
    }
  }
  // epilogue
#pragma unroll
  for (int r = 0; r < 4; ++r) {
    float inv = 1.f / l[r];
    float4 res;
    res.x = O[r][0] * inv;
    res.y = O[r][1] * inv;
    res.z = O[r][2] * inv;
    res.w = O[r][3] * inv;
    int i = qb + ty * 4 + r;
    *(float4*)&Lout[((size_t)(b * TT + i)) * DD + h * 64 + tx * 4] = res;
  }
}

// ---------------------------------------------------------------------------
// Gated delta scan. One wave per (b,h). S[64][64] distributed: lane=v holds
// column v across 64 registers. 1023 sequential steps.
// ---------------------------------------------------------------------------
__global__ __launch_bounds__(64, 1) void scan_kernel(
    const float* __restrict__ ksh, const float* __restrict__ vfull,
    const float* __restrict__ beta, const float* __restrict__ g,
    const float* __restrict__ S0, float* __restrict__ gdnin,
    float* __restrict__ Sf) {
  int bh = blockIdx.x;
  int b = bh >> 4, h = bh & 15;
  int lane = threadIdx.x;  // v index
  float S[64];
  const float* s0p = S0 + (size_t)bh * 64 * 64;
#pragma unroll
  for (int k = 0; k < 64; ++k) S[k] = s0p[k * 64 + lane];
  // zero gdn row t=0 for this (b,h)
  gdnin[((size_t)b * TT) * DD + h * 64 + lane] = 0.f;

  __shared__ float sk[64];
  // prefetch t=0
  float kv = ksh[(((size_t)b * TT + 0) * HH + h) * 64 + lane];
  float vv = vfull[(((size_t)b * TT + 1) * HH + h) * 64 + lane];
  float bt = beta[((size_t)b * TT + 0) * HH + h];
  float gt = g[((size_t)b * TT + 0) * HH + h];

  for (int t = 0; t < TT - 1; ++t) {
    __syncthreads();
    sk[lane] = kv;
    __syncthreads();
    float ka[64];
#pragma unroll
    for (int k = 0; k < 64; ++k) ka[k] = sk[k];
    // prefetch next step
    float kvn = 0.f, vvn = 0.f, btn = 0.f, gtn = 0.f;
    if (t < TT - 2) {
      kvn = ksh[(((size_t)b * TT + (t + 1)) * HH + h) * 64 + lane];
      vvn = vfull[(((size_t)b * TT + (t + 2)) * HH + h) * 64 + lane];
      btn = beta[((size_t)b * TT + (t + 1)) * HH + h];
      gtn = g[((size_t)b * TT + (t + 1)) * HH + h];
    }
    // dot = sum_k ka[k]*S[k]
    float d0 = 0.f, d1 = 0.f, d2 = 0.f, d3 = 0.f;
#pragma unroll
    for (int k = 0; k < 64; k += 4) {
      d0 = fmaf(ka[k + 0], S[k + 0], d0);
      d1 = fmaf(ka[k + 1], S[k + 1], d1);
      d2 = fmaf(ka[k + 2], S[k + 2], d2);
      d3 = fmaf(ka[k + 3], S[k + 3], d3);
    }
    float dot = (d0 + d1) + (d2 + d3);
    float err = vv - gt * dot;
    float c = bt * err;
    float o0 = 0.f, o1 = 0.f, o2 = 0.f, o3 = 0.f;
#pragma unroll
    for (int k = 0; k < 64; k += 4) {
      float t0 = fmaf(gt, S[k + 0], c * ka[k + 0]);
      float t1 = fmaf(gt, S[k + 1], c * ka[k + 1]);
      float t2 = fmaf(gt, S[k + 2], c * ka[k + 2]);
      float t3 = fmaf(gt, S[k + 3], c * ka[k + 3]);
      S[k + 0] = t0; S[k + 1] = t1; S[k + 2] = t2; S[k + 3] = t3;
      o0 = fmaf(ka[k + 0], t0, o0);
      o1 = fmaf(ka[k + 1], t1, o1);
      o2 = fmaf(ka[k + 2], t2, o2);
      o3 = fmaf(ka[k + 3], t3, o3);
    }
    float o = (o0 + o1) + (o2 + o3);
    gdnin[((size_t)b * TT + (t + 1)) * DD + h * 64 + lane] = o;
    kv = kvn; vv = vvn; bt = btn; gt = gtn;
  }
  float* sfp = Sf + (size_t)bh * 64 * 64;
#pragma unroll
  for (int k = 0; k < 64; ++k) sfp[k * 64 + lane] = S[k];
}

// ---------------------------------------------------------------------------
// retrieved[b,t,h,:] = k_shared[b,t,h,:] @ Sf[b,h,:,:]. One wave per (b,t,h).
// ---------------------------------------------------------------------------
__global__ __launch_bounds__(256) void retrieve_kernel(
    const float* __restrict__ ksh, const float* __restrict__ Sf,
    float* __restrict__ retr) {
  int w = blockIdx.x * 4 + (threadIdx.x >> 6);  // (b*T+t)*H + h
  int lane = threadIdx.x & 63;                  // v index
  float kl = ksh[(size_t)w * 64 + lane];
  int bt = w >> 4;
  int b = bt >> 10;
  int bh = b * 16 + (w & 15);
  const float* sfp = Sf + (size_t)bh * 64 * 64;
  float acc = 0.f;
#pragma unroll
  for (int k = 0; k < 64; ++k) {
    float kk = __shfl(kl, k);
    acc = fmaf(kk, sfp[k * 64 + lane], acc);
  }
  retr[(size_t)bt * DD + (w & 15) * 64 + lane] = acc;
}

// ---------------------------------------------------------------------------
extern "C" void kernel_launch(void* const* d_in, const int* in_sizes, int n_in,
                              void* d_out, int out_size, void* d_ws,
                              size_t ws_size, hipStream_t stream) {
  (void)in_sizes; (void)n_in; (void)out_size; (void)ws_size;
  const float* x       = (const float*)d_in[0];
  const float* S0      = (const float*)d_in[1];
  const float* W_k     = (const float*)d_in[2];
  const float* W_v     = (const float*)d_in[3];
  const float* W_gdn_o = (const float*)d_in[4];
  const float* W_beta  = (const float*)d_in[5];
  const float* b_beta  = (const float*)d_in[6];
  const float* W_g     = (const float*)d_in[7];
  const float* b_g     = (const float*)d_in[8];
  const float* W_lq    = (const float*)d_in[9];
  const float* W_lk    = (const float*)d_in[10];
  const float* W_lv    = (const float*)d_in[11];
  const float* W_swa_o = (const float*)d_in[12];
  const float* W_ret_o = (const float*)d_in[13];
  const float* W_gate  = (const float*)d_in[14];
  const float* b_gate  = (const float*)d_in[15];
  const float* norm_w  = (const float*)d_in[16];
  const int*   ids     = (const int*)d_in[17];
  float* out = (float*)d_out;

  char* ws = (char*)d_ws;
  size_t off = 0;
  auto alloc = [&](size_t nfloats) {
    float* p = (float*)(ws + off);
    off += nfloats * sizeof(float);
    return p;
  };
  const size_t BTD = (size_t)BB * TT * DD;  // 4M
  float* XN   = alloc(BTD);
  float* KSH  = alloc(BTD);
  float* VF   = alloc(BTD);
  float* Qb   = alloc(BTD);
  float* KLb  = alloc(BTD);
  float* VLb  = alloc(BTD);
  float* BETA = alloc((size_t)BB * TT * HH);
  float* Gg   = alloc((size_t)BB * TT * HH);
  float* MG   = alloc((size_t)BB * TT);
  float* SF   = alloc((size_t)BB * HH * KK * VV);
  float* LOCAL = XN;   // reuse after smallproj consumed XN
  float* GDN   = KLb;  // reuse after attention consumed KLb
  float* RETR  = Qb;   // reuse after attention consumed Qb

  const int M = BB * TT;  // 4096
  dim3 gemmGrid(DD / 64, M / 64);

  rmsnorm_kernel<<<M, 256, 0, stream>>>(x, norm_w, XN);

  gemm64_kernel<<<gemmGrid, 256, 0, stream>>>(XN, W_k, KSH, nullptr, nullptr, 1.f, M, DD, DD);
  gemm64_kernel<<<gemmGrid, 256, 0, stream>>>(XN, W_v, VF, nullptr, nullptr, 1.f, M, DD, DD);
  gemm64_kernel<<<gemmGrid, 256, 0, stream>>>(XN, W_lq, Qb, nullptr, nullptr, 1.f, M, DD, DD);
  gemm64_kernel<<<gemmGrid, 256, 0, stream>>>(XN, W_lk, KLb, nullptr, nullptr, 1.f, M, DD, DD);
  gemm64_kernel<<<gemmGrid, 256, 0, stream>>>(XN, W_lv, VLb, nullptr, nullptr, 1.f, M, DD, DD);

  knorm_kernel<<<(BB * TT * HH) / 4, 256, 0, stream>>>(KSH);
  smallproj_kernel<<<M, 256, 0, stream>>>(XN, W_beta, b_beta, W_g, b_g, W_gate,
                                          b_gate, ids, BETA, Gg, MG);

  attn_tile_kernel<<<dim3(TT / 64, BB * HH), 256, 0, stream>>>(Qb, KLb, VLb, LOCAL);

  scan_kernel<<<BB * HH, 64, 0, stream>>>(KSH, VF, BETA, Gg, S0, GDN, SF);

  retrieve_kernel<<<(BB * TT * HH) / 4, 256, 0, stream>>>(KSH, SF, RETR);

  // out = x + GDN @ W_gdn_o
  gemm64_kernel<<<gemmGrid, 256, 0, stream>>>(GDN, W_gdn_o, out, x, nullptr, 1.f, M, DD, DD);
  // out += 0.3 * LOCAL @ W_swa_o
  gemm64_kernel<<<gemmGrid, 256, 0, stream>>>(LOCAL, W_swa_o, out, out, nullptr, 0.3f, M, DD, DD);
  // out += mg[m] * RETR @ W_ret_o
  gemm64_kernel<<<gemmGrid, 256, 0, stream>>>(RETR, W_ret_o, out, out, MG, 1.f, M, DD, DD);
}

// Round 3
// 1487.529 us; speedup vs baseline: 2.1709x; 1.4146x over previous
//
#include <hip/hip_runtime.h>
#include <hip/hip_bf16.h>

// Problem constants
#define BB 4
#define TT 1024
#define DD 1024
#define HH 16
#define KK 64
#define VV 64
#define WIN 256
#define MARKER_ID 50251

typedef short bfrag8 __attribute__((ext_vector_type(8)));
typedef float f32x4 __attribute__((ext_vector_type(4)));

static __device__ __forceinline__ unsigned short f2bf(float f) {
  __hip_bfloat16 h = __float2bfloat16(f);
  union { __hip_bfloat16 h; unsigned short u; } cv;
  cv.h = h;
  return cv.u;
}
static __device__ __forceinline__ float bf2f(unsigned short u) {
  union { unsigned int i; float f; } c;
  c.i = ((unsigned int)u) << 16;
  return c.f;
}

// ---------------------------------------------------------------------------
// RMSNorm: xnb (bf16) = x / sqrt(mean(x^2)+eps) * norm_w. One block per row.
// ---------------------------------------------------------------------------
__global__ __launch_bounds__(256) void rmsnorm_kernel(
    const float* __restrict__ x, const float* __restrict__ nw,
    unsigned short* __restrict__ xnb) {
  int row = blockIdx.x;
  int tid = threadIdx.x;
  const float4* xr = (const float4*)(x + (size_t)row * DD);
  float4 v = xr[tid];
  float ss = v.x * v.x + v.y * v.y + v.z * v.z + v.w * v.w;
#pragma unroll
  for (int off = 32; off; off >>= 1) ss += __shfl_xor(ss, off);
  __shared__ float red[4];
  int wid = tid >> 6;
  if ((tid & 63) == 0) red[wid] = ss;
  __syncthreads();
  float tot = red[0] + red[1] + red[2] + red[3];
  float inv = 1.0f / sqrtf(tot * (1.0f / DD) + 1e-6f);
  const float4* wr = (const float4*)nw;
  float4 wv = wr[tid];
  ushort4 o;
  o.x = f2bf(v.x * inv * wv.x);
  o.y = f2bf(v.y * inv * wv.y);
  o.z = f2bf(v.z * inv * wv.z);
  o.w = f2bf(v.w * inv * wv.w);
  *(ushort4*)&xnb[(size_t)row * DD + tid * 4] = o;
}

// ---------------------------------------------------------------------------
// Convert + transpose 1024x1024 weights fp32 [K][N] -> bf16 [N][K].
// grid (16,16,8): z selects which weight.
// ---------------------------------------------------------------------------
__global__ __launch_bounds__(256) void convert_wt_kernel(
    const float* W0, const float* W1, const float* W2, const float* W3,
    const float* W4, const float* W5, const float* W6, const float* W7,
    unsigned short* T0, unsigned short* T1, unsigned short* T2,
    unsigned short* T3, unsigned short* T4, unsigned short* T5,
    unsigned short* T6, unsigned short* T7) {
  const float* W;
  unsigned short* T;
  switch (blockIdx.z) {
    case 0: W = W0; T = T0; break;
    case 1: W = W1; T = T1; break;
    case 2: W = W2; T = T2; break;
    case 3: W = W3; T = T3; break;
    case 4: W = W4; T = T4; break;
    case 5: W = W5; T = T5; break;
    case 6: W = W6; T = T6; break;
    default: W = W7; T = T7; break;
  }
  __shared__ float Ts[64][68];
  int tid = threadIdx.x;
  int n0 = blockIdx.x * 64, k0 = blockIdx.y * 64;
#pragma unroll
  for (int p = 0; p < 4; ++p) {
    int e = p * 256 + tid;
    int k = e >> 4, nq = e & 15;
    float4 w = *(const float4*)&W[(size_t)(k0 + k) * 1024 + n0 + nq * 4];
    Ts[nq * 4 + 0][k] = w.x;
    Ts[nq * 4 + 1][k] = w.y;
    Ts[nq * 4 + 2][k] = w.z;
    Ts[nq * 4 + 3][k] = w.w;
  }
  __syncthreads();
#pragma unroll
  for (int p = 0; p < 4; ++p) {
    int e = p * 256 + tid;
    int n = e >> 4, kq = e & 15;
    float4 v = *(const float4*)&Ts[n][kq * 4];
    ushort4 u;
    u.x = f2bf(v.x);
    u.y = f2bf(v.y);
    u.z = f2bf(v.z);
    u.w = f2bf(v.w);
    *(ushort4*)&T[(size_t)(n0 + n) * 1024 + k0 + kq * 4] = u;
  }
}

// ---------------------------------------------------------------------------
// bf16 MFMA GEMM: C[m][n] = add[m][n] + scale*rowscale[m]*sum_k A[m][k]BT[n][k]
// A: [M][K] bf16, BT: [N][K] bf16 (pre-transposed weight), C fp32.
// 128x128 tile, BK=32, 256 threads = 4 waves (2x2 of 64x64), 16 MFMA/iter.
// LDS stride 40 ushorts (80B = 5*16B): frag ds_read_b128 lands 2-way banked.
// ---------------------------------------------------------------------------
__global__ __launch_bounds__(256) void gemm_mfma_kernel(
    const unsigned short* __restrict__ A, const unsigned short* __restrict__ BT,
    float* __restrict__ C, const float* __restrict__ addp,
    const float* __restrict__ rowscale, float scale, int M, int N, int K) {
  __shared__ unsigned short As[128][40];
  __shared__ unsigned short Bs[128][40];
  int tid = threadIdx.x;
  int n0 = blockIdx.x * 128, m0 = blockIdx.y * 128;
  int wave = tid >> 6, lane = tid & 63;
  int wm = (wave & 1) * 64, wn = (wave >> 1) * 64;
  int r16 = lane & 15, quad = lane >> 4;
  int srow = tid >> 2, scq = tid & 3;

  f32x4 acc[4][4];
#pragma unroll
  for (int i = 0; i < 4; ++i)
#pragma unroll
    for (int j = 0; j < 4; ++j) acc[i][j] = {0.f, 0.f, 0.f, 0.f};

  for (int kt = 0; kt < K; kt += 32) {
    uint4 a0 = *(const uint4*)&A[(size_t)(m0 + srow) * K + kt + scq * 8];
    uint4 a1 = *(const uint4*)&A[(size_t)(m0 + 64 + srow) * K + kt + scq * 8];
    uint4 b0 = *(const uint4*)&BT[(size_t)(n0 + srow) * K + kt + scq * 8];
    uint4 b1 = *(const uint4*)&BT[(size_t)(n0 + 64 + srow) * K + kt + scq * 8];
    __syncthreads();  // previous iter frag reads done
    *(uint4*)&As[srow][scq * 8] = a0;
    *(uint4*)&As[64 + srow][scq * 8] = a1;
    *(uint4*)&Bs[srow][scq * 8] = b0;
    *(uint4*)&Bs[64 + srow][scq * 8] = b1;
    __syncthreads();
    bfrag8 af[4], bq[4];
#pragma unroll
    for (int i = 0; i < 4; ++i) {
      af[i] = *(const bfrag8*)&As[wm + i * 16 + r16][quad * 8];
      bq[i] = *(const bfrag8*)&Bs[wn + i * 16 + r16][quad * 8];
    }
#pragma unroll
    for (int i = 0; i < 4; ++i)
#pragma unroll
      for (int j = 0; j < 4; ++j)
        acc[i][j] = __builtin_amdgcn_mfma_f32_16x16x32_bf16(af[i], bq[j],
                                                            acc[i][j], 0, 0, 0);
  }
  // epilogue: C/D layout col=lane&15, row=quad*4+reg
#pragma unroll
  for (int i = 0; i < 4; ++i) {
#pragma unroll
    for (int r = 0; r < 4; ++r) {
      int row = m0 + wm + i * 16 + quad * 4 + r;
      float rs = scale * (rowscale ? rowscale[row] : 1.f);
#pragma unroll
      for (int j = 0; j < 4; ++j) {
        int col = n0 + wn + j * 16 + r16;
        size_t idx = (size_t)row * N + col;
        float base = addp ? addp[idx] : 0.f;
        C[idx] = base + rs * acc[i][j][r];
      }
    }
  }
}

// ---------------------------------------------------------------------------
// L2-normalize rows of 64 (k_shared). One wave per row, 4 waves per block.
// ---------------------------------------------------------------------------
__global__ __launch_bounds__(256) void knorm_kernel(float* __restrict__ ksh) {
  int w = blockIdx.x * 4 + (threadIdx.x >> 6);
  int lane = threadIdx.x & 63;
  float v = ksh[(size_t)w * 64 + lane];
  float ss = v * v;
#pragma unroll
  for (int off = 32; off; off >>= 1) ss += __shfl_xor(ss, off);
  float n = sqrtf(ss);
  n = fmaxf(n, 1e-12f);
  ksh[(size_t)w * 64 + lane] = v / n;
}

// ---------------------------------------------------------------------------
// Small projections: beta, g, gate (sigmoid + bias), beta marker mask,
// and mean over heads of gate. One block per (b,t) row. bf16 xn input.
// ---------------------------------------------------------------------------
__global__ __launch_bounds__(256) void smallproj_kernel(
    const unsigned short* __restrict__ xnb, const float* __restrict__ Wb,
    const float* __restrict__ bb, const float* __restrict__ Wg,
    const float* __restrict__ bg, const float* __restrict__ Wgate,
    const float* __restrict__ bgate, const int* __restrict__ ids,
    float* __restrict__ beta, float* __restrict__ g, float* __restrict__ mg) {
  int row = blockIdx.x;
  int tid = threadIdx.x;
  __shared__ float xr[DD];
  __shared__ float gl[16];
  ushort4 u = *(const ushort4*)&xnb[(size_t)row * DD + tid * 4];
  xr[tid * 4 + 0] = bf2f(u.x);
  xr[tid * 4 + 1] = bf2f(u.y);
  xr[tid * 4 + 2] = bf2f(u.z);
  xr[tid * 4 + 3] = bf2f(u.w);
  __syncthreads();
  if (tid < 48) {
    int h = tid & 15;
    const float* W = (tid < 16) ? Wb : ((tid < 32) ? Wg : Wgate);
    float acc = 0.f;
    for (int d = 0; d < DD; ++d) acc = fmaf(xr[d], W[d * 16 + h], acc);
    if (tid < 16) {
      float s = 1.f / (1.f + __expf(-(acc + bb[h])));
      float mk = (ids[row] == MARKER_ID) ? 1.0f : 0.1f;
      beta[(size_t)row * 16 + h] = s * mk;
    } else if (tid < 32) {
      g[(size_t)row * 16 + h] = 1.f / (1.f + __expf(-(acc + bg[h])));
    } else {
      gl[h] = 1.f / (1.f + __expf(-(acc + bgate[h])));
    }
  }
  __syncthreads();
  if (tid == 0) {
    float s = 0.f;
#pragma unroll
    for (int h = 0; h < 16; ++h) s += gl[h];
    mg[row] = s * (1.f / 16.f);
  }
}

// ---------------------------------------------------------------------------
// Tiled flash-style sliding-window attention (fp32 in, bf16 out).
// ---------------------------------------------------------------------------
__global__ __launch_bounds__(256) void attn_tile_kernel(
    const float* __restrict__ Q, const float* __restrict__ KL,
    const float* __restrict__ VL, unsigned short* __restrict__ Loutb) {
  __shared__ float Qs[64][68];
  __shared__ float Ks[64][68];
  __shared__ float Ps[64][68];
  __shared__ float Vs[64][68];
  int qb = blockIdx.x * 64;
  int bh = blockIdx.y;
  int h = bh & 15, b = bh >> 4;
  int tid = threadIdx.x;
  int tx = tid & 15, ty = tid >> 4;

  const float* Qg = Q + (size_t)b * TT * DD + h * 64;
  const float* Kg = KL + (size_t)b * TT * DD + h * 64;
  const float* Vg = VL + (size_t)b * TT * DD + h * 64;

#pragma unroll
  for (int p = 0; p < 4; ++p) {
    int e = p * 1024 + tid * 4;
    int i = e >> 6, d = e & 63;
    float4 qv = *(const float4*)&Qg[(size_t)(qb + i) * DD + d];
    Qs[d + 0][i] = qv.x;
    Qs[d + 1][i] = qv.y;
    Qs[d + 2][i] = qv.z;
    Qs[d + 3][i] = qv.w;
  }

  float O[4][4];
  float m[4], l[4];
#pragma unroll
  for (int r = 0; r < 4; ++r) {
    m[r] = -1e30f;
    l[r] = 0.f;
#pragma unroll
    for (int c = 0; c < 4; ++c) O[r][c] = 0.f;
  }

  int kt_start = qb - (int)WIN;
  if (kt_start < 0) kt_start = 0;

  for (int kt = kt_start; kt <= qb; kt += 64) {
    __syncthreads();
#pragma unroll
    for (int p = 0; p < 4; ++p) {
      int e = p * 1024 + tid * 4;
      int i = e >> 6, d = e & 63;
      float4 kv = *(const float4*)&Kg[(size_t)(kt + i) * DD + d];
      Ks[d + 0][i] = kv.x;
      Ks[d + 1][i] = kv.y;
      Ks[d + 2][i] = kv.z;
      Ks[d + 3][i] = kv.w;
      float4 vv = *(const float4*)&Vg[(size_t)(kt + i) * DD + d];
      *(float4*)&Vs[i][d] = vv;
    }
    __syncthreads();

    float s[4][4];
#pragma unroll
    for (int r = 0; r < 4; ++r)
#pragma unroll
      for (int c = 0; c < 4; ++c) s[r][c] = 0.f;
#pragma unroll 4
    for (int d = 0; d < 64; ++d) {
      float4 qv = *(const float4*)&Qs[d][ty * 4];
      float4 kv = *(const float4*)&Ks[d][tx * 4];
      s[0][0] = fmaf(qv.x, kv.x, s[0][0]);
      s[0][1] = fmaf(qv.x, kv.y, s[0][1]);
      s[0][2] = fmaf(qv.x, kv.z, s[0][2]);
      s[0][3] = fmaf(qv.x, kv.w, s[0][3]);
      s[1][0] = fmaf(qv.y, kv.x, s[1][0]);
      s[1][1] = fmaf(qv.y, kv.y, s[1][1]);
      s[1][2] = fmaf(qv.y, kv.z, s[1][2]);
      s[1][3] = fmaf(qv.y, kv.w, s[1][3]);
      s[2][0] = fmaf(qv.z, kv.x, s[2][0]);
      s[2][1] = fmaf(qv.z, kv.y, s[2][1]);
      s[2][2] = fmaf(qv.z, kv.z, s[2][2]);
      s[2][3] = fmaf(qv.z, kv.w, s[2][3]);
      s[3][0] = fmaf(qv.w, kv.x, s[3][0]);
      s[3][1] = fmaf(qv.w, kv.y, s[3][1]);
      s[3][2] = fmaf(qv.w, kv.z, s[3][2]);
      s[3][3] = fmaf(qv.w, kv.w, s[3][3]);
    }
    bool oldest = (kt == qb - (int)WIN);
    bool newest = (kt == qb);
#pragma unroll
    for (int r = 0; r < 4; ++r) {
      int il = ty * 4 + r;
#pragma unroll
      for (int c = 0; c < 4; ++c) {
        int jl = tx * 4 + c;
        float v = s[r][c] * 0.125f;
        if (oldest && jl < il) v = -1e30f;
        if (newest && jl > il) v = -1e30f;
        s[r][c] = v;
      }
    }
#pragma unroll
    for (int r = 0; r < 4; ++r) {
      float rm = fmaxf(fmaxf(s[r][0], s[r][1]), fmaxf(s[r][2], s[r][3]));
#pragma unroll
      for (int off = 1; off < 16; off <<= 1) rm = fmaxf(rm, __shfl_xor(rm, off));
      float mn = fmaxf(m[r], rm);
      float alpha = __expf(m[r] - mn);
      m[r] = mn;
      float rs = 0.f;
#pragma unroll
      for (int c = 0; c < 4; ++c) {
        float p = __expf(s[r][c] - mn);
        s[r][c] = p;
        rs += p;
      }
#pragma unroll
      for (int off = 1; off < 16; off <<= 1) rs += __shfl_xor(rs, off);
      l[r] = l[r] * alpha + rs;
#pragma unroll
      for (int c = 0; c < 4; ++c) O[r][c] *= alpha;
    }
#pragma unroll
    for (int r = 0; r < 4; ++r)
#pragma unroll
      for (int c = 0; c < 4; ++c) Ps[tx * 4 + c][ty * 4 + r] = s[r][c];
    __syncthreads();
#pragma unroll 4
    for (int j = 0; j < 64; ++j) {
      float4 pv = *(const float4*)&Ps[j][ty * 4];
      float4 vv = *(const float4*)&Vs[j][tx * 4];
      O[0][0] = fmaf(pv.x, vv.x, O[0][0]);
      O[0][1] = fmaf(pv.x, vv.y, O[0][1]);
      O[0][2] = fmaf(pv.x, vv.z, O[0][2]);
      O[0][3] = fmaf(pv.x, vv.w, O[0][3]);
      O[1][0] = fmaf(pv.y, vv.x, O[1][0]);
      O[1][1] = fmaf(pv.y, vv.y, O[1][1]);
      O[1][2] = fmaf(pv.y, vv.z, O[1][2]);
      O[1][3] = fmaf(pv.y, vv.w, O[1][3]);
      O[2][0] = fmaf(pv.z, vv.x, O[2][0]);
      O[2][1] = fmaf(pv.z, vv.y, O[2][1]);
      O[2][2] = fmaf(pv.z, vv.z, O[2][2]);
      O[2][3] = fmaf(pv.z, vv.w, O[2][3]);
      O[3][0] = fmaf(pv.w, vv.x, O[3][0]);
      O[3][1] = fmaf(pv.w, vv.y, O[3][1]);
      O[3][2] = fmaf(pv.w, vv.z, O[3][2]);
      O[3][3] = fmaf(pv.w, vv.w, O[3][3]);
    }
  }
#pragma unroll
  for (int r = 0; r < 4; ++r) {
    float inv = 1.f / l[r];
    ushort4 res;
    res.x = f2bf(O[r][0] * inv);
    res.y = f2bf(O[r][1] * inv);
    res.z = f2bf(O[r][2] * inv);
    res.w = f2bf(O[r][3] * inv);
    int i = qb + ty * 4 + r;
    *(ushort4*)&Loutb[((size_t)(b * TT + i)) * DD + h * 64 + tx * 4] = res;
  }
}

// ---------------------------------------------------------------------------
// Gated delta scan. One wave per (b,h), lane = v column, S[64] over k in regs.
// k/v/beta/g staged into LDS 64 steps at a time (bulk coalesced); inner steps
// read k via 16x ds_read_b128 broadcast. bf16 output.
// ---------------------------------------------------------------------------
__global__ __launch_bounds__(64, 1) void scan_kernel(
    const float* __restrict__ ksh, const float* __restrict__ vfull,
    const float* __restrict__ beta, const float* __restrict__ g,
    const float* __restrict__ S0, unsigned short* __restrict__ gdnb,
    float* __restrict__ Sf) {
  int bh = blockIdx.x;
  int b = bh >> 4, h = bh & 15;
  int lane = threadIdx.x;  // v index
  float S[64];
  const float* s0p = S0 + (size_t)bh * 4096;
#pragma unroll
  for (int k = 0; k < 64; ++k) S[k] = s0p[k * 64 + lane];
  gdnb[((size_t)b * TT) * DD + h * 64 + lane] = f2bf(0.f);

  __shared__ float ck[64][64];
  __shared__ float cv[64][64];
  __shared__ float cb[64];
  __shared__ float cg[64];

  const float* kbase = ksh + (size_t)b * TT * 1024 + h * 64;
  const float* vbase = vfull + (size_t)b * TT * 1024 + h * 64;
  const float* bbase = beta + (size_t)b * TT * 16 + h;
  const float* gbase = g + (size_t)b * TT * 16 + h;

  int i0 = lane >> 4, dq = lane & 15;
  for (int c = 0; c < 16; ++c) {
    int tc = c * 64;
    int L = (c == 15) ? 63 : 64;
    __syncthreads();  // WAR vs previous chunk reads
#pragma unroll
    for (int p = 0; p < 16; ++p) {
      int i = p * 4 + i0;
      if (i < L) {
        *(float4*)&ck[i][dq * 4] =
            *(const float4*)&kbase[(size_t)(tc + i) * 1024 + dq * 4];
        *(float4*)&cv[i][dq * 4] =
            *(const float4*)&vbase[(size_t)(tc + i + 1) * 1024 + dq * 4];
      }
    }
    if (lane < L) {
      cb[lane] = bbase[(size_t)(tc + lane) * 16];
      cg[lane] = gbase[(size_t)(tc + lane) * 16];
    }
    __syncthreads();
    for (int i = 0; i < L; ++i) {
      float ka[64];
#pragma unroll
      for (int k4 = 0; k4 < 16; ++k4) {
        float4 kq = *(const float4*)&ck[i][k4 * 4];
        ka[k4 * 4 + 0] = kq.x;
        ka[k4 * 4 + 1] = kq.y;
        ka[k4 * 4 + 2] = kq.z;
        ka[k4 * 4 + 3] = kq.w;
      }
      float vv = cv[i][lane];
      float bt = cb[i];
      float gt = cg[i];
      float d0 = 0.f, d1 = 0.f, d2 = 0.f, d3 = 0.f;
#pragma unroll
      for (int k = 0; k < 64; k += 4) {
        d0 = fmaf(ka[k + 0], S[k + 0], d0);
        d1 = fmaf(ka[k + 1], S[k + 1], d1);
        d2 = fmaf(ka[k + 2], S[k + 2], d2);
        d3 = fmaf(ka[k + 3], S[k + 3], d3);
      }
      float dot = (d0 + d1) + (d2 + d3);
      float err = vv - gt * dot;
      float cc = bt * err;
      float o0 = 0.f, o1 = 0.f, o2 = 0.f, o3 = 0.f;
#pragma unroll
      for (int k = 0; k < 64; k += 4) {
        float t0 = fmaf(gt, S[k + 0], cc * ka[k + 0]);
        float t1 = fmaf(gt, S[k + 1], cc * ka[k + 1]);
        float t2 = fmaf(gt, S[k + 2], cc * ka[k + 2]);
        float t3 = fmaf(gt, S[k + 3], cc * ka[k + 3]);
        S[k + 0] = t0;
        S[k + 1] = t1;
        S[k + 2] = t2;
        S[k + 3] = t3;
        o0 = fmaf(ka[k + 0], t0, o0);
        o1 = fmaf(ka[k + 1], t1, o1);
        o2 = fmaf(ka[k + 2], t2, o2);
        o3 = fmaf(ka[k + 3], t3, o3);
      }
      float o = (o0 + o1) + (o2 + o3);
      gdnb[((size_t)b * TT + (tc + i + 1)) * DD + h * 64 + lane] = f2bf(o);
    }
  }
  float* sfp = Sf + (size_t)bh * 4096;
#pragma unroll
  for (int k = 0; k < 64; ++k) sfp[k * 64 + lane] = S[k];
}

// ---------------------------------------------------------------------------
// retrieved[b,t,h,:] = k_shared[b,t,h,:] @ Sf[b,h,:,:]. bf16 out.
// ---------------------------------------------------------------------------
__global__ __launch_bounds__(256) void retrieve_kernel(
    const float* __restrict__ ksh, const float* __restrict__ Sf,
    unsigned short* __restrict__ retrb) {
  int w = blockIdx.x * 4 + (threadIdx.x >> 6);  // (b*T+t)*H + h
  int lane = threadIdx.x & 63;                  // v index
  float kl = ksh[(size_t)w * 64 + lane];
  int bt = w >> 4;
  int b = bt >> 10;
  int bh = b * 16 + (w & 15);
  const float* sfp = Sf + (size_t)bh * 4096;
  float acc = 0.f;
#pragma unroll
  for (int k = 0; k < 64; ++k) {
    float kk = __shfl(kl, k);
    acc = fmaf(kk, sfp[k * 64 + lane], acc);
  }
  retrb[(size_t)bt * DD + (w & 15) * 64 + lane] = f2bf(acc);
}

// ---------------------------------------------------------------------------
extern "C" void kernel_launch(void* const* d_in, const int* in_sizes, int n_in,
                              void* d_out, int out_size, void* d_ws,
                              size_t ws_size, hipStream_t stream) {
  (void)in_sizes; (void)n_in; (void)out_size; (void)ws_size;
  const float* x       = (const float*)d_in[0];
  const float* S0      = (const float*)d_in[1];
  const float* W_k     = (const float*)d_in[2];
  const float* W_v     = (const float*)d_in[3];
  const float* W_gdn_o = (const float*)d_in[4];
  const float* W_beta  = (const float*)d_in[5];
  const float* b_beta  = (const float*)d_in[6];
  const float* W_g     = (const float*)d_in[7];
  const float* b_g     = (const float*)d_in[8];
  const float* W_lq    = (const float*)d_in[9];
  const float* W_lk    = (const float*)d_in[10];
  const float* W_lv    = (const float*)d_in[11];
  const float* W_swa_o = (const float*)d_in[12];
  const float* W_ret_o = (const float*)d_in[13];
  const float* W_gate  = (const float*)d_in[14];
  const float* b_gate  = (const float*)d_in[15];
  const float* norm_w  = (const float*)d_in[16];
  const int*   ids     = (const int*)d_in[17];
  float* out = (float*)d_out;

  char* ws = (char*)d_ws;
  size_t off = 0;
  auto allocf = [&](size_t nfloats) {
    float* p = (float*)(ws + off);
    off += nfloats * sizeof(float);
    return p;
  };
  auto allocu = [&](size_t nshorts) {
    unsigned short* p = (unsigned short*)(ws + off);
    off += nshorts * sizeof(unsigned short);
    return p;
  };
  const size_t BTD = (size_t)BB * TT * DD;  // 4M
  unsigned short* XNb = allocu(BTD);
  float* KSH  = allocf(BTD);
  float* VF   = allocf(BTD);
  float* Qb   = allocf(BTD);
  float* KLb  = allocf(BTD);
  float* VLb  = allocf(BTD);
  unsigned short* WTk   = allocu(1024 * 1024);
  unsigned short* WTv   = allocu(1024 * 1024);
  unsigned short* WTlq  = allocu(1024 * 1024);
  unsigned short* WTlk  = allocu(1024 * 1024);
  unsigned short* WTlv  = allocu(1024 * 1024);
  unsigned short* WTgdn = allocu(1024 * 1024);
  unsigned short* WTswa = allocu(1024 * 1024);
  unsigned short* WTret = allocu(1024 * 1024);
  float* BETA = allocf((size_t)BB * TT * HH);
  float* Gg   = allocf((size_t)BB * TT * HH);
  float* MG   = allocf((size_t)BB * TT);
  float* SF   = allocf((size_t)BB * HH * KK * VV);
  // Reuse (ordering guarantees no read-write overlap):
  unsigned short* GDNb   = XNb;                   // after smallproj+5 gemms
  unsigned short* LOCALb = (unsigned short*)VF;   // after scan consumed VF
  unsigned short* RETRb  = (unsigned short*)Qb;   // after attn consumed Qb

  const int M = BB * TT;  // 4096
  dim3 gemmGrid(DD / 128, M / 128);

  rmsnorm_kernel<<<M, 256, 0, stream>>>(x, norm_w, XNb);

  convert_wt_kernel<<<dim3(16, 16, 8), 256, 0, stream>>>(
      W_k, W_v, W_lq, W_lk, W_lv, W_gdn_o, W_swa_o, W_ret_o,
      WTk, WTv, WTlq, WTlk, WTlv, WTgdn, WTswa, WTret);

  gemm_mfma_kernel<<<gemmGrid, 256, 0, stream>>>(XNb, WTk, KSH, nullptr, nullptr, 1.f, M, DD, DD);
  gemm_mfma_kernel<<<gemmGrid, 256, 0, stream>>>(XNb, WTv, VF, nullptr, nullptr, 1.f, M, DD, DD);
  gemm_mfma_kernel<<<gemmGrid, 256, 0, stream>>>(XNb, WTlq, Qb, nullptr, nullptr, 1.f, M, DD, DD);
  gemm_mfma_kernel<<<gemmGrid, 256, 0, stream>>>(XNb, WTlk, KLb, nullptr, nullptr, 1.f, M, DD, DD);
  gemm_mfma_kernel<<<gemmGrid, 256, 0, stream>>>(XNb, WTlv, VLb, nullptr, nullptr, 1.f, M, DD, DD);

  knorm_kernel<<<(BB * TT * HH) / 4, 256, 0, stream>>>(KSH);
  smallproj_kernel<<<M, 256, 0, stream>>>(XNb, W_beta, b_beta, W_g, b_g, W_gate,
                                          b_gate, ids, BETA, Gg, MG);

  scan_kernel<<<BB * HH, 64, 0, stream>>>(KSH, VF, BETA, Gg, S0, GDNb, SF);

  attn_tile_kernel<<<dim3(TT / 64, BB * HH), 256, 0, stream>>>(Qb, KLb, VLb, LOCALb);

  retrieve_kernel<<<(BB * TT * HH) / 4, 256, 0, stream>>>(KSH, SF, RETRb);

  gemm_mfma_kernel<<<gemmGrid, 256, 0, stream>>>(GDNb, WTgdn, out, x, nullptr, 1.f, M, DD, DD);
  gemm_mfma_kernel<<<gemmGrid, 256, 0, stream>>>(LOCALb, WTswa, out, out, nullptr, 0.3f, M, DD, DD);
  gemm_mfma_kernel<<<gemmGrid, 256, 0, stream>>>(RETRb, WTret, out, out, MG, 1.f, M, DD, DD);
}

// Round 4
// 958.468 us; speedup vs baseline: 3.3692x; 1.5520x over previous
//
#include <hip/hip_runtime.h>
#include <hip/hip_bf16.h>

// Problem constants
#define BB 4
#define TT 1024
#define DD 1024
#define HH 16
#define KK 64
#define VV 64
#define WIN 256
#define MARKER_ID 50251

typedef short bfrag8 __attribute__((ext_vector_type(8)));
typedef float f32x4 __attribute__((ext_vector_type(4)));

static __device__ __forceinline__ unsigned short f2bf(float f) {
  __hip_bfloat16 h = __float2bfloat16(f);
  union { __hip_bfloat16 h; unsigned short u; } cv;
  cv.h = h;
  return cv.u;
}
static __device__ __forceinline__ float bf2f(unsigned short u) {
  union { unsigned int i; float f; } c;
  c.i = ((unsigned int)u) << 16;
  return c.f;
}

// ---------------------------------------------------------------------------
// RMSNorm: xnb (bf16) = x / sqrt(mean(x^2)+eps) * norm_w. One block per row.
// ---------------------------------------------------------------------------
__global__ __launch_bounds__(256) void rmsnorm_kernel(
    const float* __restrict__ x, const float* __restrict__ nw,
    unsigned short* __restrict__ xnb) {
  int row = blockIdx.x;
  int tid = threadIdx.x;
  const float4* xr = (const float4*)(x + (size_t)row * DD);
  float4 v = xr[tid];
  float ss = v.x * v.x + v.y * v.y + v.z * v.z + v.w * v.w;
#pragma unroll
  for (int off = 32; off; off >>= 1) ss += __shfl_xor(ss, off);
  __shared__ float red[4];
  int wid = tid >> 6;
  if ((tid & 63) == 0) red[wid] = ss;
  __syncthreads();
  float tot = red[0] + red[1] + red[2] + red[3];
  float inv = 1.0f / sqrtf(tot * (1.0f / DD) + 1e-6f);
  const float4* wr = (const float4*)nw;
  float4 wv = wr[tid];
  ushort4 o;
  o.x = f2bf(v.x * inv * wv.x);
  o.y = f2bf(v.y * inv * wv.y);
  o.z = f2bf(v.z * inv * wv.z);
  o.w = f2bf(v.w * inv * wv.w);
  *(ushort4*)&xnb[(size_t)row * DD + tid * 4] = o;
}

// ---------------------------------------------------------------------------
// Convert + transpose 1024x1024 weights fp32 [K][N] -> bf16 [N][K].
// ---------------------------------------------------------------------------
__global__ __launch_bounds__(256) void convert_wt_kernel(
    const float* W0, const float* W1, const float* W2, const float* W3,
    const float* W4, const float* W5, const float* W6, const float* W7,
    unsigned short* T0, unsigned short* T1, unsigned short* T2,
    unsigned short* T3, unsigned short* T4, unsigned short* T5,
    unsigned short* T6, unsigned short* T7) {
  const float* W;
  unsigned short* T;
  switch (blockIdx.z) {
    case 0: W = W0; T = T0; break;
    case 1: W = W1; T = T1; break;
    case 2: W = W2; T = T2; break;
    case 3: W = W3; T = T3; break;
    case 4: W = W4; T = T4; break;
    case 5: W = W5; T = T5; break;
    case 6: W = W6; T = T6; break;
    default: W = W7; T = T7; break;
  }
  __shared__ float Ts[64][68];
  int tid = threadIdx.x;
  int n0 = blockIdx.x * 64, k0 = blockIdx.y * 64;
#pragma unroll
  for (int p = 0; p < 4; ++p) {
    int e = p * 256 + tid;
    int k = e >> 4, nq = e & 15;
    float4 w = *(const float4*)&W[(size_t)(k0 + k) * 1024 + n0 + nq * 4];
    Ts[nq * 4 + 0][k] = w.x;
    Ts[nq * 4 + 1][k] = w.y;
    Ts[nq * 4 + 2][k] = w.z;
    Ts[nq * 4 + 3][k] = w.w;
  }
  __syncthreads();
#pragma unroll
  for (int p = 0; p < 4; ++p) {
    int e = p * 256 + tid;
    int n = e >> 4, kq = e & 15;
    float4 v = *(const float4*)&Ts[n][kq * 4];
    ushort4 u;
    u.x = f2bf(v.x);
    u.y = f2bf(v.y);
    u.z = f2bf(v.z);
    u.w = f2bf(v.w);
    *(ushort4*)&T[(size_t)(n0 + n) * 1024 + k0 + kq * 4] = u;
  }
}

// ---------------------------------------------------------------------------
// bf16 MFMA GEMM (128x128 tile, BK=32), as in R3.
// ---------------------------------------------------------------------------
__global__ __launch_bounds__(256) void gemm_mfma_kernel(
    const unsigned short* __restrict__ A, const unsigned short* __restrict__ BT,
    float* __restrict__ C, const float* __restrict__ addp,
    const float* __restrict__ rowscale, float scale, int M, int N, int K) {
  __shared__ unsigned short As[128][40];
  __shared__ unsigned short Bs[128][40];
  int tid = threadIdx.x;
  int n0 = blockIdx.x * 128, m0 = blockIdx.y * 128;
  int wave = tid >> 6, lane = tid & 63;
  int wm = (wave & 1) * 64, wn = (wave >> 1) * 64;
  int r16 = lane & 15, quad = lane >> 4;
  int srow = tid >> 2, scq = tid & 3;

  f32x4 acc[4][4];
#pragma unroll
  for (int i = 0; i < 4; ++i)
#pragma unroll
    for (int j = 0; j < 4; ++j) acc[i][j] = {0.f, 0.f, 0.f, 0.f};

  for (int kt = 0; kt < K; kt += 32) {
    uint4 a0 = *(const uint4*)&A[(size_t)(m0 + srow) * K + kt + scq * 8];
    uint4 a1 = *(const uint4*)&A[(size_t)(m0 + 64 + srow) * K + kt + scq * 8];
    uint4 b0 = *(const uint4*)&BT[(size_t)(n0 + srow) * K + kt + scq * 8];
    uint4 b1 = *(const uint4*)&BT[(size_t)(n0 + 64 + srow) * K + kt + scq * 8];
    __syncthreads();
    *(uint4*)&As[srow][scq * 8] = a0;
    *(uint4*)&As[64 + srow][scq * 8] = a1;
    *(uint4*)&Bs[srow][scq * 8] = b0;
    *(uint4*)&Bs[64 + srow][scq * 8] = b1;
    __syncthreads();
    bfrag8 af[4], bq[4];
#pragma unroll
    for (int i = 0; i < 4; ++i) {
      af[i] = *(const bfrag8*)&As[wm + i * 16 + r16][quad * 8];
      bq[i] = *(const bfrag8*)&Bs[wn + i * 16 + r16][quad * 8];
    }
#pragma unroll
    for (int i = 0; i < 4; ++i)
#pragma unroll
      for (int j = 0; j < 4; ++j)
        acc[i][j] = __builtin_amdgcn_mfma_f32_16x16x32_bf16(af[i], bq[j],
                                                            acc[i][j], 0, 0, 0);
  }
#pragma unroll
  for (int i = 0; i < 4; ++i) {
#pragma unroll
    for (int r = 0; r < 4; ++r) {
      int row = m0 + wm + i * 16 + quad * 4 + r;
      float rs = scale * (rowscale ? rowscale[row] : 1.f);
#pragma unroll
      for (int j = 0; j < 4; ++j) {
        int col = n0 + wn + j * 16 + r16;
        size_t idx = (size_t)row * N + col;
        float base = addp ? addp[idx] : 0.f;
        C[idx] = base + rs * acc[i][j][r];
      }
    }
  }
}

// ---------------------------------------------------------------------------
// L2-normalize rows of 64 (k_shared).
// ---------------------------------------------------------------------------
__global__ __launch_bounds__(256) void knorm_kernel(float* __restrict__ ksh) {
  int w = blockIdx.x * 4 + (threadIdx.x >> 6);
  int lane = threadIdx.x & 63;
  float v = ksh[(size_t)w * 64 + lane];
  float ss = v * v;
#pragma unroll
  for (int off = 32; off; off >>= 1) ss += __shfl_xor(ss, off);
  float n = sqrtf(ss);
  n = fmaxf(n, 1e-12f);
  ksh[(size_t)w * 64 + lane] = v / n;
}

// ---------------------------------------------------------------------------
// Small projections: beta, g, gate.
// ---------------------------------------------------------------------------
__global__ __launch_bounds__(256) void smallproj_kernel(
    const unsigned short* __restrict__ xnb, const float* __restrict__ Wb,
    const float* __restrict__ bb, const float* __restrict__ Wg,
    const float* __restrict__ bg, const float* __restrict__ Wgate,
    const float* __restrict__ bgate, const int* __restrict__ ids,
    float* __restrict__ beta, float* __restrict__ g, float* __restrict__ mg) {
  int row = blockIdx.x;
  int tid = threadIdx.x;
  __shared__ float xr[DD];
  __shared__ float gl[16];
  ushort4 u = *(const ushort4*)&xnb[(size_t)row * DD + tid * 4];
  xr[tid * 4 + 0] = bf2f(u.x);
  xr[tid * 4 + 1] = bf2f(u.y);
  xr[tid * 4 + 2] = bf2f(u.z);
  xr[tid * 4 + 3] = bf2f(u.w);
  __syncthreads();
  if (tid < 48) {
    int h = tid & 15;
    const float* W = (tid < 16) ? Wb : ((tid < 32) ? Wg : Wgate);
    float acc = 0.f;
    for (int d = 0; d < DD; ++d) acc = fmaf(xr[d], W[d * 16 + h], acc);
    if (tid < 16) {
      float s = 1.f / (1.f + __expf(-(acc + bb[h])));
      float mk = (ids[row] == MARKER_ID) ? 1.0f : 0.1f;
      beta[(size_t)row * 16 + h] = s * mk;
    } else if (tid < 32) {
      g[(size_t)row * 16 + h] = 1.f / (1.f + __expf(-(acc + bg[h])));
    } else {
      gl[h] = 1.f / (1.f + __expf(-(acc + bgate[h])));
    }
  }
  __syncthreads();
  if (tid == 0) {
    float s = 0.f;
#pragma unroll
    for (int h = 0; h < 16; ++h) s += gl[h];
    mg[row] = s * (1.f / 16.f);
  }
}

// ---------------------------------------------------------------------------
// Tiled flash-style sliding-window attention (fp32 in, bf16 out). As in R3.
// ---------------------------------------------------------------------------
__global__ __launch_bounds__(256) void attn_tile_kernel(
    const float* __restrict__ Q, const float* __restrict__ KL,
    const float* __restrict__ VL, unsigned short* __restrict__ Loutb) {
  __shared__ float Qs[64][68];
  __shared__ float Ks[64][68];
  __shared__ float Ps[64][68];
  __shared__ float Vs[64][68];
  int qb = blockIdx.x * 64;
  int bh = blockIdx.y;
  int h = bh & 15, b = bh >> 4;
  int tid = threadIdx.x;
  int tx = tid & 15, ty = tid >> 4;

  const float* Qg = Q + (size_t)b * TT * DD + h * 64;
  const float* Kg = KL + (size_t)b * TT * DD + h * 64;
  const float* Vg = VL + (size_t)b * TT * DD + h * 64;

#pragma unroll
  for (int p = 0; p < 4; ++p) {
    int e = p * 1024 + tid * 4;
    int i = e >> 6, d = e & 63;
    float4 qv = *(const float4*)&Qg[(size_t)(qb + i) * DD + d];
    Qs[d + 0][i] = qv.x;
    Qs[d + 1][i] = qv.y;
    Qs[d + 2][i] = qv.z;
    Qs[d + 3][i] = qv.w;
  }

  float O[4][4];
  float m[4], l[4];
#pragma unroll
  for (int r = 0; r < 4; ++r) {
    m[r] = -1e30f;
    l[r] = 0.f;
#pragma unroll
    for (int c = 0; c < 4; ++c) O[r][c] = 0.f;
  }

  int kt_start = qb - (int)WIN;
  if (kt_start < 0) kt_start = 0;

  for (int kt = kt_start; kt <= qb; kt += 64) {
    __syncthreads();
#pragma unroll
    for (int p = 0; p < 4; ++p) {
      int e = p * 1024 + tid * 4;
      int i = e >> 6, d = e & 63;
      float4 kv = *(const float4*)&Kg[(size_t)(kt + i) * DD + d];
      Ks[d + 0][i] = kv.x;
      Ks[d + 1][i] = kv.y;
      Ks[d + 2][i] = kv.z;
      Ks[d + 3][i] = kv.w;
      float4 vv = *(const float4*)&Vg[(size_t)(kt + i) * DD + d];
      *(float4*)&Vs[i][d] = vv;
    }
    __syncthreads();

    float s[4][4];
#pragma unroll
    for (int r = 0; r < 4; ++r)
#pragma unroll
      for (int c = 0; c < 4; ++c) s[r][c] = 0.f;
#pragma unroll 4
    for (int d = 0; d < 64; ++d) {
      float4 qv = *(const float4*)&Qs[d][ty * 4];
      float4 kv = *(const float4*)&Ks[d][tx * 4];
      s[0][0] = fmaf(qv.x, kv.x, s[0][0]);
      s[0][1] = fmaf(qv.x, kv.y, s[0][1]);
      s[0][2] = fmaf(qv.x, kv.z, s[0][2]);
      s[0][3] = fmaf(qv.x, kv.w, s[0][3]);
      s[1][0] = fmaf(qv.y, kv.x, s[1][0]);
      s[1][1] = fmaf(qv.y, kv.y, s[1][1]);
      s[1][2] = fmaf(qv.y, kv.z, s[1][2]);
      s[1][3] = fmaf(qv.y, kv.w, s[1][3]);
      s[2][0] = fmaf(qv.z, kv.x, s[2][0]);
      s[2][1] = fmaf(qv.z, kv.y, s[2][1]);
      s[2][2] = fmaf(qv.z, kv.z, s[2][2]);
      s[2][3] = fmaf(qv.z, kv.w, s[2][3]);
      s[3][0] = fmaf(qv.w, kv.x, s[3][0]);
      s[3][1] = fmaf(qv.w, kv.y, s[3][1]);
      s[3][2] = fmaf(qv.w, kv.z, s[3][2]);
      s[3][3] = fmaf(qv.w, kv.w, s[3][3]);
    }
    bool oldest = (kt == qb - (int)WIN);
    bool newest = (kt == qb);
#pragma unroll
    for (int r = 0; r < 4; ++r) {
      int il = ty * 4 + r;
#pragma unroll
      for (int c = 0; c < 4; ++c) {
        int jl = tx * 4 + c;
        float v = s[r][c] * 0.125f;
        if (oldest && jl < il) v = -1e30f;
        if (newest && jl > il) v = -1e30f;
        s[r][c] = v;
      }
    }
#pragma unroll
    for (int r = 0; r < 4; ++r) {
      float rm = fmaxf(fmaxf(s[r][0], s[r][1]), fmaxf(s[r][2], s[r][3]));
#pragma unroll
      for (int off = 1; off < 16; off <<= 1) rm = fmaxf(rm, __shfl_xor(rm, off));
      float mn = fmaxf(m[r], rm);
      float alpha = __expf(m[r] - mn);
      m[r] = mn;
      float rs = 0.f;
#pragma unroll
      for (int c = 0; c < 4; ++c) {
        float p = __expf(s[r][c] - mn);
        s[r][c] = p;
        rs += p;
      }
#pragma unroll
      for (int off = 1; off < 16; off <<= 1) rs += __shfl_xor(rs, off);
      l[r] = l[r] * alpha + rs;
#pragma unroll
      for (int c = 0; c < 4; ++c) O[r][c] *= alpha;
    }
#pragma unroll
    for (int r = 0; r < 4; ++r)
#pragma unroll
      for (int c = 0; c < 4; ++c) Ps[tx * 4 + c][ty * 4 + r] = s[r][c];
    __syncthreads();
#pragma unroll 4
    for (int j = 0; j < 64; ++j) {
      float4 pv = *(const float4*)&Ps[j][ty * 4];
      float4 vv = *(const float4*)&Vs[j][tx * 4];
      O[0][0] = fmaf(pv.x, vv.x, O[0][0]);
      O[0][1] = fmaf(pv.x, vv.y, O[0][1]);
      O[0][2] = fmaf(pv.x, vv.z, O[0][2]);
      O[0][3] = fmaf(pv.x, vv.w, O[0][3]);
      O[1][0] = fmaf(pv.y, vv.x, O[1][0]);
      O[1][1] = fmaf(pv.y, vv.y, O[1][1]);
      O[1][2] = fmaf(pv.y, vv.z, O[1][2]);
      O[1][3] = fmaf(pv.y, vv.w, O[1][3]);
      O[2][0] = fmaf(pv.z, vv.x, O[2][0]);
      O[2][1] = fmaf(pv.z, vv.y, O[2][1]);
      O[2][2] = fmaf(pv.z, vv.z, O[2][2]);
      O[2][3] = fmaf(pv.z, vv.w, O[2][3]);
      O[3][0] = fmaf(pv.w, vv.x, O[3][0]);
      O[3][1] = fmaf(pv.w, vv.y, O[3][1]);
      O[3][2] = fmaf(pv.w, vv.z, O[3][2]);
      O[3][3] = fmaf(pv.w, vv.w, O[3][3]);
    }
  }
#pragma unroll
  for (int r = 0; r < 4; ++r) {
    float inv = 1.f / l[r];
    ushort4 res;
    res.x = f2bf(O[r][0] * inv);
    res.y = f2bf(O[r][1] * inv);
    res.z = f2bf(O[r][2] * inv);
    res.w = f2bf(O[r][3] * inv);
    int i = qb + ty * 4 + r;
    *(ushort4*)&Loutb[((size_t)(b * TT + i)) * DD + h * 64 + tx * 4] = res;
  }
}

// ---------------------------------------------------------------------------
// Chunk-parallel gated delta scan. One block (4 waves) per (b,h); 16 chunks
// of 64 steps. Per chunk:
//   u_t = beta_t(v_t - a_t S0^T k_t) - sum_{s<t} beta_t (a_t/a_s)(k_s.k_t) u_s
//   o_t = a_t S0^T k_t + sum_{s<=t} (a_t/a_s)(k_s.k_t) u_s
//   S_C = a_C S0 + sum_t (a_C/a_t) k_t u_t^T
// KK^T / S0^T K / O / S-update via bf16 MFMA (fp32 accum); triangular solve
// fp32 on wave 0 with U fully in registers (unrolled).
// ---------------------------------------------------------------------------
__global__ __launch_bounds__(256) void scan_chunk_kernel(
    const float* __restrict__ ksh, const float* __restrict__ vfull,
    const float* __restrict__ beta, const float* __restrict__ g,
    const float* __restrict__ S0, unsigned short* __restrict__ gdnb,
    float* __restrict__ Sf) {
  __shared__ float Sf32[64][68];   // state S[k][v], fp32 master
  __shared__ float Vc[64][68];     // V chunk -> RHS (in place)
  __shared__ float Obuf[64][68];   // a_t * S0k
  __shared__ float Msv[64][68];    // solve matrix (strict lower, else 0)
  __shared__ unsigned short Kc[64][72];   // K[t][k] bf16
  __shared__ unsigned short KTb[64][72];  // K^T[k][t] * (aC/a_t) bf16
  __shared__ unsigned short STb[64][72];  // S^T[v][k] bf16 mirror
  __shared__ unsigned short UTb[64][72];  // U^T[v][t] bf16
  __shared__ unsigned short WL[64][72];   // (a_t/a_s)KK lower incl diag
  __shared__ float aArr[64], iaArr[64], bArr[64], sKT[64];
  __shared__ float aCs;

  int bh = blockIdx.x;
  int b = bh >> 4, h = bh & 15;
  int tid = threadIdx.x;
  int lane = tid & 63;
  int wave = tid >> 6;
  int r16 = lane & 15, quad = lane >> 4;
  int m0w = wave * 16;

  const float* kbase = ksh + ((size_t)b * TT) * DD + h * 64;
  const float* vbase = vfull + ((size_t)b * TT) * DD + h * 64;
  const float* bbase = beta + ((size_t)b * TT) * HH + h;
  const float* gbase = g + ((size_t)b * TT) * HH + h;

  // Init: S0 -> Sf32 + STb; zero gdn row t=0.
  {
    const float* s0p = S0 + (size_t)bh * 4096;
    int r = tid >> 2, q = tid & 3;
#pragma unroll
    for (int i = 0; i < 4; ++i) {
      float4 sv = *(const float4*)&s0p[r * 64 + q * 16 + i * 4];
      *(float4*)&Sf32[r][q * 16 + i * 4] = sv;
      STb[q * 16 + i * 4 + 0][r] = f2bf(sv.x);
      STb[q * 16 + i * 4 + 1][r] = f2bf(sv.y);
      STb[q * 16 + i * 4 + 2][r] = f2bf(sv.z);
      STb[q * 16 + i * 4 + 3][r] = f2bf(sv.w);
    }
    if (tid < 64) gdnb[((size_t)b * TT) * DD + h * 64 + tid] = 0;
  }

  for (int c = 0; c < 16; ++c) {
    int tc = c * 64;
    __syncthreads();  // prev chunk reads done / init done
    // --- stage 1: g, beta, cumulative products (wave 0) ---
    if (tid < 64) {
      int ts = tc + tid;
      bool pad = (ts > 1022);
      float gv = pad ? 1.f : gbase[(size_t)ts * HH];
      float bv = pad ? 0.f : bbase[(size_t)ts * HH];
      float p = gv;
#pragma unroll
      for (int o = 1; o < 64; o <<= 1) {
        float t = __shfl_up(p, o);
        if (lane >= o) p *= t;
      }
      float ip = 1.f / p;
      aArr[tid] = p;
      iaArr[tid] = ip;
      bArr[tid] = bv;
      float aC = __shfl(p, 63);
      sKT[tid] = aC * ip;
      if (tid == 0) aCs = aC;
    }
    __syncthreads();  // a ready
    // --- stage 2: K, V chunk -> LDS ---
    {
      int r = tid >> 2, q = tid & 3;
      int ts = tc + r;
      float skt = sKT[r];
#pragma unroll
      for (int i = 0; i < 4; ++i) {
        float4 kv = *(const float4*)&kbase[(size_t)ts * DD + q * 16 + i * 4];
        ushort4 ku;
        ku.x = f2bf(kv.x);
        ku.y = f2bf(kv.y);
        ku.z = f2bf(kv.z);
        ku.w = f2bf(kv.w);
        *(ushort4*)&Kc[r][q * 16 + i * 4] = ku;
        KTb[q * 16 + i * 4 + 0][r] = f2bf(kv.x * skt);
        KTb[q * 16 + i * 4 + 1][r] = f2bf(kv.y * skt);
        KTb[q * 16 + i * 4 + 2][r] = f2bf(kv.z * skt);
        KTb[q * 16 + i * 4 + 3][r] = f2bf(kv.w * skt);
        float4 vv;
        if (ts <= 1022)
          vv = *(const float4*)&vbase[(size_t)(ts + 1) * DD + q * 16 + i * 4];
        else
          vv = make_float4(0.f, 0.f, 0.f, 0.f);
        *(float4*)&Vc[r][q * 16 + i * 4] = vv;
      }
    }
    __syncthreads();  // staging done
    // --- GEMM1 (KK^T) + GEMM2 (S0^T K): A = Kc rows of this wave ---
    {
      bfrag8 af0 = *(const bfrag8*)&Kc[m0w + r16][quad * 8];
      bfrag8 af1 = *(const bfrag8*)&Kc[m0w + r16][quad * 8 + 32];
      f32x4 acc1[4], acc2[4];
#pragma unroll
      for (int j = 0; j < 4; ++j) {
        acc1[j] = {0.f, 0.f, 0.f, 0.f};
        acc2[j] = {0.f, 0.f, 0.f, 0.f};
      }
#pragma unroll
      for (int j = 0; j < 4; ++j) {
        bfrag8 k0 = *(const bfrag8*)&Kc[j * 16 + r16][quad * 8];
        bfrag8 k1 = *(const bfrag8*)&Kc[j * 16 + r16][quad * 8 + 32];
        acc1[j] = __builtin_amdgcn_mfma_f32_16x16x32_bf16(af0, k0, acc1[j], 0, 0, 0);
        acc1[j] = __builtin_amdgcn_mfma_f32_16x16x32_bf16(af1, k1, acc1[j], 0, 0, 0);
        bfrag8 s0 = *(const bfrag8*)&STb[j * 16 + r16][quad * 8];
        bfrag8 s1 = *(const bfrag8*)&STb[j * 16 + r16][quad * 8 + 32];
        acc2[j] = __builtin_amdgcn_mfma_f32_16x16x32_bf16(af0, s0, acc2[j], 0, 0, 0);
        acc2[j] = __builtin_amdgcn_mfma_f32_16x16x32_bf16(af1, s1, acc2[j], 0, 0, 0);
      }
#pragma unroll
      for (int j = 0; j < 4; ++j) {
#pragma unroll
        for (int r = 0; r < 4; ++r) {
          int row = m0w + quad * 4 + r;
          int col = j * 16 + r16;
          float ar = aArr[row], br = bArr[row];
          // KK epilogue
          float w = ar * iaArr[col] * acc1[j][r];
          Msv[row][col] = (col < row) ? br * w : 0.f;
          WL[row][col] = (col <= row) ? f2bf(w) : (unsigned short)0;
          // S0k epilogue
          float oa = ar * acc2[j][r];
          Obuf[row][col] = oa;
          Vc[row][col] = br * (Vc[row][col] - oa);  // RHS in place
        }
      }
    }
    __syncthreads();  // Msv, RHS ready
    // --- triangular solve (wave 0, lane = v) ---
    if (wave == 0) {
      float u[64];
#pragma unroll
      for (int t = 0; t < 64; ++t) u[t] = Vc[t][lane];
#pragma unroll
      for (int t = 1; t < 64; ++t) {
        float a0 = 0.f, a1 = 0.f, a2 = 0.f, a3 = 0.f;
#pragma unroll
        for (int s4 = 0; s4 * 4 < t; ++s4) {
          float4 mr = *(const float4*)&Msv[t][s4 * 4];  // zeros for s>=t
          a0 = fmaf(mr.x, u[s4 * 4 + 0], a0);
          a1 = fmaf(mr.y, u[s4 * 4 + 1], a1);
          a2 = fmaf(mr.z, u[s4 * 4 + 2], a2);
          a3 = fmaf(mr.w, u[s4 * 4 + 3], a3);
        }
        u[t] -= (a0 + a1) + (a2 + a3);
      }
#pragma unroll
      for (int t2 = 0; t2 < 32; ++t2) {
        unsigned int pk = (unsigned int)f2bf(u[2 * t2]) |
                          ((unsigned int)f2bf(u[2 * t2 + 1]) << 16);
        *(unsigned int*)&UTb[lane][2 * t2] = pk;
      }
    }
    __syncthreads();  // U ready
    // --- GEMM3 (O = Obuf + WL U) + GEMM4 (S = aC*S + KT U) ---
    {
      bfrag8 bu0[4], bu1[4];
#pragma unroll
      for (int j = 0; j < 4; ++j) {
        bu0[j] = *(const bfrag8*)&UTb[j * 16 + r16][quad * 8];
        bu1[j] = *(const bfrag8*)&UTb[j * 16 + r16][quad * 8 + 32];
      }
      // GEMM3
      {
        bfrag8 wa0 = *(const bfrag8*)&WL[m0w + r16][quad * 8];
        bfrag8 wa1 = *(const bfrag8*)&WL[m0w + r16][quad * 8 + 32];
        f32x4 acc[4];
#pragma unroll
        for (int j = 0; j < 4; ++j) acc[j] = {0.f, 0.f, 0.f, 0.f};
#pragma unroll
        for (int j = 0; j < 4; ++j) {
          acc[j] = __builtin_amdgcn_mfma_f32_16x16x32_bf16(wa0, bu0[j], acc[j], 0, 0, 0);
          acc[j] = __builtin_amdgcn_mfma_f32_16x16x32_bf16(wa1, bu1[j], acc[j], 0, 0, 0);
        }
#pragma unroll
        for (int j = 0; j < 4; ++j) {
#pragma unroll
          for (int r = 0; r < 4; ++r) {
            int row = m0w + quad * 4 + r;
            int col = j * 16 + r16;
            int ts = tc + row;
            if (ts < 1023) {
              float out = Obuf[row][col] + acc[j][r];
              gdnb[((size_t)b * TT + ts + 1) * DD + h * 64 + col] = f2bf(out);
            }
          }
        }
      }
      // GEMM4
      {
        bfrag8 ka0 = *(const bfrag8*)&KTb[m0w + r16][quad * 8];
        bfrag8 ka1 = *(const bfrag8*)&KTb[m0w + r16][quad * 8 + 32];
        f32x4 acc[4];
#pragma unroll
        for (int j = 0; j < 4; ++j) acc[j] = {0.f, 0.f, 0.f, 0.f};
#pragma unroll
        for (int j = 0; j < 4; ++j) {
          acc[j] = __builtin_amdgcn_mfma_f32_16x16x32_bf16(ka0, bu0[j], acc[j], 0, 0, 0);
          acc[j] = __builtin_amdgcn_mfma_f32_16x16x32_bf16(ka1, bu1[j], acc[j], 0, 0, 0);
        }
        float aC = aCs;
#pragma unroll
        for (int j = 0; j < 4; ++j) {
#pragma unroll
          for (int r = 0; r < 4; ++r) {
            int row = m0w + quad * 4 + r;  // k
            int col = j * 16 + r16;        // v
            float sn = aC * Sf32[row][col] + acc[j][r];
            Sf32[row][col] = sn;
            STb[col][row] = f2bf(sn);
          }
        }
      }
    }
  }
  __syncthreads();
  // Final state out (fp32)
  {
    int r = tid >> 2, q = tid & 3;
    float* sfp = Sf + (size_t)bh * 4096;
#pragma unroll
    for (int i = 0; i < 4; ++i) {
      float4 sv = *(const float4*)&Sf32[r][q * 16 + i * 4];
      *(float4*)&sfp[r * 64 + q * 16 + i * 4] = sv;
    }
  }
}

// ---------------------------------------------------------------------------
// retrieved[b,t,h,:] = k_shared[b,t,h,:] @ Sf[b,h,:,:]. bf16 out.
// ---------------------------------------------------------------------------
__global__ __launch_bounds__(256) void retrieve_kernel(
    const float* __restrict__ ksh, const float* __restrict__ Sf,
    unsigned short* __restrict__ retrb) {
  int w = blockIdx.x * 4 + (threadIdx.x >> 6);  // (b*T+t)*H + h
  int lane = threadIdx.x & 63;                  // v index
  float kl = ksh[(size_t)w * 64 + lane];
  int bt = w >> 4;
  int b = bt >> 10;
  int bh = b * 16 + (w & 15);
  const float* sfp = Sf + (size_t)bh * 4096;
  float acc = 0.f;
#pragma unroll
  for (int k = 0; k < 64; ++k) {
    float kk = __shfl(kl, k);
    acc = fmaf(kk, sfp[k * 64 + lane], acc);
  }
  retrb[(size_t)bt * DD + (w & 15) * 64 + lane] = f2bf(acc);
}

// ---------------------------------------------------------------------------
extern "C" void kernel_launch(void* const* d_in, const int* in_sizes, int n_in,
                              void* d_out, int out_size, void* d_ws,
                              size_t ws_size, hipStream_t stream) {
  (void)in_sizes; (void)n_in; (void)out_size; (void)ws_size;
  const float* x       = (const float*)d_in[0];
  const float* S0      = (const float*)d_in[1];
  const float* W_k     = (const float*)d_in[2];
  const float* W_v     = (const float*)d_in[3];
  const float* W_gdn_o = (const float*)d_in[4];
  const float* W_beta  = (const float*)d_in[5];
  const float* b_beta  = (const float*)d_in[6];
  const float* W_g     = (const float*)d_in[7];
  const float* b_g     = (const float*)d_in[8];
  const float* W_lq    = (const float*)d_in[9];
  const float* W_lk    = (const float*)d_in[10];
  const float* W_lv    = (const float*)d_in[11];
  const float* W_swa_o = (const float*)d_in[12];
  const float* W_ret_o = (const float*)d_in[13];
  const float* W_gate  = (const float*)d_in[14];
  const float* b_gate  = (const float*)d_in[15];
  const float* norm_w  = (const float*)d_in[16];
  const int*   ids     = (const int*)d_in[17];
  float* out = (float*)d_out;

  char* ws = (char*)d_ws;
  size_t off = 0;
  auto allocf = [&](size_t nfloats) {
    float* p = (float*)(ws + off);
    off += nfloats * sizeof(float);
    return p;
  };
  auto allocu = [&](size_t nshorts) {
    unsigned short* p = (unsigned short*)(ws + off);
    off += nshorts * sizeof(unsigned short);
    return p;
  };
  const size_t BTD = (size_t)BB * TT * DD;  // 4M
  unsigned short* XNb = allocu(BTD);
  float* KSH  = allocf(BTD);
  float* VF   = allocf(BTD);
  float* Qb   = allocf(BTD);
  float* KLb  = allocf(BTD);
  float* VLb  = allocf(BTD);
  unsigned short* WTk   = allocu(1024 * 1024);
  unsigned short* WTv   = allocu(1024 * 1024);
  unsigned short* WTlq  = allocu(1024 * 1024);
  unsigned short* WTlk  = allocu(1024 * 1024);
  unsigned short* WTlv  = allocu(1024 * 1024);
  unsigned short* WTgdn = allocu(1024 * 1024);
  unsigned short* WTswa = allocu(1024 * 1024);
  unsigned short* WTret = allocu(1024 * 1024);
  float* BETA = allocf((size_t)BB * TT * HH);
  float* Gg   = allocf((size_t)BB * TT * HH);
  float* MG   = allocf((size_t)BB * TT);
  float* SF   = allocf((size_t)BB * HH * KK * VV);
  unsigned short* GDNb   = XNb;                   // after smallproj+5 gemms
  unsigned short* LOCALb = (unsigned short*)VF;   // after scan consumed VF
  unsigned short* RETRb  = (unsigned short*)Qb;   // after attn consumed Qb

  const int M = BB * TT;  // 4096
  dim3 gemmGrid(DD / 128, M / 128);

  rmsnorm_kernel<<<M, 256, 0, stream>>>(x, norm_w, XNb);

  convert_wt_kernel<<<dim3(16, 16, 8), 256, 0, stream>>>(
      W_k, W_v, W_lq, W_lk, W_lv, W_gdn_o, W_swa_o, W_ret_o,
      WTk, WTv, WTlq, WTlk, WTlv, WTgdn, WTswa, WTret);

  gemm_mfma_kernel<<<gemmGrid, 256, 0, stream>>>(XNb, WTk, KSH, nullptr, nullptr, 1.f, M, DD, DD);
  gemm_mfma_kernel<<<gemmGrid, 256, 0, stream>>>(XNb, WTv, VF, nullptr, nullptr, 1.f, M, DD, DD);
  gemm_mfma_kernel<<<gemmGrid, 256, 0, stream>>>(XNb, WTlq, Qb, nullptr, nullptr, 1.f, M, DD, DD);
  gemm_mfma_kernel<<<gemmGrid, 256, 0, stream>>>(XNb, WTlk, KLb, nullptr, nullptr, 1.f, M, DD, DD);
  gemm_mfma_kernel<<<gemmGrid, 256, 0, stream>>>(XNb, WTlv, VLb, nullptr, nullptr, 1.f, M, DD, DD);

  knorm_kernel<<<(BB * TT * HH) / 4, 256, 0, stream>>>(KSH);
  smallproj_kernel<<<M, 256, 0, stream>>>(XNb, W_beta, b_beta, W_g, b_g, W_gate,
                                          b_gate, ids, BETA, Gg, MG);

  scan_chunk_kernel<<<BB * HH, 256, 0, stream>>>(KSH, VF, BETA, Gg, S0, GDNb, SF);

  attn_tile_kernel<<<dim3(TT / 64, BB * HH), 256, 0, stream>>>(Qb, KLb, VLb, LOCALb);

  retrieve_kernel<<<(BB * TT * HH) / 4, 256, 0, stream>>>(KSH, SF, RETRb);

  gemm_mfma_kernel<<<gemmGrid, 256, 0, stream>>>(GDNb, WTgdn, out, x, nullptr, 1.f, M, DD, DD);
  gemm_mfma_kernel<<<gemmGrid, 256, 0, stream>>>(LOCALb, WTswa, out, out, nullptr, 0.3f, M, DD, DD);
  gemm_mfma_kernel<<<gemmGrid, 256, 0, stream>>>(RETRb, WTret, out, out, MG, 1.f, M, DD, DD);
}

// Round 5
// 685.593 us; speedup vs baseline: 4.7102x; 1.3980x over previous
//
#include <hip/hip_runtime.h>
#include <hip/hip_bf16.h>

// Problem constants
#define BB 4
#define TT 1024
#define DD 1024
#define HH 16
#define KK 64
#define VV 64
#define WIN 256
#define MARKER_ID 50251

typedef short bfrag8 __attribute__((ext_vector_type(8)));
typedef float f32x4 __attribute__((ext_vector_type(4)));

static __device__ __forceinline__ unsigned short f2bf(float f) {
  __hip_bfloat16 h = __float2bfloat16(f);
  union { __hip_bfloat16 h; unsigned short u; } cv;
  cv.h = h;
  return cv.u;
}
static __device__ __forceinline__ float bf2f(unsigned short u) {
  union { unsigned int i; float f; } c;
  c.i = ((unsigned int)u) << 16;
  return c.f;
}

// ---------------------------------------------------------------------------
// RMSNorm: xnb (bf16) = x / sqrt(mean(x^2)+eps) * norm_w. One block per row.
// ---------------------------------------------------------------------------
__global__ __launch_bounds__(256) void rmsnorm_kernel(
    const float* __restrict__ x, const float* __restrict__ nw,
    unsigned short* __restrict__ xnb) {
  int row = blockIdx.x;
  int tid = threadIdx.x;
  const float4* xr = (const float4*)(x + (size_t)row * DD);
  float4 v = xr[tid];
  float ss = v.x * v.x + v.y * v.y + v.z * v.z + v.w * v.w;
#pragma unroll
  for (int off = 32; off; off >>= 1) ss += __shfl_xor(ss, off);
  __shared__ float red[4];
  int wid = tid >> 6;
  if ((tid & 63) == 0) red[wid] = ss;
  __syncthreads();
  float tot = red[0] + red[1] + red[2] + red[3];
  float inv = 1.0f / sqrtf(tot * (1.0f / DD) + 1e-6f);
  const float4* wr = (const float4*)nw;
  float4 wv = wr[tid];
  ushort4 o;
  o.x = f2bf(v.x * inv * wv.x);
  o.y = f2bf(v.y * inv * wv.y);
  o.z = f2bf(v.z * inv * wv.z);
  o.w = f2bf(v.w * inv * wv.w);
  *(ushort4*)&xnb[(size_t)row * DD + tid * 4] = o;
}

// ---------------------------------------------------------------------------
// Convert + transpose 1024x1024 weights fp32 [K][N] -> bf16 [N][K].
// ---------------------------------------------------------------------------
__global__ __launch_bounds__(256) void convert_wt_kernel(
    const float* W0, const float* W1, const float* W2, const float* W3,
    const float* W4, const float* W5, const float* W6, const float* W7,
    unsigned short* T0, unsigned short* T1, unsigned short* T2,
    unsigned short* T3, unsigned short* T4, unsigned short* T5,
    unsigned short* T6, unsigned short* T7) {
  const float* W;
  unsigned short* T;
  switch (blockIdx.z) {
    case 0: W = W0; T = T0; break;
    case 1: W = W1; T = T1; break;
    case 2: W = W2; T = T2; break;
    case 3: W = W3; T = T3; break;
    case 4: W = W4; T = T4; break;
    case 5: W = W5; T = T5; break;
    case 6: W = W6; T = T6; break;
    default: W = W7; T = T7; break;
  }
  __shared__ float Ts[64][68];
  int tid = threadIdx.x;
  int n0 = blockIdx.x * 64, k0 = blockIdx.y * 64;
#pragma unroll
  for (int p = 0; p < 4; ++p) {
    int e = p * 256 + tid;
    int k = e >> 4, nq = e & 15;
    float4 w = *(const float4*)&W[(size_t)(k0 + k) * 1024 + n0 + nq * 4];
    Ts[nq * 4 + 0][k] = w.x;
    Ts[nq * 4 + 1][k] = w.y;
    Ts[nq * 4 + 2][k] = w.z;
    Ts[nq * 4 + 3][k] = w.w;
  }
  __syncthreads();
#pragma unroll
  for (int p = 0; p < 4; ++p) {
    int e = p * 256 + tid;
    int n = e >> 4, kq = e & 15;
    float4 v = *(const float4*)&Ts[n][kq * 4];
    ushort4 u;
    u.x = f2bf(v.x);
    u.y = f2bf(v.y);
    u.z = f2bf(v.z);
    u.w = f2bf(v.w);
    *(ushort4*)&T[(size_t)(n0 + n) * 1024 + k0 + kq * 4] = u;
  }
}

// ---------------------------------------------------------------------------
// bf16 MFMA GEMM (128x128 tile, BK=32), as in R3.
// ---------------------------------------------------------------------------
__global__ __launch_bounds__(256) void gemm_mfma_kernel(
    const unsigned short* __restrict__ A, const unsigned short* __restrict__ BT,
    float* __restrict__ C, const float* __restrict__ addp,
    const float* __restrict__ rowscale, float scale, int M, int N, int K) {
  __shared__ unsigned short As[128][40];
  __shared__ unsigned short Bs[128][40];
  int tid = threadIdx.x;
  int n0 = blockIdx.x * 128, m0 = blockIdx.y * 128;
  int wave = tid >> 6, lane = tid & 63;
  int wm = (wave & 1) * 64, wn = (wave >> 1) * 64;
  int r16 = lane & 15, quad = lane >> 4;
  int srow = tid >> 2, scq = tid & 3;

  f32x4 acc[4][4];
#pragma unroll
  for (int i = 0; i < 4; ++i)
#pragma unroll
    for (int j = 0; j < 4; ++j) acc[i][j] = {0.f, 0.f, 0.f, 0.f};

  for (int kt = 0; kt < K; kt += 32) {
    uint4 a0 = *(const uint4*)&A[(size_t)(m0 + srow) * K + kt + scq * 8];
    uint4 a1 = *(const uint4*)&A[(size_t)(m0 + 64 + srow) * K + kt + scq * 8];
    uint4 b0 = *(const uint4*)&BT[(size_t)(n0 + srow) * K + kt + scq * 8];
    uint4 b1 = *(const uint4*)&BT[(size_t)(n0 + 64 + srow) * K + kt + scq * 8];
    __syncthreads();
    *(uint4*)&As[srow][scq * 8] = a0;
    *(uint4*)&As[64 + srow][scq * 8] = a1;
    *(uint4*)&Bs[srow][scq * 8] = b0;
    *(uint4*)&Bs[64 + srow][scq * 8] = b1;
    __syncthreads();
    bfrag8 af[4], bq[4];
#pragma unroll
    for (int i = 0; i < 4; ++i) {
      af[i] = *(const bfrag8*)&As[wm + i * 16 + r16][quad * 8];
      bq[i] = *(const bfrag8*)&Bs[wn + i * 16 + r16][quad * 8];
    }
#pragma unroll
    for (int i = 0; i < 4; ++i)
#pragma unroll
      for (int j = 0; j < 4; ++j)
        acc[i][j] = __builtin_amdgcn_mfma_f32_16x16x32_bf16(af[i], bq[j],
                                                            acc[i][j], 0, 0, 0);
  }
#pragma unroll
  for (int i = 0; i < 4; ++i) {
#pragma unroll
    for (int r = 0; r < 4; ++r) {
      int row = m0 + wm + i * 16 + quad * 4 + r;
      float rs = scale * (rowscale ? rowscale[row] : 1.f);
#pragma unroll
      for (int j = 0; j < 4; ++j) {
        int col = n0 + wn + j * 16 + r16;
        size_t idx = (size_t)row * N + col;
        float base = addp ? addp[idx] : 0.f;
        C[idx] = base + rs * acc[i][j][r];
      }
    }
  }
}

// ---------------------------------------------------------------------------
// L2-normalize rows of 64 (k_shared).
// ---------------------------------------------------------------------------
__global__ __launch_bounds__(256) void knorm_kernel(float* __restrict__ ksh) {
  int w = blockIdx.x * 4 + (threadIdx.x >> 6);
  int lane = threadIdx.x & 63;
  float v = ksh[(size_t)w * 64 + lane];
  float ss = v * v;
#pragma unroll
  for (int off = 32; off; off >>= 1) ss += __shfl_xor(ss, off);
  float n = sqrtf(ss);
  n = fmaxf(n, 1e-12f);
  ksh[(size_t)w * 64 + lane] = v / n;
}

// ---------------------------------------------------------------------------
// Small projections: beta, g, gate.
// ---------------------------------------------------------------------------
__global__ __launch_bounds__(256) void smallproj_kernel(
    const unsigned short* __restrict__ xnb, const float* __restrict__ Wb,
    const float* __restrict__ bb, const float* __restrict__ Wg,
    const float* __restrict__ bg, const float* __restrict__ Wgate,
    const float* __restrict__ bgate, const int* __restrict__ ids,
    float* __restrict__ beta, float* __restrict__ g, float* __restrict__ mg) {
  int row = blockIdx.x;
  int tid = threadIdx.x;
  __shared__ float xr[DD];
  __shared__ float gl[16];
  ushort4 u = *(const ushort4*)&xnb[(size_t)row * DD + tid * 4];
  xr[tid * 4 + 0] = bf2f(u.x);
  xr[tid * 4 + 1] = bf2f(u.y);
  xr[tid * 4 + 2] = bf2f(u.z);
  xr[tid * 4 + 3] = bf2f(u.w);
  __syncthreads();
  if (tid < 48) {
    int h = tid & 15;
    const float* W = (tid < 16) ? Wb : ((tid < 32) ? Wg : Wgate);
    float acc = 0.f;
    for (int d = 0; d < DD; ++d) acc = fmaf(xr[d], W[d * 16 + h], acc);
    if (tid < 16) {
      float s = 1.f / (1.f + __expf(-(acc + bb[h])));
      float mk = (ids[row] == MARKER_ID) ? 1.0f : 0.1f;
      beta[(size_t)row * 16 + h] = s * mk;
    } else if (tid < 32) {
      g[(size_t)row * 16 + h] = 1.f / (1.f + __expf(-(acc + bg[h])));
    } else {
      gl[h] = 1.f / (1.f + __expf(-(acc + bgate[h])));
    }
  }
  __syncthreads();
  if (tid == 0) {
    float s = 0.f;
#pragma unroll
    for (int h = 0; h < 16; ++h) s += gl[h];
    mg[row] = s * (1.f / 16.f);
  }
}

// ---------------------------------------------------------------------------
// Tiled flash-style sliding-window attention (fp32 in, bf16 out). As in R3.
// ---------------------------------------------------------------------------
__global__ __launch_bounds__(256) void attn_tile_kernel(
    const float* __restrict__ Q, const float* __restrict__ KL,
    const float* __restrict__ VL, unsigned short* __restrict__ Loutb) {
  __shared__ float Qs[64][68];
  __shared__ float Ks[64][68];
  __shared__ float Ps[64][68];
  __shared__ float Vs[64][68];
  int qb = blockIdx.x * 64;
  int bh = blockIdx.y;
  int h = bh & 15, b = bh >> 4;
  int tid = threadIdx.x;
  int tx = tid & 15, ty = tid >> 4;

  const float* Qg = Q + (size_t)b * TT * DD + h * 64;
  const float* Kg = KL + (size_t)b * TT * DD + h * 64;
  const float* Vg = VL + (size_t)b * TT * DD + h * 64;

#pragma unroll
  for (int p = 0; p < 4; ++p) {
    int e = p * 1024 + tid * 4;
    int i = e >> 6, d = e & 63;
    float4 qv = *(const float4*)&Qg[(size_t)(qb + i) * DD + d];
    Qs[d + 0][i] = qv.x;
    Qs[d + 1][i] = qv.y;
    Qs[d + 2][i] = qv.z;
    Qs[d + 3][i] = qv.w;
  }

  float O[4][4];
  float m[4], l[4];
#pragma unroll
  for (int r = 0; r < 4; ++r) {
    m[r] = -1e30f;
    l[r] = 0.f;
#pragma unroll
    for (int c = 0; c < 4; ++c) O[r][c] = 0.f;
  }

  int kt_start = qb - (int)WIN;
  if (kt_start < 0) kt_start = 0;

  for (int kt = kt_start; kt <= qb; kt += 64) {
    __syncthreads();
#pragma unroll
    for (int p = 0; p < 4; ++p) {
      int e = p * 1024 + tid * 4;
      int i = e >> 6, d = e & 63;
      float4 kv = *(const float4*)&Kg[(size_t)(kt + i) * DD + d];
      Ks[d + 0][i] = kv.x;
      Ks[d + 1][i] = kv.y;
      Ks[d + 2][i] = kv.z;
      Ks[d + 3][i] = kv.w;
      float4 vv = *(const float4*)&Vg[(size_t)(kt + i) * DD + d];
      *(float4*)&Vs[i][d] = vv;
    }
    __syncthreads();

    float s[4][4];
#pragma unroll
    for (int r = 0; r < 4; ++r)
#pragma unroll
      for (int c = 0; c < 4; ++c) s[r][c] = 0.f;
#pragma unroll 4
    for (int d = 0; d < 64; ++d) {
      float4 qv = *(const float4*)&Qs[d][ty * 4];
      float4 kv = *(const float4*)&Ks[d][tx * 4];
      s[0][0] = fmaf(qv.x, kv.x, s[0][0]);
      s[0][1] = fmaf(qv.x, kv.y, s[0][1]);
      s[0][2] = fmaf(qv.x, kv.z, s[0][2]);
      s[0][3] = fmaf(qv.x, kv.w, s[0][3]);
      s[1][0] = fmaf(qv.y, kv.x, s[1][0]);
      s[1][1] = fmaf(qv.y, kv.y, s[1][1]);
      s[1][2] = fmaf(qv.y, kv.z, s[1][2]);
      s[1][3] = fmaf(qv.y, kv.w, s[1][3]);
      s[2][0] = fmaf(qv.z, kv.x, s[2][0]);
      s[2][1] = fmaf(qv.z, kv.y, s[2][1]);
      s[2][2] = fmaf(qv.z, kv.z, s[2][2]);
      s[2][3] = fmaf(qv.z, kv.w, s[2][3]);
      s[3][0] = fmaf(qv.w, kv.x, s[3][0]);
      s[3][1] = fmaf(qv.w, kv.y, s[3][1]);
      s[3][2] = fmaf(qv.w, kv.z, s[3][2]);
      s[3][3] = fmaf(qv.w, kv.w, s[3][3]);
    }
    bool oldest = (kt == qb - (int)WIN);
    bool newest = (kt == qb);
#pragma unroll
    for (int r = 0; r < 4; ++r) {
      int il = ty * 4 + r;
#pragma unroll
      for (int c = 0; c < 4; ++c) {
        int jl = tx * 4 + c;
        float v = s[r][c] * 0.125f;
        if (oldest && jl < il) v = -1e30f;
        if (newest && jl > il) v = -1e30f;
        s[r][c] = v;
      }
    }
#pragma unroll
    for (int r = 0; r < 4; ++r) {
      float rm = fmaxf(fmaxf(s[r][0], s[r][1]), fmaxf(s[r][2], s[r][3]));
#pragma unroll
      for (int off = 1; off < 16; off <<= 1) rm = fmaxf(rm, __shfl_xor(rm, off));
      float mn = fmaxf(m[r], rm);
      float alpha = __expf(m[r] - mn);
      m[r] = mn;
      float rs = 0.f;
#pragma unroll
      for (int c = 0; c < 4; ++c) {
        float p = __expf(s[r][c] - mn);
        s[r][c] = p;
        rs += p;
      }
#pragma unroll
      for (int off = 1; off < 16; off <<= 1) rs += __shfl_xor(rs, off);
      l[r] = l[r] * alpha + rs;
#pragma unroll
      for (int c = 0; c < 4; ++c) O[r][c] *= alpha;
    }
#pragma unroll
    for (int r = 0; r < 4; ++r)
#pragma unroll
      for (int c = 0; c < 4; ++c) Ps[tx * 4 + c][ty * 4 + r] = s[r][c];
    __syncthreads();
#pragma unroll 4
    for (int j = 0; j < 64; ++j) {
      float4 pv = *(const float4*)&Ps[j][ty * 4];
      float4 vv = *(const float4*)&Vs[j][tx * 4];
      O[0][0] = fmaf(pv.x, vv.x, O[0][0]);
      O[0][1] = fmaf(pv.x, vv.y, O[0][1]);
      O[0][2] = fmaf(pv.x, vv.z, O[0][2]);
      O[0][3] = fmaf(pv.x, vv.w, O[0][3]);
      O[1][0] = fmaf(pv.y, vv.x, O[1][0]);
      O[1][1] = fmaf(pv.y, vv.y, O[1][1]);
      O[1][2] = fmaf(pv.y, vv.z, O[1][2]);
      O[1][3] = fmaf(pv.y, vv.w, O[1][3]);
      O[2][0] = fmaf(pv.z, vv.x, O[2][0]);
      O[2][1] = fmaf(pv.z, vv.y, O[2][1]);
      O[2][2] = fmaf(pv.z, vv.z, O[2][2]);
      O[2][3] = fmaf(pv.z, vv.w, O[2][3]);
      O[3][0] = fmaf(pv.w, vv.x, O[3][0]);
      O[3][1] = fmaf(pv.w, vv.y, O[3][1]);
      O[3][2] = fmaf(pv.w, vv.z, O[3][2]);
      O[3][3] = fmaf(pv.w, vv.w, O[3][3]);
    }
  }
#pragma unroll
  for (int r = 0; r < 4; ++r) {
    float inv = 1.f / l[r];
    ushort4 res;
    res.x = f2bf(O[r][0] * inv);
    res.y = f2bf(O[r][1] * inv);
    res.z = f2bf(O[r][2] * inv);
    res.w = f2bf(O[r][3] * inv);
    int i = qb + ty * 4 + r;
    *(ushort4*)&Loutb[((size_t)(b * TT + i)) * DD + h * 64 + tx * 4] = res;
  }
}

// ---------------------------------------------------------------------------
// Scan phase A: per (bh, chunk) block computes chunk-local quantities.
//   M[t][s]   = beta_t (a_t/a_s)(k_s.k_t), strict lower
//   u_free    = (I+M)^-1 (beta .* v)                 -> UFg  [t][v] bf16
//   Z         = (I+M)^-1 diag(beta*a) K              -> Zg   [t][k] bf16
//   P         = aC I - Kt^T Z  (Kt = diag(aC/a)K)    -> Pg   [k][k'] bf16
//   Q         = Kt^T u_free                          -> Qg   [k][v] bf16
//   a (cumprod g)                                    -> Ag   [t] fp32
// Grid (16, 64) = (chunk, bh), 256 threads (4 waves).
// ---------------------------------------------------------------------------
__global__ __launch_bounds__(256) void scan_phaseA(
    const float* __restrict__ ksh, const float* __restrict__ vfull,
    const float* __restrict__ beta, const float* __restrict__ g,
    unsigned short* __restrict__ UFg, unsigned short* __restrict__ Zg,
    unsigned short* __restrict__ Pg, unsigned short* __restrict__ Qg,
    float* __restrict__ Ag) {
  __shared__ unsigned short Kc[64][72];   // K[t][k] bf16
  __shared__ unsigned short KTb[64][72];  // Kt^T[k][t] bf16
  __shared__ float Vc[64][68];            // v chunk
  __shared__ float Msv[64][68];           // M (strict lower, zeros elsewhere)
  __shared__ unsigned short UFT[64][72];  // u_free^T [v][t] bf16
  __shared__ unsigned short ZTl[64][72];  // Z^T [k'][t] bf16
  __shared__ float aArr[64], iaArr[64], bArr[64], baArr[64], sKT[64];
  __shared__ float aCs;

  int c = blockIdx.x, bh = blockIdx.y;
  int b = bh >> 4, h = bh & 15;
  int tc = c * 64;
  int tid = threadIdx.x, lane = tid & 63, wave = tid >> 6;
  int r16 = lane & 15, quad = lane >> 4;
  int m0w = wave * 16;
  size_t bhc = (size_t)bh * 16 + c;

  const float* kbase = ksh + ((size_t)b * TT) * DD + h * 64;
  const float* vbase = vfull + ((size_t)b * TT) * DD + h * 64;
  const float* bbase = beta + ((size_t)b * TT) * HH + h;
  const float* gbase = g + ((size_t)b * TT) * HH + h;

  if (tid < 64) {
    int ts = tc + tid;
    bool pad = (ts > 1022);
    float gv = pad ? 1.f : gbase[(size_t)ts * HH];
    float bv = pad ? 0.f : bbase[(size_t)ts * HH];
    float p = gv;
#pragma unroll
    for (int o = 1; o < 64; o <<= 1) {
      float t = __shfl_up(p, o);
      if (lane >= o) p *= t;
    }
    aArr[tid] = p;
    iaArr[tid] = 1.f / p;
    bArr[tid] = bv;
    baArr[tid] = bv * p;
    float aC = __shfl(p, 63);
    sKT[tid] = aC / p;
    if (tid == 0) aCs = aC;
    Ag[bhc * 64 + tid] = p;
  }
  __syncthreads();
  {  // stage K (bf16 + scaled transpose) and V (fp32)
    int r = tid >> 2, q = tid & 3;
    int ts = tc + r;
    float skt = sKT[r];
#pragma unroll
    for (int i = 0; i < 4; ++i) {
      float4 kv = *(const float4*)&kbase[(size_t)ts * DD + q * 16 + i * 4];
      ushort4 ku;
      ku.x = f2bf(kv.x); ku.y = f2bf(kv.y); ku.z = f2bf(kv.z); ku.w = f2bf(kv.w);
      *(ushort4*)&Kc[r][q * 16 + i * 4] = ku;
      KTb[q * 16 + i * 4 + 0][r] = f2bf(kv.x * skt);
      KTb[q * 16 + i * 4 + 1][r] = f2bf(kv.y * skt);
      KTb[q * 16 + i * 4 + 2][r] = f2bf(kv.z * skt);
      KTb[q * 16 + i * 4 + 3][r] = f2bf(kv.w * skt);
      float4 vv;
      if (ts <= 1022)
        vv = *(const float4*)&vbase[(size_t)(ts + 1) * DD + q * 16 + i * 4];
      else
        vv = make_float4(0.f, 0.f, 0.f, 0.f);
      *(float4*)&Vc[r][q * 16 + i * 4] = vv;
    }
  }
  __syncthreads();
  {  // KK^T -> M
    bfrag8 af0 = *(const bfrag8*)&Kc[m0w + r16][quad * 8];
    bfrag8 af1 = *(const bfrag8*)&Kc[m0w + r16][quad * 8 + 32];
    f32x4 acc1[4];
#pragma unroll
    for (int j = 0; j < 4; ++j) acc1[j] = {0.f, 0.f, 0.f, 0.f};
#pragma unroll
    for (int j = 0; j < 4; ++j) {
      bfrag8 k0 = *(const bfrag8*)&Kc[j * 16 + r16][quad * 8];
      bfrag8 k1 = *(const bfrag8*)&Kc[j * 16 + r16][quad * 8 + 32];
      acc1[j] = __builtin_amdgcn_mfma_f32_16x16x32_bf16(af0, k0, acc1[j], 0, 0, 0);
      acc1[j] = __builtin_amdgcn_mfma_f32_16x16x32_bf16(af1, k1, acc1[j], 0, 0, 0);
    }
#pragma unroll
    for (int j = 0; j < 4; ++j) {
#pragma unroll
      for (int r = 0; r < 4; ++r) {
        int row = m0w + quad * 4 + r;
        int col = j * 16 + r16;
        Msv[row][col] =
            (col < row) ? bArr[row] * aArr[row] * iaArr[col] * acc1[j][r] : 0.f;
      }
    }
  }
  __syncthreads();
  // --- triangular solves: wave0 -> u_free (col=lane=v), wave1 -> Z (col=lane=k')
  if (wave < 2) {
    float u[64];
    if (wave == 0) {
#pragma unroll
      for (int t = 0; t < 64; ++t) u[t] = bArr[t] * Vc[t][lane];
    } else {
#pragma unroll
      for (int t = 0; t < 64; ++t) u[t] = baArr[t] * bf2f(Kc[t][lane]);
    }
#pragma unroll
    for (int t = 1; t < 64; ++t) {
      float a0 = 0.f, a1 = 0.f, a2 = 0.f, a3 = 0.f;
#pragma unroll
      for (int s4 = 0; s4 * 4 < t; ++s4) {
        float4 mr = *(const float4*)&Msv[t][s4 * 4];  // zeros above diag
        a0 = fmaf(mr.x, u[s4 * 4 + 0], a0);
        a1 = fmaf(mr.y, u[s4 * 4 + 1], a1);
        a2 = fmaf(mr.z, u[s4 * 4 + 2], a2);
        a3 = fmaf(mr.w, u[s4 * 4 + 3], a3);
      }
      u[t] -= (a0 + a1) + (a2 + a3);
    }
    // write LDS transposed (for P/Q gemms) + global natural (lockstep coalesced)
    unsigned short* Tls = (wave == 0) ? &UFT[lane][0] : &ZTl[lane][0];
#pragma unroll
    for (int t2 = 0; t2 < 32; ++t2) {
      unsigned int pk = (unsigned int)f2bf(u[2 * t2]) |
                        ((unsigned int)f2bf(u[2 * t2 + 1]) << 16);
      *(unsigned int*)&Tls[2 * t2] = pk;
    }
    unsigned short* Gn = (wave == 0) ? UFg : Zg;
#pragma unroll
    for (int t = 0; t < 64; ++t) {
      Gn[(bhc * 64 + t) * 64 + lane] = f2bf(u[t]);
    }
  }
  __syncthreads();
  // --- P = aC I - Kt^T Z ; Q = Kt^T u_free ---
  {
    bfrag8 af0 = *(const bfrag8*)&KTb[m0w + r16][quad * 8];
    bfrag8 af1 = *(const bfrag8*)&KTb[m0w + r16][quad * 8 + 32];
    f32x4 accp[4], accq[4];
#pragma unroll
    for (int j = 0; j < 4; ++j) {
      accp[j] = {0.f, 0.f, 0.f, 0.f};
      accq[j] = {0.f, 0.f, 0.f, 0.f};
    }
#pragma unroll
    for (int j = 0; j < 4; ++j) {
      bfrag8 z0 = *(const bfrag8*)&ZTl[j * 16 + r16][quad * 8];
      bfrag8 z1 = *(const bfrag8*)&ZTl[j * 16 + r16][quad * 8 + 32];
      accp[j] = __builtin_amdgcn_mfma_f32_16x16x32_bf16(af0, z0, accp[j], 0, 0, 0);
      accp[j] = __builtin_amdgcn_mfma_f32_16x16x32_bf16(af1, z1, accp[j], 0, 0, 0);
      bfrag8 u0 = *(const bfrag8*)&UFT[j * 16 + r16][quad * 8];
      bfrag8 u1 = *(const bfrag8*)&UFT[j * 16 + r16][quad * 8 + 32];
      accq[j] = __builtin_amdgcn_mfma_f32_16x16x32_bf16(af0, u0, accq[j], 0, 0, 0);
      accq[j] = __builtin_amdgcn_mfma_f32_16x16x32_bf16(af1, u1, accq[j], 0, 0, 0);
    }
    float aC = aCs;
#pragma unroll
    for (int j = 0; j < 4; ++j) {
#pragma unroll
      for (int r = 0; r < 4; ++r) {
        int row = m0w + quad * 4 + r;
        int col = j * 16 + r16;
        float pv = ((row == col) ? aC : 0.f) - accp[j][r];
        Pg[bhc * 4096 + (size_t)row * 64 + col] = f2bf(pv);
        Qg[bhc * 4096 + (size_t)row * 64 + col] = f2bf(accq[j][r]);
      }
    }
  }
}

// ---------------------------------------------------------------------------
// Scan phase B: serial state propagation. Grid 64 (bh), 256 threads.
//   S_{c+1} = P_c S_c + Q_c. Exports S_c^T (bf16) per chunk + final Sf fp32.
// ---------------------------------------------------------------------------
__global__ __launch_bounds__(256) void scan_phaseB(
    const float* __restrict__ S0, const unsigned short* __restrict__ Pg,
    const unsigned short* __restrict__ Qg, unsigned short* __restrict__ SinTg,
    float* __restrict__ Sf, unsigned short* __restrict__ gdnb) {
  __shared__ unsigned short STb[64][72];  // S^T [v][k] bf16
  __shared__ unsigned short Pl[64][72];   // P [k][k'] bf16
  int bh = blockIdx.x;
  int b = bh >> 4, h = bh & 15;
  int tid = threadIdx.x, lane = tid & 63, wave = tid >> 6;
  int r16 = lane & 15, quad = lane >> 4;
  int m0w = wave * 16;
  int rr = tid >> 2, qq = tid & 3;

  // init STb from S0; zero gdn row t=0
  {
    const float* s0p = S0 + (size_t)bh * 4096;
#pragma unroll
    for (int i = 0; i < 4; ++i) {
      float4 sv = *(const float4*)&s0p[rr * 64 + qq * 16 + i * 4];
      STb[qq * 16 + i * 4 + 0][rr] = f2bf(sv.x);
      STb[qq * 16 + i * 4 + 1][rr] = f2bf(sv.y);
      STb[qq * 16 + i * 4 + 2][rr] = f2bf(sv.z);
      STb[qq * 16 + i * 4 + 3][rr] = f2bf(sv.w);
    }
    if (tid < 64) gdnb[((size_t)b * TT) * DD + h * 64 + tid] = 0;
  }

  for (int c = 0; c < 16; ++c) {
    size_t bhc = (size_t)bh * 16 + c;
    __syncthreads();  // STb stable (writes from prev iter done)
    // export S_c^T; load P_c
    {
      uint4 s0v = *(const uint4*)&STb[rr][qq * 16];
      uint4 s1v = *(const uint4*)&STb[rr][qq * 16 + 8];
      *(uint4*)&SinTg[bhc * 4096 + (size_t)rr * 64 + qq * 16] = s0v;
      *(uint4*)&SinTg[bhc * 4096 + (size_t)rr * 64 + qq * 16 + 8] = s1v;
      uint4 p0 = *(const uint4*)&Pg[bhc * 4096 + (size_t)rr * 64 + qq * 16];
      uint4 p1 = *(const uint4*)&Pg[bhc * 4096 + (size_t)rr * 64 + qq * 16 + 8];
      *(uint4*)&Pl[rr][qq * 16] = p0;
      *(uint4*)&Pl[rr][qq * 16 + 8] = p1;
    }
    __syncthreads();  // Pl ready
    f32x4 acc[4];
#pragma unroll
    for (int j = 0; j < 4; ++j) acc[j] = {0.f, 0.f, 0.f, 0.f};
    {
      bfrag8 af0 = *(const bfrag8*)&Pl[m0w + r16][quad * 8];
      bfrag8 af1 = *(const bfrag8*)&Pl[m0w + r16][quad * 8 + 32];
#pragma unroll
      for (int j = 0; j < 4; ++j) {
        bfrag8 s0v = *(const bfrag8*)&STb[j * 16 + r16][quad * 8];
        bfrag8 s1v = *(const bfrag8*)&STb[j * 16 + r16][quad * 8 + 32];
        acc[j] = __builtin_amdgcn_mfma_f32_16x16x32_bf16(af0, s0v, acc[j], 0, 0, 0);
        acc[j] = __builtin_amdgcn_mfma_f32_16x16x32_bf16(af1, s1v, acc[j], 0, 0, 0);
      }
    }
    float snew[4][4];
#pragma unroll
    for (int j = 0; j < 4; ++j) {
#pragma unroll
      for (int r = 0; r < 4; ++r) {
        int row = m0w + quad * 4 + r;
        int col = j * 16 + r16;
        snew[j][r] = acc[j][r] +
                     bf2f(Qg[bhc * 4096 + (size_t)row * 64 + col]);
      }
    }
    __syncthreads();  // all STb reads done
#pragma unroll
    for (int j = 0; j < 4; ++j) {
#pragma unroll
      for (int r = 0; r < 4; ++r) {
        int row = m0w + quad * 4 + r;
        int col = j * 16 + r16;
        STb[col][row] = f2bf(snew[j][r]);
        if (c == 15) Sf[(size_t)bh * 4096 + (size_t)row * 64 + col] = snew[j][r];
      }
    }
  }
}

// ---------------------------------------------------------------------------
// Scan phase C: per (bh, chunk) output computation.
//   W = (a_t/a_s) KK^T (lower incl diag); U = u_free - Z S_in;
//   O = diag(a) K S_in + W U  -> gdn[t+1]. Grid (16,64), 256 threads.
// ---------------------------------------------------------------------------
__global__ __launch_bounds__(256) void scan_phaseC(
    const float* __restrict__ ksh, const unsigned short* __restrict__ UFg,
    const unsigned short* __restrict__ Zg,
    const unsigned short* __restrict__ SinTg, const float* __restrict__ Ag,
    unsigned short* __restrict__ gdnb) {
  __shared__ unsigned short Kc[64][72];   // K[t][k]
  __shared__ unsigned short SvT[64][72];  // S_in^T [v][k]
  __shared__ unsigned short Zl[64][72];   // Z [t][k]
  __shared__ unsigned short Ufl[64][72];  // u_free [t][v]
  __shared__ unsigned short Wl[64][72];   // W [t][s]
  __shared__ unsigned short UTl[64][72];  // U^T [v][t]
  __shared__ float aA[64], iaA[64];

  int c = blockIdx.x, bh = blockIdx.y;
  int b = bh >> 4, h = bh & 15;
  int tc = c * 64;
  int tid = threadIdx.x, lane = tid & 63, wave = tid >> 6;
  int r16 = lane & 15, quad = lane >> 4;
  int m0w = wave * 16;
  size_t bhc = (size_t)bh * 16 + c;
  const float* kbase = ksh + ((size_t)b * TT) * DD + h * 64;

  if (tid < 64) {
    float av = Ag[bhc * 64 + tid];
    aA[tid] = av;
    iaA[tid] = 1.f / av;
  }
  {  // stage
    int r = tid >> 2, q = tid & 3;
    int ts = tc + r;
#pragma unroll
    for (int i = 0; i < 4; ++i) {
      float4 kv = *(const float4*)&kbase[(size_t)ts * DD + q * 16 + i * 4];
      ushort4 ku;
      ku.x = f2bf(kv.x); ku.y = f2bf(kv.y); ku.z = f2bf(kv.z); ku.w = f2bf(kv.w);
      *(ushort4*)&Kc[r][q * 16 + i * 4] = ku;
    }
    uint4 sv0 = *(const uint4*)&SinTg[bhc * 4096 + (size_t)r * 64 + q * 16];
    uint4 sv1 = *(const uint4*)&SinTg[bhc * 4096 + (size_t)r * 64 + q * 16 + 8];
    *(uint4*)&SvT[r][q * 16] = sv0;
    *(uint4*)&SvT[r][q * 16 + 8] = sv1;
    uint4 zv0 = *(const uint4*)&Zg[(bhc * 64 + r) * 64 + q * 16];
    uint4 zv1 = *(const uint4*)&Zg[(bhc * 64 + r) * 64 + q * 16 + 8];
    *(uint4*)&Zl[r][q * 16] = zv0;
    *(uint4*)&Zl[r][q * 16 + 8] = zv1;
    uint4 uv0 = *(const uint4*)&UFg[(bhc * 64 + r) * 64 + q * 16];
    uint4 uv1 = *(const uint4*)&UFg[(bhc * 64 + r) * 64 + q * 16 + 8];
    *(uint4*)&Ufl[r][q * 16] = uv0;
    *(uint4*)&Ufl[r][q * 16 + 8] = uv1;
  }
  __syncthreads();
  float op[4][4];
  {  // pass 1: KK^T (acc1), G1 = K S_in (acc3), ZS = Z S_in (acc2)
    bfrag8 af0 = *(const bfrag8*)&Kc[m0w + r16][quad * 8];
    bfrag8 af1 = *(const bfrag8*)&Kc[m0w + r16][quad * 8 + 32];
    bfrag8 zf0 = *(const bfrag8*)&Zl[m0w + r16][quad * 8];
    bfrag8 zf1 = *(const bfrag8*)&Zl[m0w + r16][quad * 8 + 32];
    f32x4 acc1[4], acc2[4], acc3[4];
#pragma unroll
    for (int j = 0; j < 4; ++j) {
      acc1[j] = {0.f, 0.f, 0.f, 0.f};
      acc2[j] = {0.f, 0.f, 0.f, 0.f};
      acc3[j] = {0.f, 0.f, 0.f, 0.f};
    }
#pragma unroll
    for (int j = 0; j < 4; ++j) {
      bfrag8 k0 = *(const bfrag8*)&Kc[j * 16 + r16][quad * 8];
      bfrag8 k1 = *(const bfrag8*)&Kc[j * 16 + r16][quad * 8 + 32];
      acc1[j] = __builtin_amdgcn_mfma_f32_16x16x32_bf16(af0, k0, acc1[j], 0, 0, 0);
      acc1[j] = __builtin_amdgcn_mfma_f32_16x16x32_bf16(af1, k1, acc1[j], 0, 0, 0);
      bfrag8 s0 = *(const bfrag8*)&SvT[j * 16 + r16][quad * 8];
      bfrag8 s1 = *(const bfrag8*)&SvT[j * 16 + r16][quad * 8 + 32];
      acc3[j] = __builtin_amdgcn_mfma_f32_16x16x32_bf16(af0, s0, acc3[j], 0, 0, 0);
      acc3[j] = __builtin_amdgcn_mfma_f32_16x16x32_bf16(af1, s1, acc3[j], 0, 0, 0);
      acc2[j] = __builtin_amdgcn_mfma_f32_16x16x32_bf16(zf0, s0, acc2[j], 0, 0, 0);
      acc2[j] = __builtin_amdgcn_mfma_f32_16x16x32_bf16(zf1, s1, acc2[j], 0, 0, 0);
    }
#pragma unroll
    for (int j = 0; j < 4; ++j) {
#pragma unroll
      for (int r = 0; r < 4; ++r) {
        int row = m0w + quad * 4 + r;
        int col = j * 16 + r16;
        Wl[row][col] = (col <= row)
                           ? f2bf(aA[row] * iaA[col] * acc1[j][r])
                           : (unsigned short)0;
        float uval = bf2f(Ufl[row][col]) - acc2[j][r];
        UTl[col][row] = f2bf(uval);
        op[j][r] = aA[row] * acc3[j][r];
      }
    }
  }
  __syncthreads();
  {  // pass 2: O = op + W U
    bfrag8 wf0 = *(const bfrag8*)&Wl[m0w + r16][quad * 8];
    bfrag8 wf1 = *(const bfrag8*)&Wl[m0w + r16][quad * 8 + 32];
    f32x4 acc4[4];
#pragma unroll
    for (int j = 0; j < 4; ++j) acc4[j] = {0.f, 0.f, 0.f, 0.f};
#pragma unroll
    for (int j = 0; j < 4; ++j) {
      bfrag8 u0 = *(const bfrag8*)&UTl[j * 16 + r16][quad * 8];
      bfrag8 u1 = *(const bfrag8*)&UTl[j * 16 + r16][quad * 8 + 32];
      acc4[j] = __builtin_amdgcn_mfma_f32_16x16x32_bf16(wf0, u0, acc4[j], 0, 0, 0);
      acc4[j] = __builtin_amdgcn_mfma_f32_16x16x32_bf16(wf1, u1, acc4[j], 0, 0, 0);
    }
#pragma unroll
    for (int j = 0; j < 4; ++j) {
#pragma unroll
      for (int r = 0; r < 4; ++r) {
        int row = m0w + quad * 4 + r;
        int col = j * 16 + r16;
        int ts = tc + row;
        if (ts < 1023) {
          gdnb[((size_t)b * TT + ts + 1) * DD + h * 64 + col] =
              f2bf(op[j][r] + acc4[j][r]);
        }
      }
    }
  }
}

// ---------------------------------------------------------------------------
// retrieved[b,t,h,:] = k_shared[b,t,h,:] @ Sf[b,h,:,:]. bf16 out.
// ---------------------------------------------------------------------------
__global__ __launch_bounds__(256) void retrieve_kernel(
    const float* __restrict__ ksh, const float* __restrict__ Sf,
    unsigned short* __restrict__ retrb) {
  int w = blockIdx.x * 4 + (threadIdx.x >> 6);  // (b*T+t)*H + h
  int lane = threadIdx.x & 63;                  // v index
  float kl = ksh[(size_t)w * 64 + lane];
  int bt = w >> 4;
  int b = bt >> 10;
  int bh = b * 16 + (w & 15);
  const float* sfp = Sf + (size_t)bh * 4096;
  float acc = 0.f;
#pragma unroll
  for (int k = 0; k < 64; ++k) {
    float kk = __shfl(kl, k);
    acc = fmaf(kk, sfp[k * 64 + lane], acc);
  }
  retrb[(size_t)bt * DD + (w & 15) * 64 + lane] = f2bf(acc);
}

// ---------------------------------------------------------------------------
extern "C" void kernel_launch(void* const* d_in, const int* in_sizes, int n_in,
                              void* d_out, int out_size, void* d_ws,
                              size_t ws_size, hipStream_t stream) {
  (void)in_sizes; (void)n_in; (void)out_size; (void)ws_size;
  const float* x       = (const float*)d_in[0];
  const float* S0      = (const float*)d_in[1];
  const float* W_k     = (const float*)d_in[2];
  const float* W_v     = (const float*)d_in[3];
  const float* W_gdn_o = (const float*)d_in[4];
  const float* W_beta  = (const float*)d_in[5];
  const float* b_beta  = (const float*)d_in[6];
  const float* W_g     = (const float*)d_in[7];
  const float* b_g     = (const float*)d_in[8];
  const float* W_lq    = (const float*)d_in[9];
  const float* W_lk    = (const float*)d_in[10];
  const float* W_lv    = (const float*)d_in[11];
  const float* W_swa_o = (const float*)d_in[12];
  const float* W_ret_o = (const float*)d_in[13];
  const float* W_gate  = (const float*)d_in[14];
  const float* b_gate  = (const float*)d_in[15];
  const float* norm_w  = (const float*)d_in[16];
  const int*   ids     = (const int*)d_in[17];
  float* out = (float*)d_out;

  char* ws = (char*)d_ws;
  size_t off = 0;
  auto allocf = [&](size_t nfloats) {
    float* p = (float*)(ws + off);
    off += nfloats * sizeof(float);
    return p;
  };
  auto allocu = [&](size_t nshorts) {
    unsigned short* p = (unsigned short*)(ws + off);
    off += nshorts * sizeof(unsigned short);
    return p;
  };
  const size_t BTD = (size_t)BB * TT * DD;  // 4M
  unsigned short* XNb = allocu(BTD);
  float* KSH  = allocf(BTD);
  float* VF   = allocf(BTD);
  float* Qb   = allocf(BTD);
  float* KLb  = allocf(BTD);
  float* VLb  = allocf(BTD);
  unsigned short* WTk   = allocu(1024 * 1024);
  unsigned short* WTv   = allocu(1024 * 1024);
  unsigned short* WTlq  = allocu(1024 * 1024);
  unsigned short* WTlk  = allocu(1024 * 1024);
  unsigned short* WTlv  = allocu(1024 * 1024);
  unsigned short* WTgdn = allocu(1024 * 1024);
  unsigned short* WTswa = allocu(1024 * 1024);
  unsigned short* WTret = allocu(1024 * 1024);
  float* BETA = allocf((size_t)BB * TT * HH);
  float* Gg   = allocf((size_t)BB * TT * HH);
  float* MG   = allocf((size_t)BB * TT);
  float* SF   = allocf((size_t)BB * HH * KK * VV);
  // scan 3-phase buffers (1024 = bh*16+c blocks of 64x64)
  const size_t CH = (size_t)BB * HH * 16 * 64 * 64;  // 4M elements
  unsigned short* UFg   = allocu(CH);
  unsigned short* Zg    = allocu(CH);
  unsigned short* Pg    = allocu(CH);
  unsigned short* Qg    = allocu(CH);
  unsigned short* SinTg = allocu(CH);
  float* Ag = allocf((size_t)BB * HH * 16 * 64);
  // Reuse (ordering guarantees no read-write overlap):
  unsigned short* GDNb   = XNb;                   // after smallproj+5 gemms
  unsigned short* LOCALb = (unsigned short*)VF;   // after scan phaseA consumed VF
  unsigned short* RETRb  = (unsigned short*)Qb;   // after attn consumed Qb

  const int M = BB * TT;  // 4096
  dim3 gemmGrid(DD / 128, M / 128);

  rmsnorm_kernel<<<M, 256, 0, stream>>>(x, norm_w, XNb);

  convert_wt_kernel<<<dim3(16, 16, 8), 256, 0, stream>>>(
      W_k, W_v, W_lq, W_lk, W_lv, W_gdn_o, W_swa_o, W_ret_o,
      WTk, WTv, WTlq, WTlk, WTlv, WTgdn, WTswa, WTret);

  gemm_mfma_kernel<<<gemmGrid, 256, 0, stream>>>(XNb, WTk, KSH, nullptr, nullptr, 1.f, M, DD, DD);
  gemm_mfma_kernel<<<gemmGrid, 256, 0, stream>>>(XNb, WTv, VF, nullptr, nullptr, 1.f, M, DD, DD);
  gemm_mfma_kernel<<<gemmGrid, 256, 0, stream>>>(XNb, WTlq, Qb, nullptr, nullptr, 1.f, M, DD, DD);
  gemm_mfma_kernel<<<gemmGrid, 256, 0, stream>>>(XNb, WTlk, KLb, nullptr, nullptr, 1.f, M, DD, DD);
  gemm_mfma_kernel<<<gemmGrid, 256, 0, stream>>>(XNb, WTlv, VLb, nullptr, nullptr, 1.f, M, DD, DD);

  knorm_kernel<<<(BB * TT * HH) / 4, 256, 0, stream>>>(KSH);
  smallproj_kernel<<<M, 256, 0, stream>>>(XNb, W_beta, b_beta, W_g, b_g, W_gate,
                                          b_gate, ids, BETA, Gg, MG);

  scan_phaseA<<<dim3(16, BB * HH), 256, 0, stream>>>(KSH, VF, BETA, Gg, UFg, Zg,
                                                     Pg, Qg, Ag);
  scan_phaseB<<<BB * HH, 256, 0, stream>>>(S0, Pg, Qg, SinTg, SF, GDNb);
  scan_phaseC<<<dim3(16, BB * HH), 256, 0, stream>>>(KSH, UFg, Zg, SinTg, Ag,
                                                     GDNb);

  attn_tile_kernel<<<dim3(TT / 64, BB * HH), 256, 0, stream>>>(Qb, KLb, VLb, LOCALb);

  retrieve_kernel<<<(BB * TT * HH) / 4, 256, 0, stream>>>(KSH, SF, RETRb);

  gemm_mfma_kernel<<<gemmGrid, 256, 0, stream>>>(GDNb, WTgdn, out, x, nullptr, 1.f, M, DD, DD);
  gemm_mfma_kernel<<<gemmGrid, 256, 0, stream>>>(LOCALb, WTswa, out, out, nullptr, 0.3f, M, DD, DD);
  gemm_mfma_kernel<<<gemmGrid, 256, 0, stream>>>(RETRb, WTret, out, out, MG, 1.f, M, DD, DD);
}

// Round 6
// 494.189 us; speedup vs baseline: 6.5345x; 1.3873x over previous
//
#include <hip/hip_runtime.h>
#include <hip/hip_bf16.h>

// Problem constants
#define BB 4
#define TT 1024
#define DD 1024
#define HH 16
#define KK 64
#define VV 64
#define WIN 256
#define MARKER_ID 50251
#define PS32 2048  // fp32 proj buffer row stride (KSH | VF)
#define PSB 3072   // bf16 proj / epilogue-cat row stride

typedef short bfrag8 __attribute__((ext_vector_type(8)));
typedef float f32x4 __attribute__((ext_vector_type(4)));

static __device__ __forceinline__ unsigned short f2bf(float f) {
  __hip_bfloat16 h = __float2bfloat16(f);
  union { __hip_bfloat16 h; unsigned short u; } cv;
  cv.h = h;
  return cv.u;
}
static __device__ __forceinline__ float bf2f(unsigned short u) {
  union { unsigned int i; float f; } c;
  c.i = ((unsigned int)u) << 16;
  return c.f;
}

// ---------------------------------------------------------------------------
// RMSNorm: xnb (bf16) = x / sqrt(mean(x^2)+eps) * norm_w. One block per row.
// ---------------------------------------------------------------------------
__global__ __launch_bounds__(256) void rmsnorm_kernel(
    const float* __restrict__ x, const float* __restrict__ nw,
    unsigned short* __restrict__ xnb) {
  int row = blockIdx.x;
  int tid = threadIdx.x;
  const float4* xr = (const float4*)(x + (size_t)row * DD);
  float4 v = xr[tid];
  float ss = v.x * v.x + v.y * v.y + v.z * v.z + v.w * v.w;
#pragma unroll
  for (int off = 32; off; off >>= 1) ss += __shfl_xor(ss, off);
  __shared__ float red[4];
  int wid = tid >> 6;
  if ((tid & 63) == 0) red[wid] = ss;
  __syncthreads();
  float tot = red[0] + red[1] + red[2] + red[3];
  float inv = 1.0f / sqrtf(tot * (1.0f / DD) + 1e-6f);
  const float4* wr = (const float4*)nw;
  float4 wv = wr[tid];
  ushort4 o;
  o.x = f2bf(v.x * inv * wv.x);
  o.y = f2bf(v.y * inv * wv.y);
  o.z = f2bf(v.z * inv * wv.z);
  o.w = f2bf(v.w * inv * wv.w);
  *(ushort4*)&xnb[(size_t)row * DD + tid * 4] = o;
}

// ---------------------------------------------------------------------------
// Convert + transpose 1024x1024 weights fp32 [K][N] -> bf16 [N][K] into
// concatenated buffers (per-weight dst base, row stride, scale).
// ---------------------------------------------------------------------------
__global__ __launch_bounds__(256) void convert_wt_kernel(
    const float* W0, const float* W1, const float* W2, const float* W3,
    const float* W4, const float* W5, const float* W6, const float* W7,
    unsigned short* C5, unsigned short* C3) {
  const float* W;
  unsigned short* T;
  int stride;
  float scale = 1.f;
  switch (blockIdx.z) {
    case 0: W = W0; T = C5 + 0 * 1024 * 1024; stride = 1024; break;
    case 1: W = W1; T = C5 + 1 * 1024 * 1024; stride = 1024; break;
    case 2: W = W2; T = C5 + 2 * 1024 * 1024; stride = 1024; break;
    case 3: W = W3; T = C5 + 3 * 1024 * 1024; stride = 1024; break;
    case 4: W = W4; T = C5 + 4 * 1024 * 1024; stride = 1024; break;
    case 5: W = W5; T = C3 + 0; stride = PSB; break;
    case 6: W = W6; T = C3 + 1024; stride = PSB; scale = 0.3f; break;
    default: W = W7; T = C3 + 2048; stride = PSB; break;
  }
  __shared__ float Ts[64][68];
  int tid = threadIdx.x;
  int n0 = blockIdx.x * 64, k0 = blockIdx.y * 64;
#pragma unroll
  for (int p = 0; p < 4; ++p) {
    int e = p * 256 + tid;
    int k = e >> 4, nq = e & 15;
    float4 w = *(const float4*)&W[(size_t)(k0 + k) * 1024 + n0 + nq * 4];
    Ts[nq * 4 + 0][k] = w.x;
    Ts[nq * 4 + 1][k] = w.y;
    Ts[nq * 4 + 2][k] = w.z;
    Ts[nq * 4 + 3][k] = w.w;
  }
  __syncthreads();
#pragma unroll
  for (int p = 0; p < 4; ++p) {
    int e = p * 256 + tid;
    int n = e >> 4, kq = e & 15;
    float4 v = *(const float4*)&Ts[n][kq * 4];
    ushort4 u;
    u.x = f2bf(v.x * scale);
    u.y = f2bf(v.y * scale);
    u.z = f2bf(v.z * scale);
    u.w = f2bf(v.w * scale);
    *(ushort4*)&T[(size_t)(n0 + n) * stride + k0 + kq * 4] = u;
  }
}

// ---------------------------------------------------------------------------
// bf16 MFMA GEMM (128x128 tile, BK=32) fp32 out, with add. For the fused
// epilogue: C = addp + A[M][K] * BT[N][K]^T.
// ---------------------------------------------------------------------------
__global__ __launch_bounds__(256) void gemm_mfma_kernel(
    const unsigned short* __restrict__ A, const unsigned short* __restrict__ BT,
    float* __restrict__ C, const float* __restrict__ addp, int M, int N,
    int K) {
  __shared__ unsigned short As[128][40];
  __shared__ unsigned short Bs[128][40];
  int tid = threadIdx.x;
  int n0 = blockIdx.x * 128, m0 = blockIdx.y * 128;
  int wave = tid >> 6, lane = tid & 63;
  int wm = (wave & 1) * 64, wn = (wave >> 1) * 64;
  int r16 = lane & 15, quad = lane >> 4;
  int srow = tid >> 2, scq = tid & 3;

  f32x4 acc[4][4];
#pragma unroll
  for (int i = 0; i < 4; ++i)
#pragma unroll
    for (int j = 0; j < 4; ++j) acc[i][j] = {0.f, 0.f, 0.f, 0.f};

  for (int kt = 0; kt < K; kt += 32) {
    uint4 a0 = *(const uint4*)&A[(size_t)(m0 + srow) * K + kt + scq * 8];
    uint4 a1 = *(const uint4*)&A[(size_t)(m0 + 64 + srow) * K + kt + scq * 8];
    uint4 b0 = *(const uint4*)&BT[(size_t)(n0 + srow) * K + kt + scq * 8];
    uint4 b1 = *(const uint4*)&BT[(size_t)(n0 + 64 + srow) * K + kt + scq * 8];
    __syncthreads();
    *(uint4*)&As[srow][scq * 8] = a0;
    *(uint4*)&As[64 + srow][scq * 8] = a1;
    *(uint4*)&Bs[srow][scq * 8] = b0;
    *(uint4*)&Bs[64 + srow][scq * 8] = b1;
    __syncthreads();
    bfrag8 af[4], bq[4];
#pragma unroll
    for (int i = 0; i < 4; ++i) {
      af[i] = *(const bfrag8*)&As[wm + i * 16 + r16][quad * 8];
      bq[i] = *(const bfrag8*)&Bs[wn + i * 16 + r16][quad * 8];
    }
#pragma unroll
    for (int i = 0; i < 4; ++i)
#pragma unroll
      for (int j = 0; j < 4; ++j)
        acc[i][j] = __builtin_amdgcn_mfma_f32_16x16x32_bf16(af[i], bq[j],
                                                            acc[i][j], 0, 0, 0);
  }
#pragma unroll
  for (int i = 0; i < 4; ++i) {
#pragma unroll
    for (int r = 0; r < 4; ++r) {
      int row = m0 + wm + i * 16 + quad * 4 + r;
#pragma unroll
      for (int j = 0; j < 4; ++j) {
        int col = n0 + wn + j * 16 + r16;
        size_t idx = (size_t)row * N + col;
        float base = addp ? addp[idx] : 0.f;
        C[idx] = base + acc[i][j][r];
      }
    }
  }
}

// ---------------------------------------------------------------------------
// Fused projection GEMM: A=xn [4096][1024] bf16, BT=WTcat5 [5120][1024].
// Output: cols 0..2047 fp32 -> P32 (KSH|VF, stride 2048);
//         cols 2048..5119 bf16 -> PB (Q|KL|VL, stride 3072).
// ---------------------------------------------------------------------------
__global__ __launch_bounds__(256) void gemm_proj_kernel(
    const unsigned short* __restrict__ A, const unsigned short* __restrict__ BT,
    float* __restrict__ P32, unsigned short* __restrict__ PB) {
  const int K = 1024;
  __shared__ unsigned short As[128][40];
  __shared__ unsigned short Bs[128][40];
  int tid = threadIdx.x;
  int n0 = blockIdx.x * 128, m0 = blockIdx.y * 128;
  int wave = tid >> 6, lane = tid & 63;
  int wm = (wave & 1) * 64, wn = (wave >> 1) * 64;
  int r16 = lane & 15, quad = lane >> 4;
  int srow = tid >> 2, scq = tid & 3;

  f32x4 acc[4][4];
#pragma unroll
  for (int i = 0; i < 4; ++i)
#pragma unroll
    for (int j = 0; j < 4; ++j) acc[i][j] = {0.f, 0.f, 0.f, 0.f};

  for (int kt = 0; kt < K; kt += 32) {
    uint4 a0 = *(const uint4*)&A[(size_t)(m0 + srow) * K + kt + scq * 8];
    uint4 a1 = *(const uint4*)&A[(size_t)(m0 + 64 + srow) * K + kt + scq * 8];
    uint4 b0 = *(const uint4*)&BT[(size_t)(n0 + srow) * K + kt + scq * 8];
    uint4 b1 = *(const uint4*)&BT[(size_t)(n0 + 64 + srow) * K + kt + scq * 8];
    __syncthreads();
    *(uint4*)&As[srow][scq * 8] = a0;
    *(uint4*)&As[64 + srow][scq * 8] = a1;
    *(uint4*)&Bs[srow][scq * 8] = b0;
    *(uint4*)&Bs[64 + srow][scq * 8] = b1;
    __syncthreads();
    bfrag8 af[4], bq[4];
#pragma unroll
    for (int i = 0; i < 4; ++i) {
      af[i] = *(const bfrag8*)&As[wm + i * 16 + r16][quad * 8];
      bq[i] = *(const bfrag8*)&Bs[wn + i * 16 + r16][quad * 8];
    }
#pragma unroll
    for (int i = 0; i < 4; ++i)
#pragma unroll
      for (int j = 0; j < 4; ++j)
        acc[i][j] = __builtin_amdgcn_mfma_f32_16x16x32_bf16(af[i], bq[j],
                                                            acc[i][j], 0, 0, 0);
  }
  bool isf32 = (n0 < 2048);  // block-uniform (128-col blocks)
#pragma unroll
  for (int i = 0; i < 4; ++i) {
#pragma unroll
    for (int r = 0; r < 4; ++r) {
      int row = m0 + wm + i * 16 + quad * 4 + r;
#pragma unroll
      for (int j = 0; j < 4; ++j) {
        int col = n0 + wn + j * 16 + r16;
        if (isf32)
          P32[(size_t)row * PS32 + col] = acc[i][j][r];
        else
          PB[(size_t)row * PSB + col - 2048] = f2bf(acc[i][j][r]);
      }
    }
  }
}

// ---------------------------------------------------------------------------
// L2-normalize rows of 64 (k_shared) inside P32 (stride 2048, cols 0..1023).
// ---------------------------------------------------------------------------
__global__ __launch_bounds__(256) void knorm_kernel(float* __restrict__ p32) {
  int w = blockIdx.x * 4 + (threadIdx.x >> 6);  // (b*T+t)*H + h
  int lane = threadIdx.x & 63;
  size_t addr = (size_t)(w >> 4) * PS32 + (w & 15) * 64 + lane;
  float v = p32[addr];
  float ss = v * v;
#pragma unroll
  for (int off = 32; off; off >>= 1) ss += __shfl_xor(ss, off);
  float n = sqrtf(ss);
  n = fmaxf(n, 1e-12f);
  p32[addr] = v / n;
}

// ---------------------------------------------------------------------------
// Small projections: beta, g, gate (+ marker mask, head-mean of gate).
// ---------------------------------------------------------------------------
__global__ __launch_bounds__(256) void smallproj_kernel(
    const unsigned short* __restrict__ xnb, const float* __restrict__ Wb,
    const float* __restrict__ bb, const float* __restrict__ Wg,
    const float* __restrict__ bg, const float* __restrict__ Wgate,
    const float* __restrict__ bgate, const int* __restrict__ ids,
    float* __restrict__ beta, float* __restrict__ g, float* __restrict__ mg) {
  int row = blockIdx.x;
  int tid = threadIdx.x;
  __shared__ float xr[DD];
  __shared__ float gl[16];
  ushort4 u = *(const ushort4*)&xnb[(size_t)row * DD + tid * 4];
  xr[tid * 4 + 0] = bf2f(u.x);
  xr[tid * 4 + 1] = bf2f(u.y);
  xr[tid * 4 + 2] = bf2f(u.z);
  xr[tid * 4 + 3] = bf2f(u.w);
  __syncthreads();
  if (tid < 48) {
    int h = tid & 15;
    const float* W = (tid < 16) ? Wb : ((tid < 32) ? Wg : Wgate);
    float acc = 0.f;
    for (int d = 0; d < DD; ++d) acc = fmaf(xr[d], W[d * 16 + h], acc);
    if (tid < 16) {
      float s = 1.f / (1.f + __expf(-(acc + bb[h])));
      float mk = (ids[row] == MARKER_ID) ? 1.0f : 0.1f;
      beta[(size_t)row * 16 + h] = s * mk;
    } else if (tid < 32) {
      g[(size_t)row * 16 + h] = 1.f / (1.f + __expf(-(acc + bg[h])));
    } else {
      gl[h] = 1.f / (1.f + __expf(-(acc + bgate[h])));
    }
  }
  __syncthreads();
  if (tid == 0) {
    float s = 0.f;
#pragma unroll
    for (int h = 0; h < 16; ++h) s += gl[h];
    mg[row] = s * (1.f / 16.f);
  }
}

// ---------------------------------------------------------------------------
// MFMA flash sliding-window attention. bf16 Q/K/V from PB (stride 3072,
// Q at col 0, KL at 1024, VL at 2048). Output bf16 -> ACAT col 1024.
// Grid (T/64, B*H), 256 threads = 4 waves; wave owns 16 query rows.
// ---------------------------------------------------------------------------
__global__ __launch_bounds__(256) void attn_mfma_kernel(
    const unsigned short* __restrict__ PB, unsigned short* __restrict__ ACAT) {
  __shared__ unsigned short Qs[64][72];
  __shared__ unsigned short Ks[64][72];
  __shared__ unsigned short Vt[64][72];  // V transposed [vdim][key]
  __shared__ unsigned short Ps[64][72];  // P [query][key]
  int qb = blockIdx.x * 64;
  int bh = blockIdx.y;
  int h = bh & 15, b = bh >> 4;
  int tid = threadIdx.x, lane = tid & 63, wave = tid >> 6;
  int r16 = lane & 15, quad = lane >> 4;
  int m0w = wave * 16;
  const unsigned short* Qg = PB + (size_t)b * TT * PSB + h * 64;
  const unsigned short* Kg = Qg + 1024;
  const unsigned short* Vg = Qg + 2048;
  int sr = tid >> 2, sq = tid & 3;
  {
    *(uint4*)&Qs[sr][sq * 16] =
        *(const uint4*)&Qg[(size_t)(qb + sr) * PSB + sq * 16];
    *(uint4*)&Qs[sr][sq * 16 + 8] =
        *(const uint4*)&Qg[(size_t)(qb + sr) * PSB + sq * 16 + 8];
  }
  float m[4], l[4];
  f32x4 o[4];
#pragma unroll
  for (int r = 0; r < 4; ++r) {
    m[r] = -1e30f;
    l[r] = 0.f;
    o[r] = {0.f, 0.f, 0.f, 0.f};
  }
  int kt0 = qb - (int)WIN;
  if (kt0 < 0) kt0 = 0;

  for (int kt = kt0; kt <= qb; kt += 64) {
    __syncthreads();  // prev tile reads done (also covers Qs staging)
    {
      *(uint4*)&Ks[sr][sq * 16] =
          *(const uint4*)&Kg[(size_t)(kt + sr) * PSB + sq * 16];
      *(uint4*)&Ks[sr][sq * 16 + 8] =
          *(const uint4*)&Kg[(size_t)(kt + sr) * PSB + sq * 16 + 8];
      union { uint4 u4[2]; unsigned short s[16]; } vv;
      vv.u4[0] = *(const uint4*)&Vg[(size_t)(kt + sr) * PSB + sq * 16];
      vv.u4[1] = *(const uint4*)&Vg[(size_t)(kt + sr) * PSB + sq * 16 + 8];
#pragma unroll
      for (int i = 0; i < 16; ++i) Vt[sq * 16 + i][sr] = vv.s[i];
    }
    __syncthreads();
    // S = Q K^T
    bfrag8 af0 = *(const bfrag8*)&Qs[m0w + r16][quad * 8];
    bfrag8 af1 = *(const bfrag8*)&Qs[m0w + r16][quad * 8 + 32];
    f32x4 s[4];
#pragma unroll
    for (int j = 0; j < 4; ++j) s[j] = {0.f, 0.f, 0.f, 0.f};
#pragma unroll
    for (int j = 0; j < 4; ++j) {
      bfrag8 b0 = *(const bfrag8*)&Ks[j * 16 + r16][quad * 8];
      bfrag8 b1 = *(const bfrag8*)&Ks[j * 16 + r16][quad * 8 + 32];
      s[j] = __builtin_amdgcn_mfma_f32_16x16x32_bf16(af0, b0, s[j], 0, 0, 0);
      s[j] = __builtin_amdgcn_mfma_f32_16x16x32_bf16(af1, b1, s[j], 0, 0, 0);
    }
    bool oldest = (kt == qb - (int)WIN);
    bool newest = (kt == qb);
    // online softmax per row (row = m0w + quad*4 + r)
#pragma unroll
    for (int r = 0; r < 4; ++r) {
      int il = m0w + quad * 4 + r;
      float sv[4];
#pragma unroll
      for (int j = 0; j < 4; ++j) {
        int jl = j * 16 + r16;
        float v = s[j][r] * 0.125f;
        if (oldest && jl < il) v = -1e30f;
        if (newest && jl > il) v = -1e30f;
        sv[j] = v;
      }
      float mx = fmaxf(fmaxf(sv[0], sv[1]), fmaxf(sv[2], sv[3]));
#pragma unroll
      for (int off = 1; off < 16; off <<= 1) mx = fmaxf(mx, __shfl_xor(mx, off));
      float mn = fmaxf(m[r], mx);
      float al = __expf(m[r] - mn);
      m[r] = mn;
      float rs = 0.f;
#pragma unroll
      for (int j = 0; j < 4; ++j) {
        float p = __expf(sv[j] - mn);
        rs += p;
        Ps[il][j * 16 + r16] = f2bf(p);
      }
#pragma unroll
      for (int off = 1; off < 16; off <<= 1) rs += __shfl_xor(rs, off);
      l[r] = l[r] * al + rs;
#pragma unroll
      for (int j = 0; j < 4; ++j) o[j][r] *= al;
    }
    // O += P V  (Ps rows are wave-private; no cross-wave barrier needed)
    bfrag8 pa0 = *(const bfrag8*)&Ps[m0w + r16][quad * 8];
    bfrag8 pa1 = *(const bfrag8*)&Ps[m0w + r16][quad * 8 + 32];
#pragma unroll
    for (int j = 0; j < 4; ++j) {
      bfrag8 v0 = *(const bfrag8*)&Vt[j * 16 + r16][quad * 8];
      bfrag8 v1 = *(const bfrag8*)&Vt[j * 16 + r16][quad * 8 + 32];
      o[j] = __builtin_amdgcn_mfma_f32_16x16x32_bf16(pa0, v0, o[j], 0, 0, 0);
      o[j] = __builtin_amdgcn_mfma_f32_16x16x32_bf16(pa1, v1, o[j], 0, 0, 0);
    }
  }
  // epilogue -> ACAT col 1024 (local branch; 0.3 folded into W_swa)
#pragma unroll
  for (int r = 0; r < 4; ++r) {
    int row = m0w + quad * 4 + r;
    float inv = 1.f / l[r];
#pragma unroll
    for (int j = 0; j < 4; ++j) {
      ACAT[((size_t)(b * TT + qb + row)) * PSB + 1024 + h * 64 + j * 16 + r16] =
          f2bf(o[j][r] * inv);
    }
  }
}

// ---------------------------------------------------------------------------
// Scan phase A (per (bh,chunk)): M, u_free, Z, P, Q, a. As R5 but P32 input.
// ---------------------------------------------------------------------------
__global__ __launch_bounds__(256) void scan_phaseA(
    const float* __restrict__ p32, const float* __restrict__ beta,
    const float* __restrict__ g, unsigned short* __restrict__ UFg,
    unsigned short* __restrict__ Zg, unsigned short* __restrict__ Pg,
    unsigned short* __restrict__ Qg, float* __restrict__ Ag) {
  __shared__ unsigned short Kc[64][72];
  __shared__ unsigned short KTb[64][72];
  __shared__ float Vc[64][68];
  __shared__ float Msv[64][68];
  __shared__ unsigned short UFT[64][72];
  __shared__ unsigned short ZTl[64][72];
  __shared__ float aArr[64], iaArr[64], bArr[64], baArr[64], sKT[64];
  __shared__ float aCs;

  int c = blockIdx.x, bh = blockIdx.y;
  int b = bh >> 4, h = bh & 15;
  int tc = c * 64;
  int tid = threadIdx.x, lane = tid & 63, wave = tid >> 6;
  int r16 = lane & 15, quad = lane >> 4;
  int m0w = wave * 16;
  size_t bhc = (size_t)bh * 16 + c;

  const float* kbase = p32 + ((size_t)b * TT) * PS32 + h * 64;
  const float* vbase = p32 + ((size_t)b * TT) * PS32 + 1024 + h * 64;
  const float* bbase = beta + ((size_t)b * TT) * HH + h;
  const float* gbase = g + ((size_t)b * TT) * HH + h;

  if (tid < 64) {
    int ts = tc + tid;
    bool pad = (ts > 1022);
    float gv = pad ? 1.f : gbase[(size_t)ts * HH];
    float bv = pad ? 0.f : bbase[(size_t)ts * HH];
    float p = gv;
#pragma unroll
    for (int o = 1; o < 64; o <<= 1) {
      float t = __shfl_up(p, o);
      if (lane >= o) p *= t;
    }
    aArr[tid] = p;
    iaArr[tid] = 1.f / p;
    bArr[tid] = bv;
    baArr[tid] = bv * p;
    float aC = __shfl(p, 63);
    sKT[tid] = aC / p;
    if (tid == 0) aCs = aC;
    Ag[bhc * 64 + tid] = p;
  }
  __syncthreads();
  {
    int r = tid >> 2, q = tid & 3;
    int ts = tc + r;
    float skt = sKT[r];
#pragma unroll
    for (int i = 0; i < 4; ++i) {
      float4 kv = *(const float4*)&kbase[(size_t)ts * PS32 + q * 16 + i * 4];
      ushort4 ku;
      ku.x = f2bf(kv.x); ku.y = f2bf(kv.y); ku.z = f2bf(kv.z); ku.w = f2bf(kv.w);
      *(ushort4*)&Kc[r][q * 16 + i * 4] = ku;
      KTb[q * 16 + i * 4 + 0][r] = f2bf(kv.x * skt);
      KTb[q * 16 + i * 4 + 1][r] = f2bf(kv.y * skt);
      KTb[q * 16 + i * 4 + 2][r] = f2bf(kv.z * skt);
      KTb[q * 16 + i * 4 + 3][r] = f2bf(kv.w * skt);
      float4 vv;
      if (ts <= 1022)
        vv = *(const float4*)&vbase[(size_t)(ts + 1) * PS32 + q * 16 + i * 4];
      else
        vv = make_float4(0.f, 0.f, 0.f, 0.f);
      *(float4*)&Vc[r][q * 16 + i * 4] = vv;
    }
  }
  __syncthreads();
  {
    bfrag8 af0 = *(const bfrag8*)&Kc[m0w + r16][quad * 8];
    bfrag8 af1 = *(const bfrag8*)&Kc[m0w + r16][quad * 8 + 32];
    f32x4 acc1[4];
#pragma unroll
    for (int j = 0; j < 4; ++j) acc1[j] = {0.f, 0.f, 0.f, 0.f};
#pragma unroll
    for (int j = 0; j < 4; ++j) {
      bfrag8 k0 = *(const bfrag8*)&Kc[j * 16 + r16][quad * 8];
      bfrag8 k1 = *(const bfrag8*)&Kc[j * 16 + r16][quad * 8 + 32];
      acc1[j] = __builtin_amdgcn_mfma_f32_16x16x32_bf16(af0, k0, acc1[j], 0, 0, 0);
      acc1[j] = __builtin_amdgcn_mfma_f32_16x16x32_bf16(af1, k1, acc1[j], 0, 0, 0);
    }
#pragma unroll
    for (int j = 0; j < 4; ++j) {
#pragma unroll
      for (int r = 0; r < 4; ++r) {
        int row = m0w + quad * 4 + r;
        int col = j * 16 + r16;
        Msv[row][col] =
            (col < row) ? bArr[row] * aArr[row] * iaArr[col] * acc1[j][r] : 0.f;
      }
    }
  }
  __syncthreads();
  if (wave < 2) {
    float u[64];
    if (wave == 0) {
#pragma unroll
      for (int t = 0; t < 64; ++t) u[t] = bArr[t] * Vc[t][lane];
    } else {
#pragma unroll
      for (int t = 0; t < 64; ++t) u[t] = baArr[t] * bf2f(Kc[t][lane]);
    }
#pragma unroll
    for (int t = 1; t < 64; ++t) {
      float a0 = 0.f, a1 = 0.f, a2 = 0.f, a3 = 0.f;
#pragma unroll
      for (int s4 = 0; s4 * 4 < t; ++s4) {
        float4 mr = *(const float4*)&Msv[t][s4 * 4];
        a0 = fmaf(mr.x, u[s4 * 4 + 0], a0);
        a1 = fmaf(mr.y, u[s4 * 4 + 1], a1);
        a2 = fmaf(mr.z, u[s4 * 4 + 2], a2);
        a3 = fmaf(mr.w, u[s4 * 4 + 3], a3);
      }
      u[t] -= (a0 + a1) + (a2 + a3);
    }
    unsigned short* Tls = (wave == 0) ? &UFT[lane][0] : &ZTl[lane][0];
#pragma unroll
    for (int t2 = 0; t2 < 32; ++t2) {
      unsigned int pk = (unsigned int)f2bf(u[2 * t2]) |
                        ((unsigned int)f2bf(u[2 * t2 + 1]) << 16);
      *(unsigned int*)&Tls[2 * t2] = pk;
    }
    unsigned short* Gn = (wave == 0) ? UFg : Zg;
#pragma unroll
    for (int t = 0; t < 64; ++t) {
      Gn[(bhc * 64 + t) * 64 + lane] = f2bf(u[t]);
    }
  }
  __syncthreads();
  {
    bfrag8 af0 = *(const bfrag8*)&KTb[m0w + r16][quad * 8];
    bfrag8 af1 = *(const bfrag8*)&KTb[m0w + r16][quad * 8 + 32];
    f32x4 accp[4], accq[4];
#pragma unroll
    for (int j = 0; j < 4; ++j) {
      accp[j] = {0.f, 0.f, 0.f, 0.f};
      accq[j] = {0.f, 0.f, 0.f, 0.f};
    }
#pragma unroll
    for (int j = 0; j < 4; ++j) {
      bfrag8 z0 = *(const bfrag8*)&ZTl[j * 16 + r16][quad * 8];
      bfrag8 z1 = *(const bfrag8*)&ZTl[j * 16 + r16][quad * 8 + 32];
      accp[j] = __builtin_amdgcn_mfma_f32_16x16x32_bf16(af0, z0, accp[j], 0, 0, 0);
      accp[j] = __builtin_amdgcn_mfma_f32_16x16x32_bf16(af1, z1, accp[j], 0, 0, 0);
      bfrag8 u0 = *(const bfrag8*)&UFT[j * 16 + r16][quad * 8];
      bfrag8 u1 = *(const bfrag8*)&UFT[j * 16 + r16][quad * 8 + 32];
      accq[j] = __builtin_amdgcn_mfma_f32_16x16x32_bf16(af0, u0, accq[j], 0, 0, 0);
      accq[j] = __builtin_amdgcn_mfma_f32_16x16x32_bf16(af1, u1, accq[j], 0, 0, 0);
    }
    float aC = aCs;
#pragma unroll
    for (int j = 0; j < 4; ++j) {
#pragma unroll
      for (int r = 0; r < 4; ++r) {
        int row = m0w + quad * 4 + r;
        int col = j * 16 + r16;
        float pv = ((row == col) ? aC : 0.f) - accp[j][r];
        Pg[bhc * 4096 + (size_t)row * 64 + col] = f2bf(pv);
        Qg[bhc * 4096 + (size_t)row * 64 + col] = f2bf(accq[j][r]);
      }
    }
  }
}

// ---------------------------------------------------------------------------
// Scan phase B: serial S_{c+1} = P_c S_c + Q_c. Exports S_c^T, final Sf,
// zeroes gdn row t=0 in ACAT.
// ---------------------------------------------------------------------------
__global__ __launch_bounds__(256) void scan_phaseB(
    const float* __restrict__ S0, const unsigned short* __restrict__ Pg,
    const unsigned short* __restrict__ Qg, unsigned short* __restrict__ SinTg,
    float* __restrict__ Sf, unsigned short* __restrict__ ACAT) {
  __shared__ unsigned short STb[64][72];
  __shared__ unsigned short Pl[64][72];
  int bh = blockIdx.x;
  int b = bh >> 4, h = bh & 15;
  int tid = threadIdx.x, lane = tid & 63, wave = tid >> 6;
  int r16 = lane & 15, quad = lane >> 4;
  int m0w = wave * 16;
  int rr = tid >> 2, qq = tid & 3;
  {
    const float* s0p = S0 + (size_t)bh * 4096;
#pragma unroll
    for (int i = 0; i < 4; ++i) {
      float4 sv = *(const float4*)&s0p[rr * 64 + qq * 16 + i * 4];
      STb[qq * 16 + i * 4 + 0][rr] = f2bf(sv.x);
      STb[qq * 16 + i * 4 + 1][rr] = f2bf(sv.y);
      STb[qq * 16 + i * 4 + 2][rr] = f2bf(sv.z);
      STb[qq * 16 + i * 4 + 3][rr] = f2bf(sv.w);
    }
    if (tid < 64) ACAT[((size_t)b * TT) * PSB + h * 64 + tid] = 0;
  }
  for (int c = 0; c < 16; ++c) {
    size_t bhc = (size_t)bh * 16 + c;
    __syncthreads();
    {
      uint4 s0v = *(const uint4*)&STb[rr][qq * 16];
      uint4 s1v = *(const uint4*)&STb[rr][qq * 16 + 8];
      *(uint4*)&SinTg[bhc * 4096 + (size_t)rr * 64 + qq * 16] = s0v;
      *(uint4*)&SinTg[bhc * 4096 + (size_t)rr * 64 + qq * 16 + 8] = s1v;
      uint4 p0 = *(const uint4*)&Pg[bhc * 4096 + (size_t)rr * 64 + qq * 16];
      uint4 p1 = *(const uint4*)&Pg[bhc * 4096 + (size_t)rr * 64 + qq * 16 + 8];
      *(uint4*)&Pl[rr][qq * 16] = p0;
      *(uint4*)&Pl[rr][qq * 16 + 8] = p1;
    }
    __syncthreads();
    f32x4 acc[4];
#pragma unroll
    for (int j = 0; j < 4; ++j) acc[j] = {0.f, 0.f, 0.f, 0.f};
    {
      bfrag8 af0 = *(const bfrag8*)&Pl[m0w + r16][quad * 8];
      bfrag8 af1 = *(const bfrag8*)&Pl[m0w + r16][quad * 8 + 32];
#pragma unroll
      for (int j = 0; j < 4; ++j) {
        bfrag8 s0v = *(const bfrag8*)&STb[j * 16 + r16][quad * 8];
        bfrag8 s1v = *(const bfrag8*)&STb[j * 16 + r16][quad * 8 + 32];
        acc[j] = __builtin_amdgcn_mfma_f32_16x16x32_bf16(af0, s0v, acc[j], 0, 0, 0);
        acc[j] = __builtin_amdgcn_mfma_f32_16x16x32_bf16(af1, s1v, acc[j], 0, 0, 0);
      }
    }
    float snew[4][4];
#pragma unroll
    for (int j = 0; j < 4; ++j) {
#pragma unroll
      for (int r = 0; r < 4; ++r) {
        int row = m0w + quad * 4 + r;
        int col = j * 16 + r16;
        snew[j][r] = acc[j][r] + bf2f(Qg[bhc * 4096 + (size_t)row * 64 + col]);
      }
    }
    __syncthreads();
#pragma unroll
    for (int j = 0; j < 4; ++j) {
#pragma unroll
      for (int r = 0; r < 4; ++r) {
        int row = m0w + quad * 4 + r;
        int col = j * 16 + r16;
        STb[col][row] = f2bf(snew[j][r]);
        if (c == 15) Sf[(size_t)bh * 4096 + (size_t)row * 64 + col] = snew[j][r];
      }
    }
  }
}

// ---------------------------------------------------------------------------
// Scan phase C: O = diag(a) K S_in + W U -> ACAT col 0 (gdn), per (bh,chunk).
// ---------------------------------------------------------------------------
__global__ __launch_bounds__(256) void scan_phaseC(
    const float* __restrict__ p32, const unsigned short* __restrict__ UFg,
    const unsigned short* __restrict__ Zg,
    const unsigned short* __restrict__ SinTg, const float* __restrict__ Ag,
    unsigned short* __restrict__ ACAT) {
  __shared__ unsigned short Kc[64][72];
  __shared__ unsigned short SvT[64][72];
  __shared__ unsigned short Zl[64][72];
  __shared__ unsigned short Ufl[64][72];
  __shared__ unsigned short Wl[64][72];
  __shared__ unsigned short UTl[64][72];
  __shared__ float aA[64], iaA[64];

  int c = blockIdx.x, bh = blockIdx.y;
  int b = bh >> 4, h = bh & 15;
  int tc = c * 64;
  int tid = threadIdx.x, lane = tid & 63, wave = tid >> 6;
  int r16 = lane & 15, quad = lane >> 4;
  int m0w = wave * 16;
  size_t bhc = (size_t)bh * 16 + c;
  const float* kbase = p32 + ((size_t)b * TT) * PS32 + h * 64;

  if (tid < 64) {
    float av = Ag[bhc * 64 + tid];
    aA[tid] = av;
    iaA[tid] = 1.f / av;
  }
  {
    int r = tid >> 2, q = tid & 3;
    int ts = tc + r;
#pragma unroll
    for (int i = 0; i < 4; ++i) {
      float4 kv = *(const float4*)&kbase[(size_t)ts * PS32 + q * 16 + i * 4];
      ushort4 ku;
      ku.x = f2bf(kv.x); ku.y = f2bf(kv.y); ku.z = f2bf(kv.z); ku.w = f2bf(kv.w);
      *(ushort4*)&Kc[r][q * 16 + i * 4] = ku;
    }
    uint4 sv0 = *(const uint4*)&SinTg[bhc * 4096 + (size_t)r * 64 + q * 16];
    uint4 sv1 = *(const uint4*)&SinTg[bhc * 4096 + (size_t)r * 64 + q * 16 + 8];
    *(uint4*)&SvT[r][q * 16] = sv0;
    *(uint4*)&SvT[r][q * 16 + 8] = sv1;
    uint4 zv0 = *(const uint4*)&Zg[(bhc * 64 + r) * 64 + q * 16];
    uint4 zv1 = *(const uint4*)&Zg[(bhc * 64 + r) * 64 + q * 16 + 8];
    *(uint4*)&Zl[r][q * 16] = zv0;
    *(uint4*)&Zl[r][q * 16 + 8] = zv1;
    uint4 uv0 = *(const uint4*)&UFg[(bhc * 64 + r) * 64 + q * 16];
    uint4 uv1 = *(const uint4*)&UFg[(bhc * 64 + r) * 64 + q * 16 + 8];
    *(uint4*)&Ufl[r][q * 16] = uv0;
    *(uint4*)&Ufl[r][q * 16 + 8] = uv1;
  }
  __syncthreads();
  float op[4][4];
  {
    bfrag8 af0 = *(const bfrag8*)&Kc[m0w + r16][quad * 8];
    bfrag8 af1 = *(const bfrag8*)&Kc[m0w + r16][quad * 8 + 32];
    bfrag8 zf0 = *(const bfrag8*)&Zl[m0w + r16][quad * 8];
    bfrag8 zf1 = *(const bfrag8*)&Zl[m0w + r16][quad * 8 + 32];
    f32x4 acc1[4], acc2[4], acc3[4];
#pragma unroll
    for (int j = 0; j < 4; ++j) {
      acc1[j] = {0.f, 0.f, 0.f, 0.f};
      acc2[j] = {0.f, 0.f, 0.f, 0.f};
      acc3[j] = {0.f, 0.f, 0.f, 0.f};
    }
#pragma unroll
    for (int j = 0; j < 4; ++j) {
      bfrag8 k0 = *(const bfrag8*)&Kc[j * 16 + r16][quad * 8];
      bfrag8 k1 = *(const bfrag8*)&Kc[j * 16 + r16][quad * 8 + 32];
      acc1[j] = __builtin_amdgcn_mfma_f32_16x16x32_bf16(af0, k0, acc1[j], 0, 0, 0);
      acc1[j] = __builtin_amdgcn_mfma_f32_16x16x32_bf16(af1, k1, acc1[j], 0, 0, 0);
      bfrag8 s0 = *(const bfrag8*)&SvT[j * 16 + r16][quad * 8];
      bfrag8 s1 = *(const bfrag8*)&SvT[j * 16 + r16][quad * 8 + 32];
      acc3[j] = __builtin_amdgcn_mfma_f32_16x16x32_bf16(af0, s0, acc3[j], 0, 0, 0);
      acc3[j] = __builtin_amdgcn_mfma_f32_16x16x32_bf16(af1, s1, acc3[j], 0, 0, 0);
      acc2[j] = __builtin_amdgcn_mfma_f32_16x16x32_bf16(zf0, s0, acc2[j], 0, 0, 0);
      acc2[j] = __builtin_amdgcn_mfma_f32_16x16x32_bf16(zf1, s1, acc2[j], 0, 0, 0);
    }
#pragma unroll
    for (int j = 0; j < 4; ++j) {
#pragma unroll
      for (int r = 0; r < 4; ++r) {
        int row = m0w + quad * 4 + r;
        int col = j * 16 + r16;
        Wl[row][col] = (col <= row) ? f2bf(aA[row] * iaA[col] * acc1[j][r])
                                    : (unsigned short)0;
        float uval = bf2f(Ufl[row][col]) - acc2[j][r];
        UTl[col][row] = f2bf(uval);
        op[j][r] = aA[row] * acc3[j][r];
      }
    }
  }
  __syncthreads();
  {
    bfrag8 wf0 = *(const bfrag8*)&Wl[m0w + r16][quad * 8];
    bfrag8 wf1 = *(const bfrag8*)&Wl[m0w + r16][quad * 8 + 32];
    f32x4 acc4[4];
#pragma unroll
    for (int j = 0; j < 4; ++j) acc4[j] = {0.f, 0.f, 0.f, 0.f};
#pragma unroll
    for (int j = 0; j < 4; ++j) {
      bfrag8 u0 = *(const bfrag8*)&UTl[j * 16 + r16][quad * 8];
      bfrag8 u1 = *(const bfrag8*)&UTl[j * 16 + r16][quad * 8 + 32];
      acc4[j] = __builtin_amdgcn_mfma_f32_16x16x32_bf16(wf0, u0, acc4[j], 0, 0, 0);
      acc4[j] = __builtin_amdgcn_mfma_f32_16x16x32_bf16(wf1, u1, acc4[j], 0, 0, 0);
    }
#pragma unroll
    for (int j = 0; j < 4; ++j) {
#pragma unroll
      for (int r = 0; r < 4; ++r) {
        int row = m0w + quad * 4 + r;
        int col = j * 16 + r16;
        int ts = tc + row;
        if (ts < 1023) {
          ACAT[((size_t)b * TT + ts + 1) * PSB + h * 64 + col] =
              f2bf(op[j][r] + acc4[j][r]);
        }
      }
    }
  }
}

// ---------------------------------------------------------------------------
// retrieved = (k_shared @ Sf) * mg  -> ACAT col 2048 (bf16).
// ---------------------------------------------------------------------------
__global__ __launch_bounds__(256) void retrieve_kernel(
    const float* __restrict__ p32, const float* __restrict__ Sf,
    const float* __restrict__ mg, unsigned short* __restrict__ ACAT) {
  int w = blockIdx.x * 4 + (threadIdx.x >> 6);  // (b*T+t)*H + h
  int lane = threadIdx.x & 63;                  // v index
  int bt = w >> 4;
  float kl = p32[(size_t)bt * PS32 + (w & 15) * 64 + lane];
  int b = bt >> 10;
  int bh = b * 16 + (w & 15);
  const float* sfp = Sf + (size_t)bh * 4096;
  float acc = 0.f;
#pragma unroll
  for (int k = 0; k < 64; ++k) {
    float kk = __shfl(kl, k);
    acc = fmaf(kk, sfp[k * 64 + lane], acc);
  }
  ACAT[(size_t)bt * PSB + 2048 + (w & 15) * 64 + lane] = f2bf(acc * mg[bt]);
}

// ---------------------------------------------------------------------------
extern "C" void kernel_launch(void* const* d_in, const int* in_sizes, int n_in,
                              void* d_out, int out_size, void* d_ws,
                              size_t ws_size, hipStream_t stream) {
  (void)in_sizes; (void)n_in; (void)out_size; (void)ws_size;
  const float* x       = (const float*)d_in[0];
  const float* S0      = (const float*)d_in[1];
  const float* W_k     = (const float*)d_in[2];
  const float* W_v     = (const float*)d_in[3];
  const float* W_gdn_o = (const float*)d_in[4];
  const float* W_beta  = (const float*)d_in[5];
  const float* b_beta  = (const float*)d_in[6];
  const float* W_g     = (const float*)d_in[7];
  const float* b_g     = (const float*)d_in[8];
  const float* W_lq    = (const float*)d_in[9];
  const float* W_lk    = (const float*)d_in[10];
  const float* W_lv    = (const float*)d_in[11];
  const float* W_swa_o = (const float*)d_in[12];
  const float* W_ret_o = (const float*)d_in[13];
  const float* W_gate  = (const float*)d_in[14];
  const float* b_gate  = (const float*)d_in[15];
  const float* norm_w  = (const float*)d_in[16];
  const int*   ids     = (const int*)d_in[17];
  float* out = (float*)d_out;

  char* ws = (char*)d_ws;
  size_t off = 0;
  auto allocf = [&](size_t n) {
    float* p = (float*)(ws + off);
    off += n * sizeof(float);
    return p;
  };
  auto allocu = [&](size_t n) {
    unsigned short* p = (unsigned short*)(ws + off);
    off += n * sizeof(unsigned short);
    return p;
  };
  const int M = BB * TT;  // 4096
  unsigned short* XNb    = allocu((size_t)M * DD);
  float*          P32    = allocf((size_t)M * PS32);  // KSH | VF
  unsigned short* PB     = allocu((size_t)M * PSB);   // Q | KL | VL
  unsigned short* ACAT   = allocu((size_t)M * PSB);   // gdn | local | retr
  unsigned short* WTcat5 = allocu((size_t)5120 * 1024);
  unsigned short* WTcat3 = allocu((size_t)1024 * PSB);
  float* BETA = allocf((size_t)M * HH);
  float* Gg   = allocf((size_t)M * HH);
  float* MG   = allocf((size_t)M);
  float* SF   = allocf((size_t)BB * HH * KK * VV);
  const size_t CH = (size_t)BB * HH * 16 * 64 * 64;
  unsigned short* UFg   = allocu(CH);
  unsigned short* Zg    = allocu(CH);
  unsigned short* Pg    = allocu(CH);
  unsigned short* Qg    = allocu(CH);
  unsigned short* SinTg = allocu(CH);
  float* Ag = allocf((size_t)BB * HH * 16 * 64);

  rmsnorm_kernel<<<M, 256, 0, stream>>>(x, norm_w, XNb);

  convert_wt_kernel<<<dim3(16, 16, 8), 256, 0, stream>>>(
      W_k, W_v, W_lq, W_lk, W_lv, W_gdn_o, W_swa_o, W_ret_o, WTcat5, WTcat3);

  gemm_proj_kernel<<<dim3(5120 / 128, M / 128), 256, 0, stream>>>(XNb, WTcat5,
                                                                  P32, PB);

  knorm_kernel<<<(M * HH) / 4, 256, 0, stream>>>(P32);
  smallproj_kernel<<<M, 256, 0, stream>>>(XNb, W_beta, b_beta, W_g, b_g, W_gate,
                                          b_gate, ids, BETA, Gg, MG);

  scan_phaseA<<<dim3(16, BB * HH), 256, 0, stream>>>(P32, BETA, Gg, UFg, Zg, Pg,
                                                     Qg, Ag);
  scan_phaseB<<<BB * HH, 256, 0, stream>>>(S0, Pg, Qg, SinTg, SF, ACAT);
  scan_phaseC<<<dim3(16, BB * HH), 256, 0, stream>>>(P32, UFg, Zg, SinTg, Ag,
                                                     ACAT);

  attn_mfma_kernel<<<dim3(TT / 64, BB * HH), 256, 0, stream>>>(PB, ACAT);

  retrieve_kernel<<<(M * HH) / 4, 256, 0, stream>>>(P32, SF, MG, ACAT);

  // out = x + [gdn | local*0.3W | retr*mg] @ WTcat3^T  (single K=3072 GEMM)
  gemm_mfma_kernel<<<dim3(DD / 128, M / 128), 256, 0, stream>>>(
      ACAT, WTcat3, out, x, M, DD, 3072);
}

// Round 7
// 443.419 us; speedup vs baseline: 7.2827x; 1.1145x over previous
//
#include <hip/hip_runtime.h>
#include <hip/hip_bf16.h>

// Problem constants
#define BB 4
#define TT 1024
#define DD 1024
#define HH 16
#define KK 64
#define VV 64
#define WIN 256
#define MARKER_ID 50251
#define PS32 2048  // fp32 proj buffer row stride (KSH | VF)
#define PSB 3072   // bf16 proj / epilogue-cat row stride
#define NPROJ 5248 // proj GEMM N: 2048 fp32 + 3072 bf16 + 128 gates(48+80 pad)

typedef short bfrag8 __attribute__((ext_vector_type(8)));
typedef float f32x4 __attribute__((ext_vector_type(4)));

static __device__ __forceinline__ unsigned short f2bf(float f) {
  __hip_bfloat16 h = __float2bfloat16(f);
  union { __hip_bfloat16 h; unsigned short u; } cv;
  cv.h = h;
  return cv.u;
}
static __device__ __forceinline__ float bf2f(unsigned short u) {
  union { unsigned int i; float f; } c;
  c.i = ((unsigned int)u) << 16;
  return c.f;
}

// ---------------------------------------------------------------------------
// RMSNorm: xnb (bf16) = x / sqrt(mean(x^2)+eps) * norm_w. One block per row.
// ---------------------------------------------------------------------------
__global__ __launch_bounds__(256) void rmsnorm_kernel(
    const float* __restrict__ x, const float* __restrict__ nw,
    unsigned short* __restrict__ xnb) {
  int row = blockIdx.x;
  int tid = threadIdx.x;
  const float4* xr = (const float4*)(x + (size_t)row * DD);
  float4 v = xr[tid];
  float ss = v.x * v.x + v.y * v.y + v.z * v.z + v.w * v.w;
#pragma unroll
  for (int off = 32; off; off >>= 1) ss += __shfl_xor(ss, off);
  __shared__ float red[4];
  int wid = tid >> 6;
  if ((tid & 63) == 0) red[wid] = ss;
  __syncthreads();
  float tot = red[0] + red[1] + red[2] + red[3];
  float inv = 1.0f / sqrtf(tot * (1.0f / DD) + 1e-6f);
  const float4* wr = (const float4*)nw;
  float4 wv = wr[tid];
  ushort4 o;
  o.x = f2bf(v.x * inv * wv.x);
  o.y = f2bf(v.y * inv * wv.y);
  o.z = f2bf(v.z * inv * wv.z);
  o.w = f2bf(v.w * inv * wv.w);
  *(ushort4*)&xnb[(size_t)row * DD + tid * 4] = o;
}

// ---------------------------------------------------------------------------
// Convert + transpose weights fp32 [K][N] -> bf16 [N][K] into concatenated
// buffers. z=0..7: the 1024x1024 weights. z=8: small gate weights (48 rows)
// + zero-pad rows 5168..5247 of C5.
// ---------------------------------------------------------------------------
__global__ __launch_bounds__(256) void convert_wt_kernel(
    const float* W0, const float* W1, const float* W2, const float* W3,
    const float* W4, const float* W5, const float* W6, const float* W7,
    const float* Wb, const float* Wg, const float* Wgt,
    unsigned short* C5, unsigned short* C3) {
  int tid = threadIdx.x;
  if (blockIdx.z == 8) {
    if (blockIdx.x != 0) return;
    int k0 = blockIdx.y * 64;
    for (int e = tid; e < 3 * 16 * 64; e += 256) {
      int w = e >> 10;          // which weight
      int h = (e >> 6) & 15;    // head col
      int kk = e & 63;
      const float* Ws = (w == 0) ? Wb : (w == 1) ? Wg : Wgt;
      C5[(size_t)(5120 + w * 16 + h) * 1024 + k0 + kk] =
          f2bf(Ws[(size_t)(k0 + kk) * 16 + h]);
    }
    for (int e = tid; e < 80 * 64; e += 256) {
      int r = e >> 6, kk = e & 63;
      C5[(size_t)(5168 + r) * 1024 + k0 + kk] = 0;
    }
    return;
  }
  const float* W;
  unsigned short* T;
  int stride;
  float scale = 1.f;
  switch (blockIdx.z) {
    case 0: W = W0; T = C5 + 0 * 1024 * 1024; stride = 1024; break;
    case 1: W = W1; T = C5 + 1 * 1024 * 1024; stride = 1024; break;
    case 2: W = W2; T = C5 + 2 * 1024 * 1024; stride = 1024; break;
    case 3: W = W3; T = C5 + 3 * 1024 * 1024; stride = 1024; break;
    case 4: W = W4; T = C5 + 4 * 1024 * 1024; stride = 1024; break;
    case 5: W = W5; T = C3 + 0; stride = PSB; break;
    case 6: W = W6; T = C3 + 1024; stride = PSB; scale = 0.3f; break;
    default: W = W7; T = C3 + 2048; stride = PSB; break;
  }
  __shared__ float Ts[64][68];
  int n0 = blockIdx.x * 64, k0 = blockIdx.y * 64;
#pragma unroll
  for (int p = 0; p < 4; ++p) {
    int e = p * 256 + tid;
    int k = e >> 4, nq = e & 15;
    float4 w = *(const float4*)&W[(size_t)(k0 + k) * 1024 + n0 + nq * 4];
    Ts[nq * 4 + 0][k] = w.x;
    Ts[nq * 4 + 1][k] = w.y;
    Ts[nq * 4 + 2][k] = w.z;
    Ts[nq * 4 + 3][k] = w.w;
  }
  __syncthreads();
#pragma unroll
  for (int p = 0; p < 4; ++p) {
    int e = p * 256 + tid;
    int n = e >> 4, kq = e & 15;
    float4 v = *(const float4*)&Ts[n][kq * 4];
    ushort4 u;
    u.x = f2bf(v.x * scale);
    u.y = f2bf(v.y * scale);
    u.z = f2bf(v.z * scale);
    u.w = f2bf(v.w * scale);
    *(ushort4*)&T[(size_t)(n0 + n) * stride + k0 + kq * 4] = u;
  }
}

// ---------------------------------------------------------------------------
// Epilogue GEMM: out = x + ACAT[4096][3072] @ WTcat3[1024][3072]^T.
// 128M x 64N tile -> 512 blocks (2/CU). 4 waves of 32M x 64N.
// XCD swizzle: flat%8 = XCD owns 4 contiguous m-tiles (A-slice ~3MB -> L2).
// Grid MUST be (16, 32).
// ---------------------------------------------------------------------------
__global__ __launch_bounds__(256) void gemm_out_kernel(
    const unsigned short* __restrict__ A, const unsigned short* __restrict__ BT,
    float* __restrict__ C, const float* __restrict__ addp, int M, int N,
    int K) {
  __shared__ unsigned short As[128][40];
  __shared__ unsigned short Bs[64][40];
  int flat = blockIdx.y * gridDim.x + blockIdx.x;
  int xcd = flat & 7, local = flat >> 3;
  int m0 = (xcd * 4 + (local & 3)) * 128;
  int n0 = (local >> 2) * 64;
  int tid = threadIdx.x;
  int wave = tid >> 6, lane = tid & 63;
  int wm = wave * 32;
  int r16 = lane & 15, quad = lane >> 4;
  int srow = tid >> 2, scq = tid & 3;

  f32x4 acc[2][4];
#pragma unroll
  for (int i = 0; i < 2; ++i)
#pragma unroll
    for (int j = 0; j < 4; ++j) acc[i][j] = {0.f, 0.f, 0.f, 0.f};

  for (int kt = 0; kt < K; kt += 32) {
    uint4 a0 = *(const uint4*)&A[(size_t)(m0 + srow) * K + kt + scq * 8];
    uint4 a1 = *(const uint4*)&A[(size_t)(m0 + 64 + srow) * K + kt + scq * 8];
    uint4 b0 = *(const uint4*)&BT[(size_t)(n0 + srow) * K + kt + scq * 8];
    __syncthreads();
    *(uint4*)&As[srow][scq * 8] = a0;
    *(uint4*)&As[64 + srow][scq * 8] = a1;
    if (srow < 64) *(uint4*)&Bs[srow][scq * 8] = b0;
    __syncthreads();
    bfrag8 af[2], bq[4];
#pragma unroll
    for (int i = 0; i < 2; ++i)
      af[i] = *(const bfrag8*)&As[wm + i * 16 + r16][quad * 8];
#pragma unroll
    for (int j = 0; j < 4; ++j)
      bq[j] = *(const bfrag8*)&Bs[j * 16 + r16][quad * 8];
#pragma unroll
    for (int i = 0; i < 2; ++i)
#pragma unroll
      for (int j = 0; j < 4; ++j)
        acc[i][j] = __builtin_amdgcn_mfma_f32_16x16x32_bf16(af[i], bq[j],
                                                            acc[i][j], 0, 0, 0);
  }
#pragma unroll
  for (int i = 0; i < 2; ++i) {
#pragma unroll
    for (int r = 0; r < 4; ++r) {
      int row = m0 + wm + i * 16 + quad * 4 + r;
#pragma unroll
      for (int j = 0; j < 4; ++j) {
        int col = n0 + j * 16 + r16;
        size_t idx = (size_t)row * N + col;
        C[idx] = addp[idx] + acc[i][j][r];
      }
    }
  }
}

// ---------------------------------------------------------------------------
// Fused projection GEMM: A=xn [4096][1024] bf16, BT=WTcat5 [5248][1024].
// cols 0..2047 fp32 -> P32 (KSH|VF); 2048..5119 bf16 -> PB (Q|KL|VL);
// 5120..5247 fp32 -> SPRJ (gate logits, stride 128).
// ---------------------------------------------------------------------------
__global__ __launch_bounds__(256) void gemm_proj_kernel(
    const unsigned short* __restrict__ A, const unsigned short* __restrict__ BT,
    float* __restrict__ P32, unsigned short* __restrict__ PB,
    float* __restrict__ SPRJ) {
  const int K = 1024;
  __shared__ unsigned short As[128][40];
  __shared__ unsigned short Bs[128][40];
  int tid = threadIdx.x;
  int n0 = blockIdx.x * 128, m0 = blockIdx.y * 128;
  int wave = tid >> 6, lane = tid & 63;
  int wm = (wave & 1) * 64, wn = (wave >> 1) * 64;
  int r16 = lane & 15, quad = lane >> 4;
  int srow = tid >> 2, scq = tid & 3;

  f32x4 acc[4][4];
#pragma unroll
  for (int i = 0; i < 4; ++i)
#pragma unroll
    for (int j = 0; j < 4; ++j) acc[i][j] = {0.f, 0.f, 0.f, 0.f};

  for (int kt = 0; kt < K; kt += 32) {
    uint4 a0 = *(const uint4*)&A[(size_t)(m0 + srow) * K + kt + scq * 8];
    uint4 a1 = *(const uint4*)&A[(size_t)(m0 + 64 + srow) * K + kt + scq * 8];
    uint4 b0 = *(const uint4*)&BT[(size_t)(n0 + srow) * K + kt + scq * 8];
    uint4 b1 = *(const uint4*)&BT[(size_t)(n0 + 64 + srow) * K + kt + scq * 8];
    __syncthreads();
    *(uint4*)&As[srow][scq * 8] = a0;
    *(uint4*)&As[64 + srow][scq * 8] = a1;
    *(uint4*)&Bs[srow][scq * 8] = b0;
    *(uint4*)&Bs[64 + srow][scq * 8] = b1;
    __syncthreads();
    bfrag8 af[4], bq[4];
#pragma unroll
    for (int i = 0; i < 4; ++i) {
      af[i] = *(const bfrag8*)&As[wm + i * 16 + r16][quad * 8];
      bq[i] = *(const bfrag8*)&Bs[wn + i * 16 + r16][quad * 8];
    }
#pragma unroll
    for (int i = 0; i < 4; ++i)
#pragma unroll
      for (int j = 0; j < 4; ++j)
        acc[i][j] = __builtin_amdgcn_mfma_f32_16x16x32_bf16(af[i], bq[j],
                                                            acc[i][j], 0, 0, 0);
  }
  int kind = (n0 < 2048) ? 0 : (n0 < 5120) ? 1 : 2;  // block-uniform
#pragma unroll
  for (int i = 0; i < 4; ++i) {
#pragma unroll
    for (int r = 0; r < 4; ++r) {
      int row = m0 + wm + i * 16 + quad * 4 + r;
#pragma unroll
      for (int j = 0; j < 4; ++j) {
        int col = n0 + wn + j * 16 + r16;
        if (kind == 0)
          P32[(size_t)row * PS32 + col] = acc[i][j][r];
        else if (kind == 1)
          PB[(size_t)row * PSB + col - 2048] = f2bf(acc[i][j][r]);
        else
          SPRJ[(size_t)row * 128 + col - 5120] = acc[i][j][r];
      }
    }
  }
}

// ---------------------------------------------------------------------------
// Gates: sigmoid(logit + bias) for beta/g/gate; marker mask; head-mean of
// gate. One wave per row; lanes 0..15 beta, 16..31 g, 32..47 gate.
// ---------------------------------------------------------------------------
__global__ __launch_bounds__(256) void gates_kernel(
    const float* __restrict__ SPRJ, const float* __restrict__ bb,
    const float* __restrict__ bg, const float* __restrict__ bgt,
    const int* __restrict__ ids, float* __restrict__ beta,
    float* __restrict__ g, float* __restrict__ mg) {
  int row = blockIdx.x * 4 + (threadIdx.x >> 6);
  int lane = threadIdx.x & 63;
  if (lane < 48) {
    int h = lane & 15;
    float v = SPRJ[(size_t)row * 128 + lane];
    float bias = (lane < 16) ? bb[h] : (lane < 32) ? bg[h] : bgt[h];
    float s = 1.f / (1.f + __expf(-(v + bias)));
    if (lane < 16) {
      float mk = (ids[row] == MARKER_ID) ? 1.f : 0.1f;
      beta[(size_t)row * 16 + h] = s * mk;
    } else if (lane < 32) {
      g[(size_t)row * 16 + h] = s;
    } else {
      float sum = s;
#pragma unroll
      for (int off = 1; off < 16; off <<= 1) sum += __shfl_xor(sum, off);
      if (lane == 32) mg[row] = sum * (1.f / 16.f);
    }
  }
}

// ---------------------------------------------------------------------------
// L2-normalize rows of 64 (k_shared) inside P32 (stride 2048, cols 0..1023).
// ---------------------------------------------------------------------------
__global__ __launch_bounds__(256) void knorm_kernel(float* __restrict__ p32) {
  int w = blockIdx.x * 4 + (threadIdx.x >> 6);
  int lane = threadIdx.x & 63;
  size_t addr = (size_t)(w >> 4) * PS32 + (w & 15) * 64 + lane;
  float v = p32[addr];
  float ss = v * v;
#pragma unroll
  for (int off = 32; off; off >>= 1) ss += __shfl_xor(ss, off);
  float n = sqrtf(ss);
  n = fmaxf(n, 1e-12f);
  p32[addr] = v / n;
}

// ---------------------------------------------------------------------------
// MFMA flash sliding-window attention (as R6).
// ---------------------------------------------------------------------------
__global__ __launch_bounds__(256) void attn_mfma_kernel(
    const unsigned short* __restrict__ PB, unsigned short* __restrict__ ACAT) {
  __shared__ unsigned short Qs[64][72];
  __shared__ unsigned short Ks[64][72];
  __shared__ unsigned short Vt[64][72];
  __shared__ unsigned short Ps[64][72];
  int qb = blockIdx.x * 64;
  int bh = blockIdx.y;
  int h = bh & 15, b = bh >> 4;
  int tid = threadIdx.x, lane = tid & 63, wave = tid >> 6;
  int r16 = lane & 15, quad = lane >> 4;
  int m0w = wave * 16;
  const unsigned short* Qg = PB + (size_t)b * TT * PSB + h * 64;
  const unsigned short* Kg = Qg + 1024;
  const unsigned short* Vg = Qg + 2048;
  int sr = tid >> 2, sq = tid & 3;
  {
    *(uint4*)&Qs[sr][sq * 16] =
        *(const uint4*)&Qg[(size_t)(qb + sr) * PSB + sq * 16];
    *(uint4*)&Qs[sr][sq * 16 + 8] =
        *(const uint4*)&Qg[(size_t)(qb + sr) * PSB + sq * 16 + 8];
  }
  float m[4], l[4];
  f32x4 o[4];
#pragma unroll
  for (int r = 0; r < 4; ++r) {
    m[r] = -1e30f;
    l[r] = 0.f;
    o[r] = {0.f, 0.f, 0.f, 0.f};
  }
  int kt0 = qb - (int)WIN;
  if (kt0 < 0) kt0 = 0;

  for (int kt = kt0; kt <= qb; kt += 64) {
    __syncthreads();
    {
      *(uint4*)&Ks[sr][sq * 16] =
          *(const uint4*)&Kg[(size_t)(kt + sr) * PSB + sq * 16];
      *(uint4*)&Ks[sr][sq * 16 + 8] =
          *(const uint4*)&Kg[(size_t)(kt + sr) * PSB + sq * 16 + 8];
      union { uint4 u4[2]; unsigned short s[16]; } vv;
      vv.u4[0] = *(const uint4*)&Vg[(size_t)(kt + sr) * PSB + sq * 16];
      vv.u4[1] = *(const uint4*)&Vg[(size_t)(kt + sr) * PSB + sq * 16 + 8];
#pragma unroll
      for (int i = 0; i < 16; ++i) Vt[sq * 16 + i][sr] = vv.s[i];
    }
    __syncthreads();
    bfrag8 af0 = *(const bfrag8*)&Qs[m0w + r16][quad * 8];
    bfrag8 af1 = *(const bfrag8*)&Qs[m0w + r16][quad * 8 + 32];
    f32x4 s[4];
#pragma unroll
    for (int j = 0; j < 4; ++j) s[j] = {0.f, 0.f, 0.f, 0.f};
#pragma unroll
    for (int j = 0; j < 4; ++j) {
      bfrag8 b0 = *(const bfrag8*)&Ks[j * 16 + r16][quad * 8];
      bfrag8 b1 = *(const bfrag8*)&Ks[j * 16 + r16][quad * 8 + 32];
      s[j] = __builtin_amdgcn_mfma_f32_16x16x32_bf16(af0, b0, s[j], 0, 0, 0);
      s[j] = __builtin_amdgcn_mfma_f32_16x16x32_bf16(af1, b1, s[j], 0, 0, 0);
    }
    bool oldest = (kt == qb - (int)WIN);
    bool newest = (kt == qb);
#pragma unroll
    for (int r = 0; r < 4; ++r) {
      int il = m0w + quad * 4 + r;
      float sv[4];
#pragma unroll
      for (int j = 0; j < 4; ++j) {
        int jl = j * 16 + r16;
        float v = s[j][r] * 0.125f;
        if (oldest && jl < il) v = -1e30f;
        if (newest && jl > il) v = -1e30f;
        sv[j] = v;
      }
      float mx = fmaxf(fmaxf(sv[0], sv[1]), fmaxf(sv[2], sv[3]));
#pragma unroll
      for (int off = 1; off < 16; off <<= 1) mx = fmaxf(mx, __shfl_xor(mx, off));
      float mn = fmaxf(m[r], mx);
      float al = __expf(m[r] - mn);
      m[r] = mn;
      float rs = 0.f;
#pragma unroll
      for (int j = 0; j < 4; ++j) {
        float p = __expf(sv[j] - mn);
        rs += p;
        Ps[il][j * 16 + r16] = f2bf(p);
      }
#pragma unroll
      for (int off = 1; off < 16; off <<= 1) rs += __shfl_xor(rs, off);
      l[r] = l[r] * al + rs;
#pragma unroll
      for (int j = 0; j < 4; ++j) o[j][r] *= al;
    }
    bfrag8 pa0 = *(const bfrag8*)&Ps[m0w + r16][quad * 8];
    bfrag8 pa1 = *(const bfrag8*)&Ps[m0w + r16][quad * 8 + 32];
#pragma unroll
    for (int j = 0; j < 4; ++j) {
      bfrag8 v0 = *(const bfrag8*)&Vt[j * 16 + r16][quad * 8];
      bfrag8 v1 = *(const bfrag8*)&Vt[j * 16 + r16][quad * 8 + 32];
      o[j] = __builtin_amdgcn_mfma_f32_16x16x32_bf16(pa0, v0, o[j], 0, 0, 0);
      o[j] = __builtin_amdgcn_mfma_f32_16x16x32_bf16(pa1, v1, o[j], 0, 0, 0);
    }
  }
#pragma unroll
  for (int r = 0; r < 4; ++r) {
    int row = m0w + quad * 4 + r;
    float inv = 1.f / l[r];
#pragma unroll
    for (int j = 0; j < 4; ++j) {
      ACAT[((size_t)(b * TT + qb + row)) * PSB + 1024 + h * 64 + j * 16 + r16] =
          f2bf(o[j][r] * inv);
    }
  }
}

// ---------------------------------------------------------------------------
// Scan phase A (per (bh,chunk)): M, u_free, Z, P, Q, a. As R6.
// ---------------------------------------------------------------------------
__global__ __launch_bounds__(256) void scan_phaseA(
    const float* __restrict__ p32, const float* __restrict__ beta,
    const float* __restrict__ g, unsigned short* __restrict__ UFg,
    unsigned short* __restrict__ Zg, unsigned short* __restrict__ Pg,
    unsigned short* __restrict__ Qg, float* __restrict__ Ag) {
  __shared__ unsigned short Kc[64][72];
  __shared__ unsigned short KTb[64][72];
  __shared__ float Vc[64][68];
  __shared__ float Msv[64][68];
  __shared__ unsigned short UFT[64][72];
  __shared__ unsigned short ZTl[64][72];
  __shared__ float aArr[64], iaArr[64], bArr[64], baArr[64], sKT[64];
  __shared__ float aCs;

  int c = blockIdx.x, bh = blockIdx.y;
  int b = bh >> 4, h = bh & 15;
  int tc = c * 64;
  int tid = threadIdx.x, lane = tid & 63, wave = tid >> 6;
  int r16 = lane & 15, quad = lane >> 4;
  int m0w = wave * 16;
  size_t bhc = (size_t)bh * 16 + c;

  const float* kbase = p32 + ((size_t)b * TT) * PS32 + h * 64;
  const float* vbase = p32 + ((size_t)b * TT) * PS32 + 1024 + h * 64;
  const float* bbase = beta + ((size_t)b * TT) * HH + h;
  const float* gbase = g + ((size_t)b * TT) * HH + h;

  if (tid < 64) {
    int ts = tc + tid;
    bool pad = (ts > 1022);
    float gv = pad ? 1.f : gbase[(size_t)ts * HH];
    float bv = pad ? 0.f : bbase[(size_t)ts * HH];
    float p = gv;
#pragma unroll
    for (int o = 1; o < 64; o <<= 1) {
      float t = __shfl_up(p, o);
      if (lane >= o) p *= t;
    }
    aArr[tid] = p;
    iaArr[tid] = 1.f / p;
    bArr[tid] = bv;
    baArr[tid] = bv * p;
    float aC = __shfl(p, 63);
    sKT[tid] = aC / p;
    if (tid == 0) aCs = aC;
    Ag[bhc * 64 + tid] = p;
  }
  __syncthreads();
  {
    int r = tid >> 2, q = tid & 3;
    int ts = tc + r;
    float skt = sKT[r];
#pragma unroll
    for (int i = 0; i < 4; ++i) {
      float4 kv = *(const float4*)&kbase[(size_t)ts * PS32 + q * 16 + i * 4];
      ushort4 ku;
      ku.x = f2bf(kv.x); ku.y = f2bf(kv.y); ku.z = f2bf(kv.z); ku.w = f2bf(kv.w);
      *(ushort4*)&Kc[r][q * 16 + i * 4] = ku;
      KTb[q * 16 + i * 4 + 0][r] = f2bf(kv.x * skt);
      KTb[q * 16 + i * 4 + 1][r] = f2bf(kv.y * skt);
      KTb[q * 16 + i * 4 + 2][r] = f2bf(kv.z * skt);
      KTb[q * 16 + i * 4 + 3][r] = f2bf(kv.w * skt);
      float4 vv;
      if (ts <= 1022)
        vv = *(const float4*)&vbase[(size_t)(ts + 1) * PS32 + q * 16 + i * 4];
      else
        vv = make_float4(0.f, 0.f, 0.f, 0.f);
      *(float4*)&Vc[r][q * 16 + i * 4] = vv;
    }
  }
  __syncthreads();
  {
    bfrag8 af0 = *(const bfrag8*)&Kc[m0w + r16][quad * 8];
    bfrag8 af1 = *(const bfrag8*)&Kc[m0w + r16][quad * 8 + 32];
    f32x4 acc1[4];
#pragma unroll
    for (int j = 0; j < 4; ++j) acc1[j] = {0.f, 0.f, 0.f, 0.f};
#pragma unroll
    for (int j = 0; j < 4; ++j) {
      bfrag8 k0 = *(const bfrag8*)&Kc[j * 16 + r16][quad * 8];
      bfrag8 k1 = *(const bfrag8*)&Kc[j * 16 + r16][quad * 8 + 32];
      acc1[j] = __builtin_amdgcn_mfma_f32_16x16x32_bf16(af0, k0, acc1[j], 0, 0, 0);
      acc1[j] = __builtin_amdgcn_mfma_f32_16x16x32_bf16(af1, k1, acc1[j], 0, 0, 0);
    }
#pragma unroll
    for (int j = 0; j < 4; ++j) {
#pragma unroll
      for (int r = 0; r < 4; ++r) {
        int row = m0w + quad * 4 + r;
        int col = j * 16 + r16;
        Msv[row][col] =
            (col < row) ? bArr[row] * aArr[row] * iaArr[col] * acc1[j][r] : 0.f;
      }
    }
  }
  __syncthreads();
  if (wave < 2) {
    float u[64];
    if (wave == 0) {
#pragma unroll
      for (int t = 0; t < 64; ++t) u[t] = bArr[t] * Vc[t][lane];
    } else {
#pragma unroll
      for (int t = 0; t < 64; ++t) u[t] = baArr[t] * bf2f(Kc[t][lane]);
    }
#pragma unroll
    for (int t = 1; t < 64; ++t) {
      float a0 = 0.f, a1 = 0.f, a2 = 0.f, a3 = 0.f;
#pragma unroll
      for (int s4 = 0; s4 * 4 < t; ++s4) {
        float4 mr = *(const float4*)&Msv[t][s4 * 4];
        a0 = fmaf(mr.x, u[s4 * 4 + 0], a0);
        a1 = fmaf(mr.y, u[s4 * 4 + 1], a1);
        a2 = fmaf(mr.z, u[s4 * 4 + 2], a2);
        a3 = fmaf(mr.w, u[s4 * 4 + 3], a3);
      }
      u[t] -= (a0 + a1) + (a2 + a3);
    }
    unsigned short* Tls = (wave == 0) ? &UFT[lane][0] : &ZTl[lane][0];
#pragma unroll
    for (int t2 = 0; t2 < 32; ++t2) {
      unsigned int pk = (unsigned int)f2bf(u[2 * t2]) |
                        ((unsigned int)f2bf(u[2 * t2 + 1]) << 16);
      *(unsigned int*)&Tls[2 * t2] = pk;
    }
    unsigned short* Gn = (wave == 0) ? UFg : Zg;
#pragma unroll
    for (int t = 0; t < 64; ++t) {
      Gn[(bhc * 64 + t) * 64 + lane] = f2bf(u[t]);
    }
  }
  __syncthreads();
  {
    bfrag8 af0 = *(const bfrag8*)&KTb[m0w + r16][quad * 8];
    bfrag8 af1 = *(const bfrag8*)&KTb[m0w + r16][quad * 8 + 32];
    f32x4 accp[4], accq[4];
#pragma unroll
    for (int j = 0; j < 4; ++j) {
      accp[j] = {0.f, 0.f, 0.f, 0.f};
      accq[j] = {0.f, 0.f, 0.f, 0.f};
    }
#pragma unroll
    for (int j = 0; j < 4; ++j) {
      bfrag8 z0 = *(const bfrag8*)&ZTl[j * 16 + r16][quad * 8];
      bfrag8 z1 = *(const bfrag8*)&ZTl[j * 16 + r16][quad * 8 + 32];
      accp[j] = __builtin_amdgcn_mfma_f32_16x16x32_bf16(af0, z0, accp[j], 0, 0, 0);
      accp[j] = __builtin_amdgcn_mfma_f32_16x16x32_bf16(af1, z1, accp[j], 0, 0, 0);
      bfrag8 u0 = *(const bfrag8*)&UFT[j * 16 + r16][quad * 8];
      bfrag8 u1 = *(const bfrag8*)&UFT[j * 16 + r16][quad * 8 + 32];
      accq[j] = __builtin_amdgcn_mfma_f32_16x16x32_bf16(af0, u0, accq[j], 0, 0, 0);
      accq[j] = __builtin_amdgcn_mfma_f32_16x16x32_bf16(af1, u1, accq[j], 0, 0, 0);
    }
    float aC = aCs;
#pragma unroll
    for (int j = 0; j < 4; ++j) {
#pragma unroll
      for (int r = 0; r < 4; ++r) {
        int row = m0w + quad * 4 + r;
        int col = j * 16 + r16;
        float pv = ((row == col) ? aC : 0.f) - accp[j][r];
        Pg[bhc * 4096 + (size_t)row * 64 + col] = f2bf(pv);
        Qg[bhc * 4096 + (size_t)row * 64 + col] = f2bf(accq[j][r]);
      }
    }
  }
}

// ---------------------------------------------------------------------------
// Scan phase B: serial S_{c+1} = P_c S_c + Q_c (as R6).
// ---------------------------------------------------------------------------
__global__ __launch_bounds__(256) void scan_phaseB(
    const float* __restrict__ S0, const unsigned short* __restrict__ Pg,
    const unsigned short* __restrict__ Qg, unsigned short* __restrict__ SinTg,
    float* __restrict__ Sf, unsigned short* __restrict__ ACAT) {
  __shared__ unsigned short STb[64][72];
  __shared__ unsigned short Pl[64][72];
  int bh = blockIdx.x;
  int b = bh >> 4, h = bh & 15;
  int tid = threadIdx.x, lane = tid & 63, wave = tid >> 6;
  int r16 = lane & 15, quad = lane >> 4;
  int m0w = wave * 16;
  int rr = tid >> 2, qq = tid & 3;
  {
    const float* s0p = S0 + (size_t)bh * 4096;
#pragma unroll
    for (int i = 0; i < 4; ++i) {
      float4 sv = *(const float4*)&s0p[rr * 64 + qq * 16 + i * 4];
      STb[qq * 16 + i * 4 + 0][rr] = f2bf(sv.x);
      STb[qq * 16 + i * 4 + 1][rr] = f2bf(sv.y);
      STb[qq * 16 + i * 4 + 2][rr] = f2bf(sv.z);
      STb[qq * 16 + i * 4 + 3][rr] = f2bf(sv.w);
    }
    if (tid < 64) ACAT[((size_t)b * TT) * PSB + h * 64 + tid] = 0;
  }
  for (int c = 0; c < 16; ++c) {
    size_t bhc = (size_t)bh * 16 + c;
    __syncthreads();
    {
      uint4 s0v = *(const uint4*)&STb[rr][qq * 16];
      uint4 s1v = *(const uint4*)&STb[rr][qq * 16 + 8];
      *(uint4*)&SinTg[bhc * 4096 + (size_t)rr * 64 + qq * 16] = s0v;
      *(uint4*)&SinTg[bhc * 4096 + (size_t)rr * 64 + qq * 16 + 8] = s1v;
      uint4 p0 = *(const uint4*)&Pg[bhc * 4096 + (size_t)rr * 64 + qq * 16];
      uint4 p1 = *(const uint4*)&Pg[bhc * 4096 + (size_t)rr * 64 + qq * 16 + 8];
      *(uint4*)&Pl[rr][qq * 16] = p0;
      *(uint4*)&Pl[rr][qq * 16 + 8] = p1;
    }
    __syncthreads();
    f32x4 acc[4];
#pragma unroll
    for (int j = 0; j < 4; ++j) acc[j] = {0.f, 0.f, 0.f, 0.f};
    {
      bfrag8 af0 = *(const bfrag8*)&Pl[m0w + r16][quad * 8];
      bfrag8 af1 = *(const bfrag8*)&Pl[m0w + r16][quad * 8 + 32];
#pragma unroll
      for (int j = 0; j < 4; ++j) {
        bfrag8 s0v = *(const bfrag8*)&STb[j * 16 + r16][quad * 8];
        bfrag8 s1v = *(const bfrag8*)&STb[j * 16 + r16][quad * 8 + 32];
        acc[j] = __builtin_amdgcn_mfma_f32_16x16x32_bf16(af0, s0v, acc[j], 0, 0, 0);
        acc[j] = __builtin_amdgcn_mfma_f32_16x16x32_bf16(af1, s1v, acc[j], 0, 0, 0);
      }
    }
    float snew[4][4];
#pragma unroll
    for (int j = 0; j < 4; ++j) {
#pragma unroll
      for (int r = 0; r < 4; ++r) {
        int row = m0w + quad * 4 + r;
        int col = j * 16 + r16;
        snew[j][r] = acc[j][r] + bf2f(Qg[bhc * 4096 + (size_t)row * 64 + col]);
      }
    }
    __syncthreads();
#pragma unroll
    for (int j = 0; j < 4; ++j) {
#pragma unroll
      for (int r = 0; r < 4; ++r) {
        int row = m0w + quad * 4 + r;
        int col = j * 16 + r16;
        STb[col][row] = f2bf(snew[j][r]);
        if (c == 15) Sf[(size_t)bh * 4096 + (size_t)row * 64 + col] = snew[j][r];
      }
    }
  }
}

// ---------------------------------------------------------------------------
// Scan phase C: O = diag(a) K S_in + W U -> ACAT col 0 (as R6).
// ---------------------------------------------------------------------------
__global__ __launch_bounds__(256) void scan_phaseC(
    const float* __restrict__ p32, const unsigned short* __restrict__ UFg,
    const unsigned short* __restrict__ Zg,
    const unsigned short* __restrict__ SinTg, const float* __restrict__ Ag,
    unsigned short* __restrict__ ACAT) {
  __shared__ unsigned short Kc[64][72];
  __shared__ unsigned short SvT[64][72];
  __shared__ unsigned short Zl[64][72];
  __shared__ unsigned short Ufl[64][72];
  __shared__ unsigned short Wl[64][72];
  __shared__ unsigned short UTl[64][72];
  __shared__ float aA[64], iaA[64];

  int c = blockIdx.x, bh = blockIdx.y;
  int b = bh >> 4, h = bh & 15;
  int tc = c * 64;
  int tid = threadIdx.x, lane = tid & 63, wave = tid >> 6;
  int r16 = lane & 15, quad = lane >> 4;
  int m0w = wave * 16;
  size_t bhc = (size_t)bh * 16 + c;
  const float* kbase = p32 + ((size_t)b * TT) * PS32 + h * 64;

  if (tid < 64) {
    float av = Ag[bhc * 64 + tid];
    aA[tid] = av;
    iaA[tid] = 1.f / av;
  }
  {
    int r = tid >> 2, q = tid & 3;
    int ts = tc + r;
#pragma unroll
    for (int i = 0; i < 4; ++i) {
      float4 kv = *(const float4*)&kbase[(size_t)ts * PS32 + q * 16 + i * 4];
      ushort4 ku;
      ku.x = f2bf(kv.x); ku.y = f2bf(kv.y); ku.z = f2bf(kv.z); ku.w = f2bf(kv.w);
      *(ushort4*)&Kc[r][q * 16 + i * 4] = ku;
    }
    uint4 sv0 = *(const uint4*)&SinTg[bhc * 4096 + (size_t)r * 64 + q * 16];
    uint4 sv1 = *(const uint4*)&SinTg[bhc * 4096 + (size_t)r * 64 + q * 16 + 8];
    *(uint4*)&SvT[r][q * 16] = sv0;
    *(uint4*)&SvT[r][q * 16 + 8] = sv1;
    uint4 zv0 = *(const uint4*)&Zg[(bhc * 64 + r) * 64 + q * 16];
    uint4 zv1 = *(const uint4*)&Zg[(bhc * 64 + r) * 64 + q * 16 + 8];
    *(uint4*)&Zl[r][q * 16] = zv0;
    *(uint4*)&Zl[r][q * 16 + 8] = zv1;
    uint4 uv0 = *(const uint4*)&UFg[(bhc * 64 + r) * 64 + q * 16];
    uint4 uv1 = *(const uint4*)&UFg[(bhc * 64 + r) * 64 + q * 16 + 8];
    *(uint4*)&Ufl[r][q * 16] = uv0;
    *(uint4*)&Ufl[r][q * 16 + 8] = uv1;
  }
  __syncthreads();
  float op[4][4];
  {
    bfrag8 af0 = *(const bfrag8*)&Kc[m0w + r16][quad * 8];
    bfrag8 af1 = *(const bfrag8*)&Kc[m0w + r16][quad * 8 + 32];
    bfrag8 zf0 = *(const bfrag8*)&Zl[m0w + r16][quad * 8];
    bfrag8 zf1 = *(const bfrag8*)&Zl[m0w + r16][quad * 8 + 32];
    f32x4 acc1[4], acc2[4], acc3[4];
#pragma unroll
    for (int j = 0; j < 4; ++j) {
      acc1[j] = {0.f, 0.f, 0.f, 0.f};
      acc2[j] = {0.f, 0.f, 0.f, 0.f};
      acc3[j] = {0.f, 0.f, 0.f, 0.f};
    }
#pragma unroll
    for (int j = 0; j < 4; ++j) {
      bfrag8 k0 = *(const bfrag8*)&Kc[j * 16 + r16][quad * 8];
      bfrag8 k1 = *(const bfrag8*)&Kc[j * 16 + r16][quad * 8 + 32];
      acc1[j] = __builtin_amdgcn_mfma_f32_16x16x32_bf16(af0, k0, acc1[j], 0, 0, 0);
      acc1[j] = __builtin_amdgcn_mfma_f32_16x16x32_bf16(af1, k1, acc1[j], 0, 0, 0);
      bfrag8 s0 = *(const bfrag8*)&SvT[j * 16 + r16][quad * 8];
      bfrag8 s1 = *(const bfrag8*)&SvT[j * 16 + r16][quad * 8 + 32];
      acc3[j] = __builtin_amdgcn_mfma_f32_16x16x32_bf16(af0, s0, acc3[j], 0, 0, 0);
      acc3[j] = __builtin_amdgcn_mfma_f32_16x16x32_bf16(af1, s1, acc3[j], 0, 0, 0);
      acc2[j] = __builtin_amdgcn_mfma_f32_16x16x32_bf16(zf0, s0, acc2[j], 0, 0, 0);
      acc2[j] = __builtin_amdgcn_mfma_f32_16x16x32_bf16(zf1, s1, acc2[j], 0, 0, 0);
    }
#pragma unroll
    for (int j = 0; j < 4; ++j) {
#pragma unroll
      for (int r = 0; r < 4; ++r) {
        int row = m0w + quad * 4 + r;
        int col = j * 16 + r16;
        Wl[row][col] = (col <= row) ? f2bf(aA[row] * iaA[col] * acc1[j][r])
                                    : (unsigned short)0;
        float uval = bf2f(Ufl[row][col]) - acc2[j][r];
        UTl[col][row] = f2bf(uval);
        op[j][r] = aA[row] * acc3[j][r];
      }
    }
  }
  __syncthreads();
  {
    bfrag8 wf0 = *(const bfrag8*)&Wl[m0w + r16][quad * 8];
    bfrag8 wf1 = *(const bfrag8*)&Wl[m0w + r16][quad * 8 + 32];
    f32x4 acc4[4];
#pragma unroll
    for (int j = 0; j < 4; ++j) acc4[j] = {0.f, 0.f, 0.f, 0.f};
#pragma unroll
    for (int j = 0; j < 4; ++j) {
      bfrag8 u0 = *(const bfrag8*)&UTl[j * 16 + r16][quad * 8];
      bfrag8 u1 = *(const bfrag8*)&UTl[j * 16 + r16][quad * 8 + 32];
      acc4[j] = __builtin_amdgcn_mfma_f32_16x16x32_bf16(wf0, u0, acc4[j], 0, 0, 0);
      acc4[j] = __builtin_amdgcn_mfma_f32_16x16x32_bf16(wf1, u1, acc4[j], 0, 0, 0);
    }
#pragma unroll
    for (int j = 0; j < 4; ++j) {
#pragma unroll
      for (int r = 0; r < 4; ++r) {
        int row = m0w + quad * 4 + r;
        int col = j * 16 + r16;
        int ts = tc + row;
        if (ts < 1023) {
          ACAT[((size_t)b * TT + ts + 1) * PSB + h * 64 + col] =
              f2bf(op[j][r] + acc4[j][r]);
        }
      }
    }
  }
}

// ---------------------------------------------------------------------------
// retrieved = (k_shared @ Sf) * mg  -> ACAT col 2048 (bf16).
// ---------------------------------------------------------------------------
__global__ __launch_bounds__(256) void retrieve_kernel(
    const float* __restrict__ p32, const float* __restrict__ Sf,
    const float* __restrict__ mg, unsigned short* __restrict__ ACAT) {
  int w = blockIdx.x * 4 + (threadIdx.x >> 6);  // (b*T+t)*H + h
  int lane = threadIdx.x & 63;                  // v index
  int bt = w >> 4;
  float kl = p32[(size_t)bt * PS32 + (w & 15) * 64 + lane];
  int b = bt >> 10;
  int bh = b * 16 + (w & 15);
  const float* sfp = Sf + (size_t)bh * 4096;
  float acc = 0.f;
#pragma unroll
  for (int k = 0; k < 64; ++k) {
    float kk = __shfl(kl, k);
    acc = fmaf(kk, sfp[k * 64 + lane], acc);
  }
  ACAT[(size_t)bt * PSB + 2048 + (w & 15) * 64 + lane] = f2bf(acc * mg[bt]);
}

// ---------------------------------------------------------------------------
extern "C" void kernel_launch(void* const* d_in, const int* in_sizes, int n_in,
                              void* d_out, int out_size, void* d_ws,
                              size_t ws_size, hipStream_t stream) {
  (void)in_sizes; (void)n_in; (void)out_size; (void)ws_size;
  const float* x       = (const float*)d_in[0];
  const float* S0      = (const float*)d_in[1];
  const float* W_k     = (const float*)d_in[2];
  const float* W_v     = (const float*)d_in[3];
  const float* W_gdn_o = (const float*)d_in[4];
  const float* W_beta  = (const float*)d_in[5];
  const float* b_beta  = (const float*)d_in[6];
  const float* W_g     = (const float*)d_in[7];
  const float* b_g     = (const float*)d_in[8];
  const float* W_lq    = (const float*)d_in[9];
  const float* W_lk    = (const float*)d_in[10];
  const float* W_lv    = (const float*)d_in[11];
  const float* W_swa_o = (const float*)d_in[12];
  const float* W_ret_o = (const float*)d_in[13];
  const float* W_gate  = (const float*)d_in[14];
  const float* b_gate  = (const float*)d_in[15];
  const float* norm_w  = (const float*)d_in[16];
  const int*   ids     = (const int*)d_in[17];
  float* out = (float*)d_out;

  char* ws = (char*)d_ws;
  size_t off = 0;
  auto allocf = [&](size_t n) {
    float* p = (float*)(ws + off);
    off += n * sizeof(float);
    return p;
  };
  auto allocu = [&](size_t n) {
    unsigned short* p = (unsigned short*)(ws + off);
    off += n * sizeof(unsigned short);
    return p;
  };
  const int M = BB * TT;  // 4096
  unsigned short* XNb    = allocu((size_t)M * DD);
  float*          P32    = allocf((size_t)M * PS32);   // KSH | VF
  unsigned short* PB     = allocu((size_t)M * PSB);    // Q | KL | VL
  unsigned short* ACAT   = allocu((size_t)M * PSB);    // gdn | local | retr
  float*          SPRJ   = allocf((size_t)M * 128);    // gate logits
  unsigned short* WTcat5 = allocu((size_t)NPROJ * 1024);
  unsigned short* WTcat3 = allocu((size_t)1024 * PSB);
  float* BETA = allocf((size_t)M * HH);
  float* Gg   = allocf((size_t)M * HH);
  float* MG   = allocf((size_t)M);
  float* SF   = allocf((size_t)BB * HH * KK * VV);
  const size_t CH = (size_t)BB * HH * 16 * 64 * 64;
  unsigned short* UFg   = allocu(CH);
  unsigned short* Zg    = allocu(CH);
  unsigned short* Pg    = allocu(CH);
  unsigned short* Qg    = allocu(CH);
  unsigned short* SinTg = allocu(CH);
  float* Ag = allocf((size_t)BB * HH * 16 * 64);

  rmsnorm_kernel<<<M, 256, 0, stream>>>(x, norm_w, XNb);

  convert_wt_kernel<<<dim3(16, 16, 9), 256, 0, stream>>>(
      W_k, W_v, W_lq, W_lk, W_lv, W_gdn_o, W_swa_o, W_ret_o, W_beta, W_g,
      W_gate, WTcat5, WTcat3);

  gemm_proj_kernel<<<dim3(NPROJ / 128, M / 128), 256, 0, stream>>>(
      XNb, WTcat5, P32, PB, SPRJ);

  knorm_kernel<<<(M * HH) / 4, 256, 0, stream>>>(P32);
  gates_kernel<<<M / 4, 256, 0, stream>>>(SPRJ, b_beta, b_g, b_gate, ids, BETA,
                                          Gg, MG);

  scan_phaseA<<<dim3(16, BB * HH), 256, 0, stream>>>(P32, BETA, Gg, UFg, Zg, Pg,
                                                     Qg, Ag);
  scan_phaseB<<<BB * HH, 256, 0, stream>>>(S0, Pg, Qg, SinTg, SF, ACAT);
  scan_phaseC<<<dim3(16, BB * HH), 256, 0, stream>>>(P32, UFg, Zg, SinTg, Ag,
                                                     ACAT);

  attn_mfma_kernel<<<dim3(TT / 64, BB * HH), 256, 0, stream>>>(PB, ACAT);

  retrieve_kernel<<<(M * HH) / 4, 256, 0, stream>>>(P32, SF, MG, ACAT);

  // out = x + [gdn | local*0.3W | retr*mg] @ WTcat3^T  (K=3072, 512 blocks)
  gemm_out_kernel<<<dim3(16, 32), 256, 0, stream>>>(ACAT, WTcat3, out, x, M, DD,
                                                    3072);
}

// Round 8
// 433.439 us; speedup vs baseline: 7.4504x; 1.0230x over previous
//
#include <hip/hip_runtime.h>
#include <hip/hip_bf16.h>

// Problem constants
#define BB 4
#define TT 1024
#define DD 1024
#define HH 16
#define KK 64
#define VV 64
#define WIN 256
#define MARKER_ID 50251
#define PS32 2048  // fp32 proj buffer row stride (KSH | VF)
#define PSB 3072   // bf16 proj / epilogue-cat row stride
#define NPROJ 5248 // proj GEMM N: 2048 fp32 + 3072 bf16 + 128 gates(48+80 pad)

typedef short bfrag8 __attribute__((ext_vector_type(8)));
typedef float f32x4 __attribute__((ext_vector_type(4)));

static __device__ __forceinline__ unsigned short f2bf(float f) {
  __hip_bfloat16 h = __float2bfloat16(f);
  union { __hip_bfloat16 h; unsigned short u; } cv;
  cv.h = h;
  return cv.u;
}
static __device__ __forceinline__ float bf2f(unsigned short u) {
  union { unsigned int i; float f; } c;
  c.i = ((unsigned int)u) << 16;
  return c.f;
}
// Async global->LDS, 16B per lane. LDS dest = wave-uniform base + lane*16
// (m104/m108): lane l lands at row l/4, ushort col (l&3)*8 of an unpadded
// 64B-per-row tile.
static __device__ __forceinline__ void gld_lds16(const unsigned short* g,
                                                 unsigned short* l) {
  __builtin_amdgcn_global_load_lds(
      (const __attribute__((address_space(1))) void*)g,
      (__attribute__((address_space(3))) void*)l, 16, 0, 0);
}

// ---------------------------------------------------------------------------
// RMSNorm: xnb (bf16) = x / sqrt(mean(x^2)+eps) * norm_w. One block per row.
// ---------------------------------------------------------------------------
__global__ __launch_bounds__(256) void rmsnorm_kernel(
    const float* __restrict__ x, const float* __restrict__ nw,
    unsigned short* __restrict__ xnb) {
  int row = blockIdx.x;
  int tid = threadIdx.x;
  const float4* xr = (const float4*)(x + (size_t)row * DD);
  float4 v = xr[tid];
  float ss = v.x * v.x + v.y * v.y + v.z * v.z + v.w * v.w;
#pragma unroll
  for (int off = 32; off; off >>= 1) ss += __shfl_xor(ss, off);
  __shared__ float red[4];
  int wid = tid >> 6;
  if ((tid & 63) == 0) red[wid] = ss;
  __syncthreads();
  float tot = red[0] + red[1] + red[2] + red[3];
  float inv = 1.0f / sqrtf(tot * (1.0f / DD) + 1e-6f);
  const float4* wr = (const float4*)nw;
  float4 wv = wr[tid];
  ushort4 o;
  o.x = f2bf(v.x * inv * wv.x);
  o.y = f2bf(v.y * inv * wv.y);
  o.z = f2bf(v.z * inv * wv.z);
  o.w = f2bf(v.w * inv * wv.w);
  *(ushort4*)&xnb[(size_t)row * DD + tid * 4] = o;
}

// ---------------------------------------------------------------------------
// Convert + transpose weights fp32 [K][N] -> bf16 [N][K] into concatenated
// buffers. z=0..7: the 1024x1024 weights. z=8: small gate weights (48 rows)
// + zero-pad rows 5168..5247 of C5.
// ---------------------------------------------------------------------------
__global__ __launch_bounds__(256) void convert_wt_kernel(
    const float* W0, const float* W1, const float* W2, const float* W3,
    const float* W4, const float* W5, const float* W6, const float* W7,
    const float* Wb, const float* Wg, const float* Wgt,
    unsigned short* C5, unsigned short* C3) {
  int tid = threadIdx.x;
  if (blockIdx.z == 8) {
    if (blockIdx.x != 0) return;
    int k0 = blockIdx.y * 64;
    for (int e = tid; e < 3 * 16 * 64; e += 256) {
      int w = e >> 10;          // which weight
      int h = (e >> 6) & 15;    // head col
      int kk = e & 63;
      const float* Ws = (w == 0) ? Wb : (w == 1) ? Wg : Wgt;
      C5[(size_t)(5120 + w * 16 + h) * 1024 + k0 + kk] =
          f2bf(Ws[(size_t)(k0 + kk) * 16 + h]);
    }
    for (int e = tid; e < 80 * 64; e += 256) {
      int r = e >> 6, kk = e & 63;
      C5[(size_t)(5168 + r) * 1024 + k0 + kk] = 0;
    }
    return;
  }
  const float* W;
  unsigned short* T;
  int stride;
  float scale = 1.f;
  switch (blockIdx.z) {
    case 0: W = W0; T = C5 + 0 * 1024 * 1024; stride = 1024; break;
    case 1: W = W1; T = C5 + 1 * 1024 * 1024; stride = 1024; break;
    case 2: W = W2; T = C5 + 2 * 1024 * 1024; stride = 1024; break;
    case 3: W = W3; T = C5 + 3 * 1024 * 1024; stride = 1024; break;
    case 4: W = W4; T = C5 + 4 * 1024 * 1024; stride = 1024; break;
    case 5: W = W5; T = C3 + 0; stride = PSB; break;
    case 6: W = W6; T = C3 + 1024; stride = PSB; scale = 0.3f; break;
    default: W = W7; T = C3 + 2048; stride = PSB; break;
  }
  __shared__ float Ts[64][68];
  int n0 = blockIdx.x * 64, k0 = blockIdx.y * 64;
#pragma unroll
  for (int p = 0; p < 4; ++p) {
    int e = p * 256 + tid;
    int k = e >> 4, nq = e & 15;
    float4 w = *(const float4*)&W[(size_t)(k0 + k) * 1024 + n0 + nq * 4];
    Ts[nq * 4 + 0][k] = w.x;
    Ts[nq * 4 + 1][k] = w.y;
    Ts[nq * 4 + 2][k] = w.z;
    Ts[nq * 4 + 3][k] = w.w;
  }
  __syncthreads();
#pragma unroll
  for (int p = 0; p < 4; ++p) {
    int e = p * 256 + tid;
    int n = e >> 4, kq = e & 15;
    float4 v = *(const float4*)&Ts[n][kq * 4];
    ushort4 u;
    u.x = f2bf(v.x * scale);
    u.y = f2bf(v.y * scale);
    u.z = f2bf(v.z * scale);
    u.w = f2bf(v.w * scale);
    *(ushort4*)&T[(size_t)(n0 + n) * stride + k0 + kq * 4] = u;
  }
}

// ---------------------------------------------------------------------------
// Epilogue GEMM: out = x + ACAT[4096][3072] @ WTcat3[1024][3072]^T.
// 128M x 64N tile -> 512 blocks (2/CU). 4 waves of 32M x 64N.
// global_load_lds width=16 staging (m97 style, unpadded LDS).
// Grid MUST be (16, 32).
// ---------------------------------------------------------------------------
__global__ __launch_bounds__(256) void gemm_out_kernel(
    const unsigned short* __restrict__ A, const unsigned short* __restrict__ BT,
    float* __restrict__ C, const float* __restrict__ addp, int M, int N,
    int K) {
  __shared__ unsigned short As[128][32];
  __shared__ unsigned short Bs[64][32];
  int flat = blockIdx.y * gridDim.x + blockIdx.x;
  int xcd = flat & 7, local = flat >> 3;
  int m0 = (xcd * 4 + (local & 3)) * 128;
  int n0 = (local >> 2) * 64;
  int tid = threadIdx.x;
  int wave = tid >> 6, lane = tid & 63;
  int wm = wave * 32;
  int r16 = lane & 15, quad = lane >> 4;
  int lrow = lane >> 2, lcol = (lane & 3) * 8;

  f32x4 acc[2][4];
#pragma unroll
  for (int i = 0; i < 2; ++i)
#pragma unroll
    for (int j = 0; j < 4; ++j) acc[i][j] = {0.f, 0.f, 0.f, 0.f};

  for (int kt = 0; kt < K; kt += 32) {
    __syncthreads();  // previous iter frag reads done
#pragma unroll
    for (int q = 0; q < 2; ++q) {
      int rb = (wave * 2 + q) * 16;
      gld_lds16(&A[(size_t)(m0 + rb + lrow) * K + kt + lcol], &As[rb][0]);
    }
    {
      int rb = wave * 16;
      gld_lds16(&BT[(size_t)(n0 + rb + lrow) * K + kt + lcol], &Bs[rb][0]);
    }
    __syncthreads();  // vmcnt drained -> LDS valid
    bfrag8 af[2], bq[4];
#pragma unroll
    for (int i = 0; i < 2; ++i)
      af[i] = *(const bfrag8*)&As[wm + i * 16 + r16][quad * 8];
#pragma unroll
    for (int j = 0; j < 4; ++j)
      bq[j] = *(const bfrag8*)&Bs[j * 16 + r16][quad * 8];
#pragma unroll
    for (int i = 0; i < 2; ++i)
#pragma unroll
      for (int j = 0; j < 4; ++j)
        acc[i][j] = __builtin_amdgcn_mfma_f32_16x16x32_bf16(af[i], bq[j],
                                                            acc[i][j], 0, 0, 0);
  }
#pragma unroll
  for (int i = 0; i < 2; ++i) {
#pragma unroll
    for (int r = 0; r < 4; ++r) {
      int row = m0 + wm + i * 16 + quad * 4 + r;
#pragma unroll
      for (int j = 0; j < 4; ++j) {
        int col = n0 + j * 16 + r16;
        size_t idx = (size_t)row * N + col;
        C[idx] = addp[idx] + acc[i][j][r];
      }
    }
  }
}

// ---------------------------------------------------------------------------
// Fused projection GEMM: A=xn [4096][1024] bf16, BT=WTcat5 [5248][1024].
// global_load_lds width=16 staging (m97 style, unpadded LDS).
// cols 0..2047 fp32 -> P32 (KSH|VF); 2048..5119 bf16 -> PB (Q|KL|VL);
// 5120..5247 fp32 -> SPRJ (gate logits, stride 128).
// ---------------------------------------------------------------------------
__global__ __launch_bounds__(256) void gemm_proj_kernel(
    const unsigned short* __restrict__ A, const unsigned short* __restrict__ BT,
    float* __restrict__ P32, unsigned short* __restrict__ PB,
    float* __restrict__ SPRJ) {
  const int K = 1024;
  __shared__ unsigned short As[128][32];
  __shared__ unsigned short Bs[128][32];
  int tid = threadIdx.x;
  int n0 = blockIdx.x * 128, m0 = blockIdx.y * 128;
  int wave = tid >> 6, lane = tid & 63;
  int wm = (wave & 1) * 64, wn = (wave >> 1) * 64;
  int r16 = lane & 15, quad = lane >> 4;
  int lrow = lane >> 2, lcol = (lane & 3) * 8;

  f32x4 acc[4][4];
#pragma unroll
  for (int i = 0; i < 4; ++i)
#pragma unroll
    for (int j = 0; j < 4; ++j) acc[i][j] = {0.f, 0.f, 0.f, 0.f};

  for (int kt = 0; kt < K; kt += 32) {
    __syncthreads();  // previous iter frag reads done
#pragma unroll
    for (int q = 0; q < 2; ++q) {
      int rb = (wave * 2 + q) * 16;
      gld_lds16(&A[(size_t)(m0 + rb + lrow) * K + kt + lcol], &As[rb][0]);
      gld_lds16(&BT[(size_t)(n0 + rb + lrow) * K + kt + lcol], &Bs[rb][0]);
    }
    __syncthreads();  // vmcnt drained -> LDS valid
    bfrag8 af[4], bq[4];
#pragma unroll
    for (int i = 0; i < 4; ++i) {
      af[i] = *(const bfrag8*)&As[wm + i * 16 + r16][quad * 8];
      bq[i] = *(const bfrag8*)&Bs[wn + i * 16 + r16][quad * 8];
    }
#pragma unroll
    for (int i = 0; i < 4; ++i)
#pragma unroll
      for (int j = 0; j < 4; ++j)
        acc[i][j] = __builtin_amdgcn_mfma_f32_16x16x32_bf16(af[i], bq[j],
                                                            acc[i][j], 0, 0, 0);
  }
  int kind = (n0 < 2048) ? 0 : (n0 < 5120) ? 1 : 2;  // block-uniform
#pragma unroll
  for (int i = 0; i < 4; ++i) {
#pragma unroll
    for (int r = 0; r < 4; ++r) {
      int row = m0 + wm + i * 16 + quad * 4 + r;
#pragma unroll
      for (int j = 0; j < 4; ++j) {
        int col = n0 + wn + j * 16 + r16;
        if (kind == 0)
          P32[(size_t)row * PS32 + col] = acc[i][j][r];
        else if (kind == 1)
          PB[(size_t)row * PSB + col - 2048] = f2bf(acc[i][j][r]);
        else
          SPRJ[(size_t)row * 128 + col - 5120] = acc[i][j][r];
      }
    }
  }
}

// ---------------------------------------------------------------------------
// Gates: sigmoid(logit + bias) for beta/g/gate; marker mask; head-mean of
// gate. One wave per row; lanes 0..15 beta, 16..31 g, 32..47 gate.
// ---------------------------------------------------------------------------
__global__ __launch_bounds__(256) void gates_kernel(
    const float* __restrict__ SPRJ, const float* __restrict__ bb,
    const float* __restrict__ bg, const float* __restrict__ bgt,
    const int* __restrict__ ids, float* __restrict__ beta,
    float* __restrict__ g, float* __restrict__ mg) {
  int row = blockIdx.x * 4 + (threadIdx.x >> 6);
  int lane = threadIdx.x & 63;
  if (lane < 48) {
    int h = lane & 15;
    float v = SPRJ[(size_t)row * 128 + lane];
    float bias = (lane < 16) ? bb[h] : (lane < 32) ? bg[h] : bgt[h];
    float s = 1.f / (1.f + __expf(-(v + bias)));
    if (lane < 16) {
      float mk = (ids[row] == MARKER_ID) ? 1.f : 0.1f;
      beta[(size_t)row * 16 + h] = s * mk;
    } else if (lane < 32) {
      g[(size_t)row * 16 + h] = s;
    } else {
      float sum = s;
#pragma unroll
      for (int off = 1; off < 16; off <<= 1) sum += __shfl_xor(sum, off);
      if (lane == 32) mg[row] = sum * (1.f / 16.f);
    }
  }
}

// ---------------------------------------------------------------------------
// L2-normalize rows of 64 (k_shared) inside P32 (stride 2048, cols 0..1023).
// ---------------------------------------------------------------------------
__global__ __launch_bounds__(256) void knorm_kernel(float* __restrict__ p32) {
  int w = blockIdx.x * 4 + (threadIdx.x >> 6);
  int lane = threadIdx.x & 63;
  size_t addr = (size_t)(w >> 4) * PS32 + (w & 15) * 64 + lane;
  float v = p32[addr];
  float ss = v * v;
#pragma unroll
  for (int off = 32; off; off >>= 1) ss += __shfl_xor(ss, off);
  float n = sqrtf(ss);
  n = fmaxf(n, 1e-12f);
  p32[addr] = v / n;
}

// ---------------------------------------------------------------------------
// MFMA flash sliding-window attention (as R6/R7).
// ---------------------------------------------------------------------------
__global__ __launch_bounds__(256) void attn_mfma_kernel(
    const unsigned short* __restrict__ PB, unsigned short* __restrict__ ACAT) {
  __shared__ unsigned short Qs[64][72];
  __shared__ unsigned short Ks[64][72];
  __shared__ unsigned short Vt[64][72];
  __shared__ unsigned short Ps[64][72];
  int qb = blockIdx.x * 64;
  int bh = blockIdx.y;
  int h = bh & 15, b = bh >> 4;
  int tid = threadIdx.x, lane = tid & 63, wave = tid >> 6;
  int r16 = lane & 15, quad = lane >> 4;
  int m0w = wave * 16;
  const unsigned short* Qg = PB + (size_t)b * TT * PSB + h * 64;
  const unsigned short* Kg = Qg + 1024;
  const unsigned short* Vg = Qg + 2048;
  int sr = tid >> 2, sq = tid & 3;
  {
    *(uint4*)&Qs[sr][sq * 16] =
        *(const uint4*)&Qg[(size_t)(qb + sr) * PSB + sq * 16];
    *(uint4*)&Qs[sr][sq * 16 + 8] =
        *(const uint4*)&Qg[(size_t)(qb + sr) * PSB + sq * 16 + 8];
  }
  float m[4], l[4];
  f32x4 o[4];
#pragma unroll
  for (int r = 0; r < 4; ++r) {
    m[r] = -1e30f;
    l[r] = 0.f;
    o[r] = {0.f, 0.f, 0.f, 0.f};
  }
  int kt0 = qb - (int)WIN;
  if (kt0 < 0) kt0 = 0;

  for (int kt = kt0; kt <= qb; kt += 64) {
    __syncthreads();
    {
      *(uint4*)&Ks[sr][sq * 16] =
          *(const uint4*)&Kg[(size_t)(kt + sr) * PSB + sq * 16];
      *(uint4*)&Ks[sr][sq * 16 + 8] =
          *(const uint4*)&Kg[(size_t)(kt + sr) * PSB + sq * 16 + 8];
      union { uint4 u4[2]; unsigned short s[16]; } vv;
      vv.u4[0] = *(const uint4*)&Vg[(size_t)(kt + sr) * PSB + sq * 16];
      vv.u4[1] = *(const uint4*)&Vg[(size_t)(kt + sr) * PSB + sq * 16 + 8];
#pragma unroll
      for (int i = 0; i < 16; ++i) Vt[sq * 16 + i][sr] = vv.s[i];
    }
    __syncthreads();
    bfrag8 af0 = *(const bfrag8*)&Qs[m0w + r16][quad * 8];
    bfrag8 af1 = *(const bfrag8*)&Qs[m0w + r16][quad * 8 + 32];
    f32x4 s[4];
#pragma unroll
    for (int j = 0; j < 4; ++j) s[j] = {0.f, 0.f, 0.f, 0.f};
#pragma unroll
    for (int j = 0; j < 4; ++j) {
      bfrag8 b0 = *(const bfrag8*)&Ks[j * 16 + r16][quad * 8];
      bfrag8 b1 = *(const bfrag8*)&Ks[j * 16 + r16][quad * 8 + 32];
      s[j] = __builtin_amdgcn_mfma_f32_16x16x32_bf16(af0, b0, s[j], 0, 0, 0);
      s[j] = __builtin_amdgcn_mfma_f32_16x16x32_bf16(af1, b1, s[j], 0, 0, 0);
    }
    bool oldest = (kt == qb - (int)WIN);
    bool newest = (kt == qb);
#pragma unroll
    for (int r = 0; r < 4; ++r) {
      int il = m0w + quad * 4 + r;
      float sv[4];
#pragma unroll
      for (int j = 0; j < 4; ++j) {
        int jl = j * 16 + r16;
        float v = s[j][r] * 0.125f;
        if (oldest && jl < il) v = -1e30f;
        if (newest && jl > il) v = -1e30f;
        sv[j] = v;
      }
      float mx = fmaxf(fmaxf(sv[0], sv[1]), fmaxf(sv[2], sv[3]));
#pragma unroll
      for (int off = 1; off < 16; off <<= 1) mx = fmaxf(mx, __shfl_xor(mx, off));
      float mn = fmaxf(m[r], mx);
      float al = __expf(m[r] - mn);
      m[r] = mn;
      float rs = 0.f;
#pragma unroll
      for (int j = 0; j < 4; ++j) {
        float p = __expf(sv[j] - mn);
        rs += p;
        Ps[il][j * 16 + r16] = f2bf(p);
      }
#pragma unroll
      for (int off = 1; off < 16; off <<= 1) rs += __shfl_xor(rs, off);
      l[r] = l[r] * al + rs;
#pragma unroll
      for (int j = 0; j < 4; ++j) o[j][r] *= al;
    }
    bfrag8 pa0 = *(const bfrag8*)&Ps[m0w + r16][quad * 8];
    bfrag8 pa1 = *(const bfrag8*)&Ps[m0w + r16][quad * 8 + 32];
#pragma unroll
    for (int j = 0; j < 4; ++j) {
      bfrag8 v0 = *(const bfrag8*)&Vt[j * 16 + r16][quad * 8];
      bfrag8 v1 = *(const bfrag8*)&Vt[j * 16 + r16][quad * 8 + 32];
      o[j] = __builtin_amdgcn_mfma_f32_16x16x32_bf16(pa0, v0, o[j], 0, 0, 0);
      o[j] = __builtin_amdgcn_mfma_f32_16x16x32_bf16(pa1, v1, o[j], 0, 0, 0);
    }
  }
#pragma unroll
  for (int r = 0; r < 4; ++r) {
    int row = m0w + quad * 4 + r;
    float inv = 1.f / l[r];
#pragma unroll
    for (int j = 0; j < 4; ++j) {
      ACAT[((size_t)(b * TT + qb + row)) * PSB + 1024 + h * 64 + j * 16 + r16] =
          f2bf(o[j][r] * inv);
    }
  }
}

// ---------------------------------------------------------------------------
// Scan phase A (per (bh,chunk)): M, u_free, Z, P, Q, a. As R6/R7.
// ---------------------------------------------------------------------------
__global__ __launch_bounds__(256) void scan_phaseA(
    const float* __restrict__ p32, const float* __restrict__ beta,
    const float* __restrict__ g, unsigned short* __restrict__ UFg,
    unsigned short* __restrict__ Zg, unsigned short* __restrict__ Pg,
    unsigned short* __restrict__ Qg, float* __restrict__ Ag) {
  __shared__ unsigned short Kc[64][72];
  __shared__ unsigned short KTb[64][72];
  __shared__ float Vc[64][68];
  __shared__ float Msv[64][68];
  __shared__ unsigned short UFT[64][72];
  __shared__ unsigned short ZTl[64][72];
  __shared__ float aArr[64], iaArr[64], bArr[64], baArr[64], sKT[64];
  __shared__ float aCs;

  int c = blockIdx.x, bh = blockIdx.y;
  int b = bh >> 4, h = bh & 15;
  int tc = c * 64;
  int tid = threadIdx.x, lane = tid & 63, wave = tid >> 6;
  int r16 = lane & 15, quad = lane >> 4;
  int m0w = wave * 16;
  size_t bhc = (size_t)bh * 16 + c;

  const float* kbase = p32 + ((size_t)b * TT) * PS32 + h * 64;
  const float* vbase = p32 + ((size_t)b * TT) * PS32 + 1024 + h * 64;
  const float* bbase = beta + ((size_t)b * TT) * HH + h;
  const float* gbase = g + ((size_t)b * TT) * HH + h;

  if (tid < 64) {
    int ts = tc + tid;
    bool pad = (ts > 1022);
    float gv = pad ? 1.f : gbase[(size_t)ts * HH];
    float bv = pad ? 0.f : bbase[(size_t)ts * HH];
    float p = gv;
#pragma unroll
    for (int o = 1; o < 64; o <<= 1) {
      float t = __shfl_up(p, o);
      if (lane >= o) p *= t;
    }
    aArr[tid] = p;
    iaArr[tid] = 1.f / p;
    bArr[tid] = bv;
    baArr[tid] = bv * p;
    float aC = __shfl(p, 63);
    sKT[tid] = aC / p;
    if (tid == 0) aCs = aC;
    Ag[bhc * 64 + tid] = p;
  }
  __syncthreads();
  {
    int r = tid >> 2, q = tid & 3;
    int ts = tc + r;
    float skt = sKT[r];
#pragma unroll
    for (int i = 0; i < 4; ++i) {
      float4 kv = *(const float4*)&kbase[(size_t)ts * PS32 + q * 16 + i * 4];
      ushort4 ku;
      ku.x = f2bf(kv.x); ku.y = f2bf(kv.y); ku.z = f2bf(kv.z); ku.w = f2bf(kv.w);
      *(ushort4*)&Kc[r][q * 16 + i * 4] = ku;
      KTb[q * 16 + i * 4 + 0][r] = f2bf(kv.x * skt);
      KTb[q * 16 + i * 4 + 1][r] = f2bf(kv.y * skt);
      KTb[q * 16 + i * 4 + 2][r] = f2bf(kv.z * skt);
      KTb[q * 16 + i * 4 + 3][r] = f2bf(kv.w * skt);
      float4 vv;
      if (ts <= 1022)
        vv = *(const float4*)&vbase[(size_t)(ts + 1) * PS32 + q * 16 + i * 4];
      else
        vv = make_float4(0.f, 0.f, 0.f, 0.f);
      *(float4*)&Vc[r][q * 16 + i * 4] = vv;
    }
  }
  __syncthreads();
  {
    bfrag8 af0 = *(const bfrag8*)&Kc[m0w + r16][quad * 8];
    bfrag8 af1 = *(const bfrag8*)&Kc[m0w + r16][quad * 8 + 32];
    f32x4 acc1[4];
#pragma unroll
    for (int j = 0; j < 4; ++j) acc1[j] = {0.f, 0.f, 0.f, 0.f};
#pragma unroll
    for (int j = 0; j < 4; ++j) {
      bfrag8 k0 = *(const bfrag8*)&Kc[j * 16 + r16][quad * 8];
      bfrag8 k1 = *(const bfrag8*)&Kc[j * 16 + r16][quad * 8 + 32];
      acc1[j] = __builtin_amdgcn_mfma_f32_16x16x32_bf16(af0, k0, acc1[j], 0, 0, 0);
      acc1[j] = __builtin_amdgcn_mfma_f32_16x16x32_bf16(af1, k1, acc1[j], 0, 0, 0);
    }
#pragma unroll
    for (int j = 0; j < 4; ++j) {
#pragma unroll
      for (int r = 0; r < 4; ++r) {
        int row = m0w + quad * 4 + r;
        int col = j * 16 + r16;
        Msv[row][col] =
            (col < row) ? bArr[row] * aArr[row] * iaArr[col] * acc1[j][r] : 0.f;
      }
    }
  }
  __syncthreads();
  if (wave < 2) {
    float u[64];
    if (wave == 0) {
#pragma unroll
      for (int t = 0; t < 64; ++t) u[t] = bArr[t] * Vc[t][lane];
    } else {
#pragma unroll
      for (int t = 0; t < 64; ++t) u[t] = baArr[t] * bf2f(Kc[t][lane]);
    }
#pragma unroll
    for (int t = 1; t < 64; ++t) {
      float a0 = 0.f, a1 = 0.f, a2 = 0.f, a3 = 0.f;
#pragma unroll
      for (int s4 = 0; s4 * 4 < t; ++s4) {
        float4 mr = *(const float4*)&Msv[t][s4 * 4];
        a0 = fmaf(mr.x, u[s4 * 4 + 0], a0);
        a1 = fmaf(mr.y, u[s4 * 4 + 1], a1);
        a2 = fmaf(mr.z, u[s4 * 4 + 2], a2);
        a3 = fmaf(mr.w, u[s4 * 4 + 3], a3);
      }
      u[t] -= (a0 + a1) + (a2 + a3);
    }
    unsigned short* Tls = (wave == 0) ? &UFT[lane][0] : &ZTl[lane][0];
#pragma unroll
    for (int t2 = 0; t2 < 32; ++t2) {
      unsigned int pk = (unsigned int)f2bf(u[2 * t2]) |
                        ((unsigned int)f2bf(u[2 * t2 + 1]) << 16);
      *(unsigned int*)&Tls[2 * t2] = pk;
    }
    unsigned short* Gn = (wave == 0) ? UFg : Zg;
#pragma unroll
    for (int t = 0; t < 64; ++t) {
      Gn[(bhc * 64 + t) * 64 + lane] = f2bf(u[t]);
    }
  }
  __syncthreads();
  {
    bfrag8 af0 = *(const bfrag8*)&KTb[m0w + r16][quad * 8];
    bfrag8 af1 = *(const bfrag8*)&KTb[m0w + r16][quad * 8 + 32];
    f32x4 accp[4], accq[4];
#pragma unroll
    for (int j = 0; j < 4; ++j) {
      accp[j] = {0.f, 0.f, 0.f, 0.f};
      accq[j] = {0.f, 0.f, 0.f, 0.f};
    }
#pragma unroll
    for (int j = 0; j < 4; ++j) {
      bfrag8 z0 = *(const bfrag8*)&ZTl[j * 16 + r16][quad * 8];
      bfrag8 z1 = *(const bfrag8*)&ZTl[j * 16 + r16][quad * 8 + 32];
      accp[j] = __builtin_amdgcn_mfma_f32_16x16x32_bf16(af0, z0, accp[j], 0, 0, 0);
      accp[j] = __builtin_amdgcn_mfma_f32_16x16x32_bf16(af1, z1, accp[j], 0, 0, 0);
      bfrag8 u0 = *(const bfrag8*)&UFT[j * 16 + r16][quad * 8];
      bfrag8 u1 = *(const bfrag8*)&UFT[j * 16 + r16][quad * 8 + 32];
      accq[j] = __builtin_amdgcn_mfma_f32_16x16x32_bf16(af0, u0, accq[j], 0, 0, 0);
      accq[j] = __builtin_amdgcn_mfma_f32_16x16x32_bf16(af1, u1, accq[j], 0, 0, 0);
    }
    float aC = aCs;
#pragma unroll
    for (int j = 0; j < 4; ++j) {
#pragma unroll
      for (int r = 0; r < 4; ++r) {
        int row = m0w + quad * 4 + r;
        int col = j * 16 + r16;
        float pv = ((row == col) ? aC : 0.f) - accp[j][r];
        Pg[bhc * 4096 + (size_t)row * 64 + col] = f2bf(pv);
        Qg[bhc * 4096 + (size_t)row * 64 + col] = f2bf(accq[j][r]);
      }
    }
  }
}

// ---------------------------------------------------------------------------
// Scan phase B: serial S_{c+1} = P_c S_c + Q_c (as R6/R7).
// ---------------------------------------------------------------------------
__global__ __launch_bounds__(256) void scan_phaseB(
    const float* __restrict__ S0, const unsigned short* __restrict__ Pg,
    const unsigned short* __restrict__ Qg, unsigned short* __restrict__ SinTg,
    float* __restrict__ Sf, unsigned short* __restrict__ ACAT) {
  __shared__ unsigned short STb[64][72];
  __shared__ unsigned short Pl[64][72];
  int bh = blockIdx.x;
  int b = bh >> 4, h = bh & 15;
  int tid = threadIdx.x, lane = tid & 63, wave = tid >> 6;
  int r16 = lane & 15, quad = lane >> 4;
  int m0w = wave * 16;
  int rr = tid >> 2, qq = tid & 3;
  {
    const float* s0p = S0 + (size_t)bh * 4096;
#pragma unroll
    for (int i = 0; i < 4; ++i) {
      float4 sv = *(const float4*)&s0p[rr * 64 + qq * 16 + i * 4];
      STb[qq * 16 + i * 4 + 0][rr] = f2bf(sv.x);
      STb[qq * 16 + i * 4 + 1][rr] = f2bf(sv.y);
      STb[qq * 16 + i * 4 + 2][rr] = f2bf(sv.z);
      STb[qq * 16 + i * 4 + 3][rr] = f2bf(sv.w);
    }
    if (tid < 64) ACAT[((size_t)b * TT) * PSB + h * 64 + tid] = 0;
  }
  for (int c = 0; c < 16; ++c) {
    size_t bhc = (size_t)bh * 16 + c;
    __syncthreads();
    {
      uint4 s0v = *(const uint4*)&STb[rr][qq * 16];
      uint4 s1v = *(const uint4*)&STb[rr][qq * 16 + 8];
      *(uint4*)&SinTg[bhc * 4096 + (size_t)rr * 64 + qq * 16] = s0v;
      *(uint4*)&SinTg[bhc * 4096 + (size_t)rr * 64 + qq * 16 + 8] = s1v;
      uint4 p0 = *(const uint4*)&Pg[bhc * 4096 + (size_t)rr * 64 + qq * 16];
      uint4 p1 = *(const uint4*)&Pg[bhc * 4096 + (size_t)rr * 64 + qq * 16 + 8];
      *(uint4*)&Pl[rr][qq * 16] = p0;
      *(uint4*)&Pl[rr][qq * 16 + 8] = p1;
    }
    __syncthreads();
    f32x4 acc[4];
#pragma unroll
    for (int j = 0; j < 4; ++j) acc[j] = {0.f, 0.f, 0.f, 0.f};
    {
      bfrag8 af0 = *(const bfrag8*)&Pl[m0w + r16][quad * 8];
      bfrag8 af1 = *(const bfrag8*)&Pl[m0w + r16][quad * 8 + 32];
#pragma unroll
      for (int j = 0; j < 4; ++j) {
        bfrag8 s0v = *(const bfrag8*)&STb[j * 16 + r16][quad * 8];
        bfrag8 s1v = *(const bfrag8*)&STb[j * 16 + r16][quad * 8 + 32];
        acc[j] = __builtin_amdgcn_mfma_f32_16x16x32_bf16(af0, s0v, acc[j], 0, 0, 0);
        acc[j] = __builtin_amdgcn_mfma_f32_16x16x32_bf16(af1, s1v, acc[j], 0, 0, 0);
      }
    }
    float snew[4][4];
#pragma unroll
    for (int j = 0; j < 4; ++j) {
#pragma unroll
      for (int r = 0; r < 4; ++r) {
        int row = m0w + quad * 4 + r;
        int col = j * 16 + r16;
        snew[j][r] = acc[j][r] + bf2f(Qg[bhc * 4096 + (size_t)row * 64 + col]);
      }
    }
    __syncthreads();
#pragma unroll
    for (int j = 0; j < 4; ++j) {
#pragma unroll
      for (int r = 0; r < 4; ++r) {
        int row = m0w + quad * 4 + r;
        int col = j * 16 + r16;
        STb[col][row] = f2bf(snew[j][r]);
        if (c == 15) Sf[(size_t)bh * 4096 + (size_t)row * 64 + col] = snew[j][r];
      }
    }
  }
}

// ---------------------------------------------------------------------------
// Scan phase C: O = diag(a) K S_in + W U -> ACAT col 0 (as R6/R7).
// ---------------------------------------------------------------------------
__global__ __launch_bounds__(256) void scan_phaseC(
    const float* __restrict__ p32, const unsigned short* __restrict__ UFg,
    const unsigned short* __restrict__ Zg,
    const unsigned short* __restrict__ SinTg, const float* __restrict__ Ag,
    unsigned short* __restrict__ ACAT) {
  __shared__ unsigned short Kc[64][72];
  __shared__ unsigned short SvT[64][72];
  __shared__ unsigned short Zl[64][72];
  __shared__ unsigned short Ufl[64][72];
  __shared__ unsigned short Wl[64][72];
  __shared__ unsigned short UTl[64][72];
  __shared__ float aA[64], iaA[64];

  int c = blockIdx.x, bh = blockIdx.y;
  int b = bh >> 4, h = bh & 15;
  int tc = c * 64;
  int tid = threadIdx.x, lane = tid & 63, wave = tid >> 6;
  int r16 = lane & 15, quad = lane >> 4;
  int m0w = wave * 16;
  size_t bhc = (size_t)bh * 16 + c;
  const float* kbase = p32 + ((size_t)b * TT) * PS32 + h * 64;

  if (tid < 64) {
    float av = Ag[bhc * 64 + tid];
    aA[tid] = av;
    iaA[tid] = 1.f / av;
  }
  {
    int r = tid >> 2, q = tid & 3;
    int ts = tc + r;
#pragma unroll
    for (int i = 0; i < 4; ++i) {
      float4 kv = *(const float4*)&kbase[(size_t)ts * PS32 + q * 16 + i * 4];
      ushort4 ku;
      ku.x = f2bf(kv.x); ku.y = f2bf(kv.y); ku.z = f2bf(kv.z); ku.w = f2bf(kv.w);
      *(ushort4*)&Kc[r][q * 16 + i * 4] = ku;
    }
    uint4 sv0 = *(const uint4*)&SinTg[bhc * 4096 + (size_t)r * 64 + q * 16];
    uint4 sv1 = *(const uint4*)&SinTg[bhc * 4096 + (size_t)r * 64 + q * 16 + 8];
    *(uint4*)&SvT[r][q * 16] = sv0;
    *(uint4*)&SvT[r][q * 16 + 8] = sv1;
    uint4 zv0 = *(const uint4*)&Zg[(bhc * 64 + r) * 64 + q * 16];
    uint4 zv1 = *(const uint4*)&Zg[(bhc * 64 + r) * 64 + q * 16 + 8];
    *(uint4*)&Zl[r][q * 16] = zv0;
    *(uint4*)&Zl[r][q * 16 + 8] = zv1;
    uint4 uv0 = *(const uint4*)&UFg[(bhc * 64 + r) * 64 + q * 16];
    uint4 uv1 = *(const uint4*)&UFg[(bhc * 64 + r) * 64 + q * 16 + 8];
    *(uint4*)&Ufl[r][q * 16] = uv0;
    *(uint4*)&Ufl[r][q * 16 + 8] = uv1;
  }
  __syncthreads();
  float op[4][4];
  {
    bfrag8 af0 = *(const bfrag8*)&Kc[m0w + r16][quad * 8];
    bfrag8 af1 = *(const bfrag8*)&Kc[m0w + r16][quad * 8 + 32];
    bfrag8 zf0 = *(const bfrag8*)&Zl[m0w + r16][quad * 8];
    bfrag8 zf1 = *(const bfrag8*)&Zl[m0w + r16][quad * 8 + 32];
    f32x4 acc1[4], acc2[4], acc3[4];
#pragma unroll
    for (int j = 0; j < 4; ++j) {
      acc1[j] = {0.f, 0.f, 0.f, 0.f};
      acc2[j] = {0.f, 0.f, 0.f, 0.f};
      acc3[j] = {0.f, 0.f, 0.f, 0.f};
    }
#pragma unroll
    for (int j = 0; j < 4; ++j) {
      bfrag8 k0 = *(const bfrag8*)&Kc[j * 16 + r16][quad * 8];
      bfrag8 k1 = *(const bfrag8*)&Kc[j * 16 + r16][quad * 8 + 32];
      acc1[j] = __builtin_amdgcn_mfma_f32_16x16x32_bf16(af0, k0, acc1[j], 0, 0, 0);
      acc1[j] = __builtin_amdgcn_mfma_f32_16x16x32_bf16(af1, k1, acc1[j], 0, 0, 0);
      bfrag8 s0 = *(const bfrag8*)&SvT[j * 16 + r16][quad * 8];
      bfrag8 s1 = *(const bfrag8*)&SvT[j * 16 + r16][quad * 8 + 32];
      acc3[j] = __builtin_amdgcn_mfma_f32_16x16x32_bf16(af0, s0, acc3[j], 0, 0, 0);
      acc3[j] = __builtin_amdgcn_mfma_f32_16x16x32_bf16(af1, s1, acc3[j], 0, 0, 0);
      acc2[j] = __builtin_amdgcn_mfma_f32_16x16x32_bf16(zf0, s0, acc2[j], 0, 0, 0);
      acc2[j] = __builtin_amdgcn_mfma_f32_16x16x32_bf16(zf1, s1, acc2[j], 0, 0, 0);
    }
#pragma unroll
    for (int j = 0; j < 4; ++j) {
#pragma unroll
      for (int r = 0; r < 4; ++r) {
        int row = m0w + quad * 4 + r;
        int col = j * 16 + r16;
        Wl[row][col] = (col <= row) ? f2bf(aA[row] * iaA[col] * acc1[j][r])
                                    : (unsigned short)0;
        float uval = bf2f(Ufl[row][col]) - acc2[j][r];
        UTl[col][row] = f2bf(uval);
        op[j][r] = aA[row] * acc3[j][r];
      }
    }
  }
  __syncthreads();
  {
    bfrag8 wf0 = *(const bfrag8*)&Wl[m0w + r16][quad * 8];
    bfrag8 wf1 = *(const bfrag8*)&Wl[m0w + r16][quad * 8 + 32];
    f32x4 acc4[4];
#pragma unroll
    for (int j = 0; j < 4; ++j) acc4[j] = {0.f, 0.f, 0.f, 0.f};
#pragma unroll
    for (int j = 0; j < 4; ++j) {
      bfrag8 u0 = *(const bfrag8*)&UTl[j * 16 + r16][quad * 8];
      bfrag8 u1 = *(const bfrag8*)&UTl[j * 16 + r16][quad * 8 + 32];
      acc4[j] = __builtin_amdgcn_mfma_f32_16x16x32_bf16(wf0, u0, acc4[j], 0, 0, 0);
      acc4[j] = __builtin_amdgcn_mfma_f32_16x16x32_bf16(wf1, u1, acc4[j], 0, 0, 0);
    }
#pragma unroll
    for (int j = 0; j < 4; ++j) {
#pragma unroll
      for (int r = 0; r < 4; ++r) {
        int row = m0w + quad * 4 + r;
        int col = j * 16 + r16;
        int ts = tc + row;
        if (ts < 1023) {
          ACAT[((size_t)b * TT + ts + 1) * PSB + h * 64 + col] =
              f2bf(op[j][r] + acc4[j][r]);
        }
      }
    }
  }
}

// ---------------------------------------------------------------------------
// retrieved = (k_shared @ Sf) * mg  -> ACAT col 2048 (bf16).
// ---------------------------------------------------------------------------
__global__ __launch_bounds__(256) void retrieve_kernel(
    const float* __restrict__ p32, const float* __restrict__ Sf,
    const float* __restrict__ mg, unsigned short* __restrict__ ACAT) {
  int w = blockIdx.x * 4 + (threadIdx.x >> 6);  // (b*T+t)*H + h
  int lane = threadIdx.x & 63;                  // v index
  int bt = w >> 4;
  float kl = p32[(size_t)bt * PS32 + (w & 15) * 64 + lane];
  int b = bt >> 10;
  int bh = b * 16 + (w & 15);
  const float* sfp = Sf + (size_t)bh * 4096;
  float acc = 0.f;
#pragma unroll
  for (int k = 0; k < 64; ++k) {
    float kk = __shfl(kl, k);
    acc = fmaf(kk, sfp[k * 64 + lane], acc);
  }
  ACAT[(size_t)bt * PSB + 2048 + (w & 15) * 64 + lane] = f2bf(acc * mg[bt]);
}

// ---------------------------------------------------------------------------
extern "C" void kernel_launch(void* const* d_in, const int* in_sizes, int n_in,
                              void* d_out, int out_size, void* d_ws,
                              size_t ws_size, hipStream_t stream) {
  (void)in_sizes; (void)n_in; (void)out_size; (void)ws_size;
  const float* x       = (const float*)d_in[0];
  const float* S0      = (const float*)d_in[1];
  const float* W_k     = (const float*)d_in[2];
  const float* W_v     = (const float*)d_in[3];
  const float* W_gdn_o = (const float*)d_in[4];
  const float* W_beta  = (const float*)d_in[5];
  const float* b_beta  = (const float*)d_in[6];
  const float* W_g     = (const float*)d_in[7];
  const float* b_g     = (const float*)d_in[8];
  const float* W_lq    = (const float*)d_in[9];
  const float* W_lk    = (const float*)d_in[10];
  const float* W_lv    = (const float*)d_in[11];
  const float* W_swa_o = (const float*)d_in[12];
  const float* W_ret_o = (const float*)d_in[13];
  const float* W_gate  = (const float*)d_in[14];
  const float* b_gate  = (const float*)d_in[15];
  const float* norm_w  = (const float*)d_in[16];
  const int*   ids     = (const int*)d_in[17];
  float* out = (float*)d_out;

  char* ws = (char*)d_ws;
  size_t off = 0;
  auto allocf = [&](size_t n) {
    float* p = (float*)(ws + off);
    off += n * sizeof(float);
    return p;
  };
  auto allocu = [&](size_t n) {
    unsigned short* p = (unsigned short*)(ws + off);
    off += n * sizeof(unsigned short);
    return p;
  };
  const int M = BB * TT;  // 4096
  unsigned short* XNb    = allocu((size_t)M * DD);
  float*          P32    = allocf((size_t)M * PS32);   // KSH | VF
  unsigned short* PB     = allocu((size_t)M * PSB);    // Q | KL | VL
  unsigned short* ACAT   = allocu((size_t)M * PSB);    // gdn | local | retr
  float*          SPRJ   = allocf((size_t)M * 128);    // gate logits
  unsigned short* WTcat5 = allocu((size_t)NPROJ * 1024);
  unsigned short* WTcat3 = allocu((size_t)1024 * PSB);
  float* BETA = allocf((size_t)M * HH);
  float* Gg   = allocf((size_t)M * HH);
  float* MG   = allocf((size_t)M);
  float* SF   = allocf((size_t)BB * HH * KK * VV);
  const size_t CH = (size_t)BB * HH * 16 * 64 * 64;
  unsigned short* UFg   = allocu(CH);
  unsigned short* Zg    = allocu(CH);
  unsigned short* Pg    = allocu(CH);
  unsigned short* Qg    = allocu(CH);
  unsigned short* SinTg = allocu(CH);
  float* Ag = allocf((size_t)BB * HH * 16 * 64);

  rmsnorm_kernel<<<M, 256, 0, stream>>>(x, norm_w, XNb);

  convert_wt_kernel<<<dim3(16, 16, 9), 256, 0, stream>>>(
      W_k, W_v, W_lq, W_lk, W_lv, W_gdn_o, W_swa_o, W_ret_o, W_beta, W_g,
      W_gate, WTcat5, WTcat3);

  gemm_proj_kernel<<<dim3(NPROJ / 128, M / 128), 256, 0, stream>>>(
      XNb, WTcat5, P32, PB, SPRJ);

  knorm_kernel<<<(M * HH) / 4, 256, 0, stream>>>(P32);
  gates_kernel<<<M / 4, 256, 0, stream>>>(SPRJ, b_beta, b_g, b_gate, ids, BETA,
                                          Gg, MG);

  scan_phaseA<<<dim3(16, BB * HH), 256, 0, stream>>>(P32, BETA, Gg, UFg, Zg, Pg,
                                                     Qg, Ag);
  scan_phaseB<<<BB * HH, 256, 0, stream>>>(S0, Pg, Qg, SinTg, SF, ACAT);
  scan_phaseC<<<dim3(16, BB * HH), 256, 0, stream>>>(P32, UFg, Zg, SinTg, Ag,
                                                     ACAT);

  attn_mfma_kernel<<<dim3(TT / 64, BB * HH), 256, 0, stream>>>(PB, ACAT);

  retrieve_kernel<<<(M * HH) / 4, 256, 0, stream>>>(P32, SF, MG, ACAT);

  // out = x + [gdn | local*0.3W | retr*mg] @ WTcat3^T  (K=3072, 512 blocks)
  gemm_out_kernel<<<dim3(16, 32), 256, 0, stream>>>(ACAT, WTcat3, out, x, M, DD,
                                                    3072);
}

// Round 9
// 420.886 us; speedup vs baseline: 7.6726x; 1.0298x over previous
//
#include <hip/hip_runtime.h>
#include <hip/hip_bf16.h>

// Problem constants
#define BB 4
#define TT 1024
#define DD 1024
#define HH 16
#define KK 64
#define VV 64
#define WIN 256
#define MARKER_ID 50251
#define PSA 5120   // bf16 all-proj row stride: K|V|Q|KL|VL
#define PSB 3072   // epilogue-cat row stride (gdn|local|retr)
#define NPROJ 5248 // proj GEMM N: 5120 bf16 + 128 gates(48+80 pad)

typedef short bfrag8 __attribute__((ext_vector_type(8)));
typedef float f32x4 __attribute__((ext_vector_type(4)));

static __device__ __forceinline__ unsigned short f2bf(float f) {
  __hip_bfloat16 h = __float2bfloat16(f);
  union { __hip_bfloat16 h; unsigned short u; } cv;
  cv.h = h;
  return cv.u;
}
static __device__ __forceinline__ float bf2f(unsigned short u) {
  union { unsigned int i; float f; } c;
  c.i = ((unsigned int)u) << 16;
  return c.f;
}
// Async global->LDS, 16B per lane. LDS dest = wave-uniform base + lane*16.
static __device__ __forceinline__ void gld_lds16(const unsigned short* g,
                                                 unsigned short* l) {
  __builtin_amdgcn_global_load_lds(
      (const __attribute__((address_space(1))) void*)g,
      (__attribute__((address_space(3))) void*)l, 16, 0, 0);
}

// ---------------------------------------------------------------------------
// RMSNorm: xnb (bf16) = x / sqrt(mean(x^2)+eps) * norm_w. One block per row.
// ---------------------------------------------------------------------------
__global__ __launch_bounds__(256) void rmsnorm_kernel(
    const float* __restrict__ x, const float* __restrict__ nw,
    unsigned short* __restrict__ xnb) {
  int row = blockIdx.x;
  int tid = threadIdx.x;
  const float4* xr = (const float4*)(x + (size_t)row * DD);
  float4 v = xr[tid];
  float ss = v.x * v.x + v.y * v.y + v.z * v.z + v.w * v.w;
#pragma unroll
  for (int off = 32; off; off >>= 1) ss += __shfl_xor(ss, off);
  __shared__ float red[4];
  int wid = tid >> 6;
  if ((tid & 63) == 0) red[wid] = ss;
  __syncthreads();
  float tot = red[0] + red[1] + red[2] + red[3];
  float inv = 1.0f / sqrtf(tot * (1.0f / DD) + 1e-6f);
  const float4* wr = (const float4*)nw;
  float4 wv = wr[tid];
  ushort4 o;
  o.x = f2bf(v.x * inv * wv.x);
  o.y = f2bf(v.y * inv * wv.y);
  o.z = f2bf(v.z * inv * wv.z);
  o.w = f2bf(v.w * inv * wv.w);
  *(ushort4*)&xnb[(size_t)row * DD + tid * 4] = o;
}

// ---------------------------------------------------------------------------
// Convert + transpose weights fp32 [K][N] -> bf16 [N][K] into concatenated
// buffers. z=0..7: the 1024x1024 weights. z=8: small gate weights (48 rows)
// + zero-pad rows 5168..5247 of C5.
// ---------------------------------------------------------------------------
__global__ __launch_bounds__(256) void convert_wt_kernel(
    const float* W0, const float* W1, const float* W2, const float* W3,
    const float* W4, const float* W5, const float* W6, const float* W7,
    const float* Wb, const float* Wg, const float* Wgt,
    unsigned short* C5, unsigned short* C3) {
  int tid = threadIdx.x;
  if (blockIdx.z == 8) {
    if (blockIdx.x != 0) return;
    int k0 = blockIdx.y * 64;
    for (int e = tid; e < 3 * 16 * 64; e += 256) {
      int w = e >> 10;          // which weight
      int h = (e >> 6) & 15;    // head col
      int kk = e & 63;
      const float* Ws = (w == 0) ? Wb : (w == 1) ? Wg : Wgt;
      C5[(size_t)(5120 + w * 16 + h) * 1024 + k0 + kk] =
          f2bf(Ws[(size_t)(k0 + kk) * 16 + h]);
    }
    for (int e = tid; e < 80 * 64; e += 256) {
      int r = e >> 6, kk = e & 63;
      C5[(size_t)(5168 + r) * 1024 + k0 + kk] = 0;
    }
    return;
  }
  const float* W;
  unsigned short* T;
  int stride;
  float scale = 1.f;
  switch (blockIdx.z) {
    case 0: W = W0; T = C5 + 0 * 1024 * 1024; stride = 1024; break;
    case 1: W = W1; T = C5 + 1 * 1024 * 1024; stride = 1024; break;
    case 2: W = W2; T = C5 + 2 * 1024 * 1024; stride = 1024; break;
    case 3: W = W3; T = C5 + 3 * 1024 * 1024; stride = 1024; break;
    case 4: W = W4; T = C5 + 4 * 1024 * 1024; stride = 1024; break;
    case 5: W = W5; T = C3 + 0; stride = PSB; break;
    case 6: W = W6; T = C3 + 1024; stride = PSB; scale = 0.3f; break;
    default: W = W7; T = C3 + 2048; stride = PSB; break;
  }
  __shared__ float Ts[64][68];
  int n0 = blockIdx.x * 64, k0 = blockIdx.y * 64;
#pragma unroll
  for (int p = 0; p < 4; ++p) {
    int e = p * 256 + tid;
    int k = e >> 4, nq = e & 15;
    float4 w = *(const float4*)&W[(size_t)(k0 + k) * 1024 + n0 + nq * 4];
    Ts[nq * 4 + 0][k] = w.x;
    Ts[nq * 4 + 1][k] = w.y;
    Ts[nq * 4 + 2][k] = w.z;
    Ts[nq * 4 + 3][k] = w.w;
  }
  __syncthreads();
#pragma unroll
  for (int p = 0; p < 4; ++p) {
    int e = p * 256 + tid;
    int n = e >> 4, kq = e & 15;
    float4 v = *(const float4*)&Ts[n][kq * 4];
    ushort4 u;
    u.x = f2bf(v.x * scale);
    u.y = f2bf(v.y * scale);
    u.z = f2bf(v.z * scale);
    u.w = f2bf(v.w * scale);
    *(ushort4*)&T[(size_t)(n0 + n) * stride + k0 + kq * 4] = u;
  }
}

// ---------------------------------------------------------------------------
// Epilogue GEMM: out = x + ACAT[4096][3072] @ WTcat3[1024][3072]^T.
// 128M x 64N tile -> 512 blocks (2/CU). XCD swizzle. Grid MUST be (16, 32).
// ---------------------------------------------------------------------------
__global__ __launch_bounds__(256) void gemm_out_kernel(
    const unsigned short* __restrict__ A, const unsigned short* __restrict__ BT,
    float* __restrict__ C, const float* __restrict__ addp, int M, int N,
    int K) {
  __shared__ unsigned short As[128][32];
  __shared__ unsigned short Bs[64][32];
  int flat = blockIdx.y * gridDim.x + blockIdx.x;
  int xcd = flat & 7, local = flat >> 3;
  int m0 = (xcd * 4 + (local & 3)) * 128;
  int n0 = (local >> 2) * 64;
  int tid = threadIdx.x;
  int wave = tid >> 6, lane = tid & 63;
  int wm = wave * 32;
  int r16 = lane & 15, quad = lane >> 4;
  int lrow = lane >> 2, lcol = (lane & 3) * 8;

  f32x4 acc[2][4];
#pragma unroll
  for (int i = 0; i < 2; ++i)
#pragma unroll
    for (int j = 0; j < 4; ++j) acc[i][j] = {0.f, 0.f, 0.f, 0.f};

  for (int kt = 0; kt < K; kt += 32) {
    __syncthreads();
#pragma unroll
    for (int q = 0; q < 2; ++q) {
      int rb = (wave * 2 + q) * 16;
      gld_lds16(&A[(size_t)(m0 + rb + lrow) * K + kt + lcol], &As[rb][0]);
    }
    {
      int rb = wave * 16;
      gld_lds16(&BT[(size_t)(n0 + rb + lrow) * K + kt + lcol], &Bs[rb][0]);
    }
    __syncthreads();
    bfrag8 af[2], bq[4];
#pragma unroll
    for (int i = 0; i < 2; ++i)
      af[i] = *(const bfrag8*)&As[wm + i * 16 + r16][quad * 8];
#pragma unroll
    for (int j = 0; j < 4; ++j)
      bq[j] = *(const bfrag8*)&Bs[j * 16 + r16][quad * 8];
#pragma unroll
    for (int i = 0; i < 2; ++i)
#pragma unroll
      for (int j = 0; j < 4; ++j)
        acc[i][j] = __builtin_amdgcn_mfma_f32_16x16x32_bf16(af[i], bq[j],
                                                            acc[i][j], 0, 0, 0);
  }
#pragma unroll
  for (int i = 0; i < 2; ++i) {
#pragma unroll
    for (int r = 0; r < 4; ++r) {
      int row = m0 + wm + i * 16 + quad * 4 + r;
#pragma unroll
      for (int j = 0; j < 4; ++j) {
        int col = n0 + j * 16 + r16;
        size_t idx = (size_t)row * N + col;
        C[idx] = addp[idx] + acc[i][j][r];
      }
    }
  }
}

// ---------------------------------------------------------------------------
// Fused projection GEMM: A=xn [4096][1024] bf16, BT=WTcat5 [5248][1024].
// XCD swizzle: 1312 blocks = 8 xcd x (4 mi x 41 ni); per-XCD A-slice 1MB.
// cols 0..5119 bf16 -> PALL (K|V|Q|KL|VL, stride 5120);
// 5120..5247 fp32 -> SPRJ (gate logits, stride 128). Grid MUST be (41,32).
// ---------------------------------------------------------------------------
__global__ __launch_bounds__(256) void gemm_proj_kernel(
    const unsigned short* __restrict__ A, const unsigned short* __restrict__ BT,
    unsigned short* __restrict__ PALL, float* __restrict__ SPRJ) {
  const int K = 1024;
  __shared__ unsigned short As[128][32];
  __shared__ unsigned short Bs[128][32];
  int flat = blockIdx.y * gridDim.x + blockIdx.x;  // 0..1311
  int xcd = flat & 7, local = flat >> 3;           // local 0..163
  int mi = local / 41, ni = local % 41;
  int m0 = (xcd * 4 + mi) * 128;
  int n0 = ni * 128;
  int tid = threadIdx.x;
  int wave = tid >> 6, lane = tid & 63;
  int wm = (wave & 1) * 64, wn = (wave >> 1) * 64;
  int r16 = lane & 15, quad = lane >> 4;
  int lrow = lane >> 2, lcol = (lane & 3) * 8;

  f32x4 acc[4][4];
#pragma unroll
  for (int i = 0; i < 4; ++i)
#pragma unroll
    for (int j = 0; j < 4; ++j) acc[i][j] = {0.f, 0.f, 0.f, 0.f};

  for (int kt = 0; kt < K; kt += 32) {
    __syncthreads();
#pragma unroll
    for (int q = 0; q < 2; ++q) {
      int rb = (wave * 2 + q) * 16;
      gld_lds16(&A[(size_t)(m0 + rb + lrow) * K + kt + lcol], &As[rb][0]);
      gld_lds16(&BT[(size_t)(n0 + rb + lrow) * K + kt + lcol], &Bs[rb][0]);
    }
    __syncthreads();
    bfrag8 af[4], bq[4];
#pragma unroll
    for (int i = 0; i < 4; ++i) {
      af[i] = *(const bfrag8*)&As[wm + i * 16 + r16][quad * 8];
      bq[i] = *(const bfrag8*)&Bs[wn + i * 16 + r16][quad * 8];
    }
#pragma unroll
    for (int i = 0; i < 4; ++i)
#pragma unroll
      for (int j = 0; j < 4; ++j)
        acc[i][j] = __builtin_amdgcn_mfma_f32_16x16x32_bf16(af[i], bq[j],
                                                            acc[i][j], 0, 0, 0);
  }
  bool gates = (n0 >= 5120);  // block-uniform (ni == 40)
#pragma unroll
  for (int i = 0; i < 4; ++i) {
#pragma unroll
    for (int r = 0; r < 4; ++r) {
      int row = m0 + wm + i * 16 + quad * 4 + r;
#pragma unroll
      for (int j = 0; j < 4; ++j) {
        int col = n0 + wn + j * 16 + r16;
        if (!gates)
          PALL[(size_t)row * PSA + col] = f2bf(acc[i][j][r]);
        else
          SPRJ[(size_t)row * 128 + col - 5120] = acc[i][j][r];
      }
    }
  }
}

// ---------------------------------------------------------------------------
// Gates: sigmoid(logit + bias) for beta/g/gate; marker mask; head-mean of
// gate. One wave per row; lanes 0..15 beta, 16..31 g, 32..47 gate.
// ---------------------------------------------------------------------------
__global__ __launch_bounds__(256) void gates_kernel(
    const float* __restrict__ SPRJ, const float* __restrict__ bb,
    const float* __restrict__ bg, const float* __restrict__ bgt,
    const int* __restrict__ ids, float* __restrict__ beta,
    float* __restrict__ g, float* __restrict__ mg) {
  int row = blockIdx.x * 4 + (threadIdx.x >> 6);
  int lane = threadIdx.x & 63;
  if (lane < 48) {
    int h = lane & 15;
    float v = SPRJ[(size_t)row * 128 + lane];
    float bias = (lane < 16) ? bb[h] : (lane < 32) ? bg[h] : bgt[h];
    float s = 1.f / (1.f + __expf(-(v + bias)));
    if (lane < 16) {
      float mk = (ids[row] == MARKER_ID) ? 1.f : 0.1f;
      beta[(size_t)row * 16 + h] = s * mk;
    } else if (lane < 32) {
      g[(size_t)row * 16 + h] = s;
    } else {
      float sum = s;
#pragma unroll
      for (int off = 1; off < 16; off <<= 1) sum += __shfl_xor(sum, off);
      if (lane == 32) mg[row] = sum * (1.f / 16.f);
    }
  }
}

// ---------------------------------------------------------------------------
// L2-normalize rows of 64 (k_shared) inside PALL (bf16, stride 5120, col 0).
// ---------------------------------------------------------------------------
__global__ __launch_bounds__(256) void knorm_kernel(
    unsigned short* __restrict__ pall) {
  int w = blockIdx.x * 4 + (threadIdx.x >> 6);  // (b*T+t)*H + h
  int lane = threadIdx.x & 63;
  size_t addr = (size_t)(w >> 4) * PSA + (w & 15) * 64 + lane;
  float v = bf2f(pall[addr]);
  float ss = v * v;
#pragma unroll
  for (int off = 32; off; off >>= 1) ss += __shfl_xor(ss, off);
  float n = sqrtf(ss);
  n = fmaxf(n, 1e-12f);
  pall[addr] = f2bf(v / n);
}

// ---------------------------------------------------------------------------
// MFMA flash sliding-window attention. Q/KL/VL at PALL cols 2048/3072/4096.
// ---------------------------------------------------------------------------
__global__ __launch_bounds__(256) void attn_mfma_kernel(
    const unsigned short* __restrict__ PALL, unsigned short* __restrict__ ACAT) {
  __shared__ unsigned short Qs[64][72];
  __shared__ unsigned short Ks[64][72];
  __shared__ unsigned short Vt[64][72];
  __shared__ unsigned short Ps[64][72];
  int qb = blockIdx.x * 64;
  int bh = blockIdx.y;
  int h = bh & 15, b = bh >> 4;
  int tid = threadIdx.x, lane = tid & 63, wave = tid >> 6;
  int r16 = lane & 15, quad = lane >> 4;
  int m0w = wave * 16;
  const unsigned short* Qg = PALL + (size_t)b * TT * PSA + 2048 + h * 64;
  const unsigned short* Kg = Qg + 1024;
  const unsigned short* Vg = Qg + 2048;
  int sr = tid >> 2, sq = tid & 3;
  {
    *(uint4*)&Qs[sr][sq * 16] =
        *(const uint4*)&Qg[(size_t)(qb + sr) * PSA + sq * 16];
    *(uint4*)&Qs[sr][sq * 16 + 8] =
        *(const uint4*)&Qg[(size_t)(qb + sr) * PSA + sq * 16 + 8];
  }
  float m[4], l[4];
  f32x4 o[4];
#pragma unroll
  for (int r = 0; r < 4; ++r) {
    m[r] = -1e30f;
    l[r] = 0.f;
    o[r] = {0.f, 0.f, 0.f, 0.f};
  }
  int kt0 = qb - (int)WIN;
  if (kt0 < 0) kt0 = 0;

  for (int kt = kt0; kt <= qb; kt += 64) {
    __syncthreads();
    {
      *(uint4*)&Ks[sr][sq * 16] =
          *(const uint4*)&Kg[(size_t)(kt + sr) * PSA + sq * 16];
      *(uint4*)&Ks[sr][sq * 16 + 8] =
          *(const uint4*)&Kg[(size_t)(kt + sr) * PSA + sq * 16 + 8];
      union { uint4 u4[2]; unsigned short s[16]; } vv;
      vv.u4[0] = *(const uint4*)&Vg[(size_t)(kt + sr) * PSA + sq * 16];
      vv.u4[1] = *(const uint4*)&Vg[(size_t)(kt + sr) * PSA + sq * 16 + 8];
#pragma unroll
      for (int i = 0; i < 16; ++i) Vt[sq * 16 + i][sr] = vv.s[i];
    }
    __syncthreads();
    bfrag8 af0 = *(const bfrag8*)&Qs[m0w + r16][quad * 8];
    bfrag8 af1 = *(const bfrag8*)&Qs[m0w + r16][quad * 8 + 32];
    f32x4 s[4];
#pragma unroll
    for (int j = 0; j < 4; ++j) s[j] = {0.f, 0.f, 0.f, 0.f};
#pragma unroll
    for (int j = 0; j < 4; ++j) {
      bfrag8 b0 = *(const bfrag8*)&Ks[j * 16 + r16][quad * 8];
      bfrag8 b1 = *(const bfrag8*)&Ks[j * 16 + r16][quad * 8 + 32];
      s[j] = __builtin_amdgcn_mfma_f32_16x16x32_bf16(af0, b0, s[j], 0, 0, 0);
      s[j] = __builtin_amdgcn_mfma_f32_16x16x32_bf16(af1, b1, s[j], 0, 0, 0);
    }
    bool oldest = (kt == qb - (int)WIN);
    bool newest = (kt == qb);
#pragma unroll
    for (int r = 0; r < 4; ++r) {
      int il = m0w + quad * 4 + r;
      float sv[4];
#pragma unroll
      for (int j = 0; j < 4; ++j) {
        int jl = j * 16 + r16;
        float v = s[j][r] * 0.125f;
        if (oldest && jl < il) v = -1e30f;
        if (newest && jl > il) v = -1e30f;
        sv[j] = v;
      }
      float mx = fmaxf(fmaxf(sv[0], sv[1]), fmaxf(sv[2], sv[3]));
#pragma unroll
      for (int off = 1; off < 16; off <<= 1) mx = fmaxf(mx, __shfl_xor(mx, off));
      float mn = fmaxf(m[r], mx);
      float al = __expf(m[r] - mn);
      m[r] = mn;
      float rs = 0.f;
#pragma unroll
      for (int j = 0; j < 4; ++j) {
        float p = __expf(sv[j] - mn);
        rs += p;
        Ps[il][j * 16 + r16] = f2bf(p);
      }
#pragma unroll
      for (int off = 1; off < 16; off <<= 1) rs += __shfl_xor(rs, off);
      l[r] = l[r] * al + rs;
#pragma unroll
      for (int j = 0; j < 4; ++j) o[j][r] *= al;
    }
    bfrag8 pa0 = *(const bfrag8*)&Ps[m0w + r16][quad * 8];
    bfrag8 pa1 = *(const bfrag8*)&Ps[m0w + r16][quad * 8 + 32];
#pragma unroll
    for (int j = 0; j < 4; ++j) {
      bfrag8 v0 = *(const bfrag8*)&Vt[j * 16 + r16][quad * 8];
      bfrag8 v1 = *(const bfrag8*)&Vt[j * 16 + r16][quad * 8 + 32];
      o[j] = __builtin_amdgcn_mfma_f32_16x16x32_bf16(pa0, v0, o[j], 0, 0, 0);
      o[j] = __builtin_amdgcn_mfma_f32_16x16x32_bf16(pa1, v1, o[j], 0, 0, 0);
    }
  }
#pragma unroll
  for (int r = 0; r < 4; ++r) {
    int row = m0w + quad * 4 + r;
    float inv = 1.f / l[r];
#pragma unroll
    for (int j = 0; j < 4; ++j) {
      ACAT[((size_t)(b * TT + qb + row)) * PSB + 1024 + h * 64 + j * 16 + r16] =
          f2bf(o[j][r] * inv);
    }
  }
}

// ---------------------------------------------------------------------------
// Scan phase A (per (bh,chunk)): M, u_free, Z, P, Q, a. bf16 K/V from PALL.
// ---------------------------------------------------------------------------
__global__ __launch_bounds__(256) void scan_phaseA(
    const unsigned short* __restrict__ PALL, const float* __restrict__ beta,
    const float* __restrict__ g, unsigned short* __restrict__ UFg,
    unsigned short* __restrict__ Zg, unsigned short* __restrict__ Pg,
    unsigned short* __restrict__ Qg, float* __restrict__ Ag) {
  __shared__ unsigned short Kc[64][72];
  __shared__ unsigned short KTb[64][72];
  __shared__ float Vc[64][68];
  __shared__ float Msv[64][68];
  __shared__ unsigned short UFT[64][72];
  __shared__ unsigned short ZTl[64][72];
  __shared__ float aArr[64], iaArr[64], bArr[64], baArr[64], sKT[64];
  __shared__ float aCs;

  int c = blockIdx.x, bh = blockIdx.y;
  int b = bh >> 4, h = bh & 15;
  int tc = c * 64;
  int tid = threadIdx.x, lane = tid & 63, wave = tid >> 6;
  int r16 = lane & 15, quad = lane >> 4;
  int m0w = wave * 16;
  size_t bhc = (size_t)bh * 16 + c;

  const unsigned short* kbase = PALL + ((size_t)b * TT) * PSA + h * 64;
  const unsigned short* vbase = kbase + 1024;
  const float* bbase = beta + ((size_t)b * TT) * HH + h;
  const float* gbase = g + ((size_t)b * TT) * HH + h;

  if (tid < 64) {
    int ts = tc + tid;
    bool pad = (ts > 1022);
    float gv = pad ? 1.f : gbase[(size_t)ts * HH];
    float bv = pad ? 0.f : bbase[(size_t)ts * HH];
    float p = gv;
#pragma unroll
    for (int o = 1; o < 64; o <<= 1) {
      float t = __shfl_up(p, o);
      if (lane >= o) p *= t;
    }
    aArr[tid] = p;
    iaArr[tid] = 1.f / p;
    bArr[tid] = bv;
    baArr[tid] = bv * p;
    float aC = __shfl(p, 63);
    sKT[tid] = aC / p;
    if (tid == 0) aCs = aC;
    Ag[bhc * 64 + tid] = p;
  }
  __syncthreads();
  {
    int r = tid >> 2, q = tid & 3;
    int ts = tc + r;
    float skt = sKT[r];
    union { uint4 u4[2]; unsigned short s[16]; } kv;
    kv.u4[0] = *(const uint4*)&kbase[(size_t)ts * PSA + q * 16];
    kv.u4[1] = *(const uint4*)&kbase[(size_t)ts * PSA + q * 16 + 8];
    *(uint4*)&Kc[r][q * 16] = kv.u4[0];
    *(uint4*)&Kc[r][q * 16 + 8] = kv.u4[1];
#pragma unroll
    for (int i = 0; i < 16; ++i)
      KTb[q * 16 + i][r] = f2bf(bf2f(kv.s[i]) * skt);
    if (ts <= 1022) {
      union { uint4 u4[2]; unsigned short s[16]; } vv;
      vv.u4[0] = *(const uint4*)&vbase[(size_t)(ts + 1) * PSA + q * 16];
      vv.u4[1] = *(const uint4*)&vbase[(size_t)(ts + 1) * PSA + q * 16 + 8];
#pragma unroll
      for (int i = 0; i < 16; ++i) Vc[r][q * 16 + i] = bf2f(vv.s[i]);
    } else {
#pragma unroll
      for (int i = 0; i < 16; ++i) Vc[r][q * 16 + i] = 0.f;
    }
  }
  __syncthreads();
  {
    bfrag8 af0 = *(const bfrag8*)&Kc[m0w + r16][quad * 8];
    bfrag8 af1 = *(const bfrag8*)&Kc[m0w + r16][quad * 8 + 32];
    f32x4 acc1[4];
#pragma unroll
    for (int j = 0; j < 4; ++j) acc1[j] = {0.f, 0.f, 0.f, 0.f};
#pragma unroll
    for (int j = 0; j < 4; ++j) {
      bfrag8 k0 = *(const bfrag8*)&Kc[j * 16 + r16][quad * 8];
      bfrag8 k1 = *(const bfrag8*)&Kc[j * 16 + r16][quad * 8 + 32];
      acc1[j] = __builtin_amdgcn_mfma_f32_16x16x32_bf16(af0, k0, acc1[j], 0, 0, 0);
      acc1[j] = __builtin_amdgcn_mfma_f32_16x16x32_bf16(af1, k1, acc1[j], 0, 0, 0);
    }
#pragma unroll
    for (int j = 0; j < 4; ++j) {
#pragma unroll
      for (int r = 0; r < 4; ++r) {
        int row = m0w + quad * 4 + r;
        int col = j * 16 + r16;
        Msv[row][col] =
            (col < row) ? bArr[row] * aArr[row] * iaArr[col] * acc1[j][r] : 0.f;
      }
    }
  }
  __syncthreads();
  if (wave < 2) {
    float u[64];
    if (wave == 0) {
#pragma unroll
      for (int t = 0; t < 64; ++t) u[t] = bArr[t] * Vc[t][lane];
    } else {
#pragma unroll
      for (int t = 0; t < 64; ++t) u[t] = baArr[t] * bf2f(Kc[t][lane]);
    }
#pragma unroll
    for (int t = 1; t < 64; ++t) {
      float a0 = 0.f, a1 = 0.f, a2 = 0.f, a3 = 0.f;
#pragma unroll
      for (int s4 = 0; s4 * 4 < t; ++s4) {
        float4 mr = *(const float4*)&Msv[t][s4 * 4];
        a0 = fmaf(mr.x, u[s4 * 4 + 0], a0);
        a1 = fmaf(mr.y, u[s4 * 4 + 1], a1);
        a2 = fmaf(mr.z, u[s4 * 4 + 2], a2);
        a3 = fmaf(mr.w, u[s4 * 4 + 3], a3);
      }
      u[t] -= (a0 + a1) + (a2 + a3);
    }
    unsigned short* Tls = (wave == 0) ? &UFT[lane][0] : &ZTl[lane][0];
#pragma unroll
    for (int t2 = 0; t2 < 32; ++t2) {
      unsigned int pk = (unsigned int)f2bf(u[2 * t2]) |
                        ((unsigned int)f2bf(u[2 * t2 + 1]) << 16);
      *(unsigned int*)&Tls[2 * t2] = pk;
    }
    unsigned short* Gn = (wave == 0) ? UFg : Zg;
#pragma unroll
    for (int t = 0; t < 64; ++t) {
      Gn[(bhc * 64 + t) * 64 + lane] = f2bf(u[t]);
    }
  }
  __syncthreads();
  {
    bfrag8 af0 = *(const bfrag8*)&KTb[m0w + r16][quad * 8];
    bfrag8 af1 = *(const bfrag8*)&KTb[m0w + r16][quad * 8 + 32];
    f32x4 accp[4], accq[4];
#pragma unroll
    for (int j = 0; j < 4; ++j) {
      accp[j] = {0.f, 0.f, 0.f, 0.f};
      accq[j] = {0.f, 0.f, 0.f, 0.f};
    }
#pragma unroll
    for (int j = 0; j < 4; ++j) {
      bfrag8 z0 = *(const bfrag8*)&ZTl[j * 16 + r16][quad * 8];
      bfrag8 z1 = *(const bfrag8*)&ZTl[j * 16 + r16][quad * 8 + 32];
      accp[j] = __builtin_amdgcn_mfma_f32_16x16x32_bf16(af0, z0, accp[j], 0, 0, 0);
      accp[j] = __builtin_amdgcn_mfma_f32_16x16x32_bf16(af1, z1, accp[j], 0, 0, 0);
      bfrag8 u0 = *(const bfrag8*)&UFT[j * 16 + r16][quad * 8];
      bfrag8 u1 = *(const bfrag8*)&UFT[j * 16 + r16][quad * 8 + 32];
      accq[j] = __builtin_amdgcn_mfma_f32_16x16x32_bf16(af0, u0, accq[j], 0, 0, 0);
      accq[j] = __builtin_amdgcn_mfma_f32_16x16x32_bf16(af1, u1, accq[j], 0, 0, 0);
    }
    float aC = aCs;
#pragma unroll
    for (int j = 0; j < 4; ++j) {
#pragma unroll
      for (int r = 0; r < 4; ++r) {
        int row = m0w + quad * 4 + r;
        int col = j * 16 + r16;
        float pv = ((row == col) ? aC : 0.f) - accp[j][r];
        Pg[bhc * 4096 + (size_t)row * 64 + col] = f2bf(pv);
        Qg[bhc * 4096 + (size_t)row * 64 + col] = f2bf(accq[j][r]);
      }
    }
  }
}

// ---------------------------------------------------------------------------
// Scan phase B: serial S_{c+1} = P_c S_c + Q_c (as R6-R8).
// ---------------------------------------------------------------------------
__global__ __launch_bounds__(256) void scan_phaseB(
    const float* __restrict__ S0, const unsigned short* __restrict__ Pg,
    const unsigned short* __restrict__ Qg, unsigned short* __restrict__ SinTg,
    float* __restrict__ Sf, unsigned short* __restrict__ ACAT) {
  __shared__ unsigned short STb[64][72];
  __shared__ unsigned short Pl[64][72];
  int bh = blockIdx.x;
  int b = bh >> 4, h = bh & 15;
  int tid = threadIdx.x, lane = tid & 63, wave = tid >> 6;
  int r16 = lane & 15, quad = lane >> 4;
  int m0w = wave * 16;
  int rr = tid >> 2, qq = tid & 3;
  {
    const float* s0p = S0 + (size_t)bh * 4096;
#pragma unroll
    for (int i = 0; i < 4; ++i) {
      float4 sv = *(const float4*)&s0p[rr * 64 + qq * 16 + i * 4];
      STb[qq * 16 + i * 4 + 0][rr] = f2bf(sv.x);
      STb[qq * 16 + i * 4 + 1][rr] = f2bf(sv.y);
      STb[qq * 16 + i * 4 + 2][rr] = f2bf(sv.z);
      STb[qq * 16 + i * 4 + 3][rr] = f2bf(sv.w);
    }
    if (tid < 64) ACAT[((size_t)b * TT) * PSB + h * 64 + tid] = 0;
  }
  for (int c = 0; c < 16; ++c) {
    size_t bhc = (size_t)bh * 16 + c;
    __syncthreads();
    {
      uint4 s0v = *(const uint4*)&STb[rr][qq * 16];
      uint4 s1v = *(const uint4*)&STb[rr][qq * 16 + 8];
      *(uint4*)&SinTg[bhc * 4096 + (size_t)rr * 64 + qq * 16] = s0v;
      *(uint4*)&SinTg[bhc * 4096 + (size_t)rr * 64 + qq * 16 + 8] = s1v;
      uint4 p0 = *(const uint4*)&Pg[bhc * 4096 + (size_t)rr * 64 + qq * 16];
      uint4 p1 = *(const uint4*)&Pg[bhc * 4096 + (size_t)rr * 64 + qq * 16 + 8];
      *(uint4*)&Pl[rr][qq * 16] = p0;
      *(uint4*)&Pl[rr][qq * 16 + 8] = p1;
    }
    __syncthreads();
    f32x4 acc[4];
#pragma unroll
    for (int j = 0; j < 4; ++j) acc[j] = {0.f, 0.f, 0.f, 0.f};
    {
      bfrag8 af0 = *(const bfrag8*)&Pl[m0w + r16][quad * 8];
      bfrag8 af1 = *(const bfrag8*)&Pl[m0w + r16][quad * 8 + 32];
#pragma unroll
      for (int j = 0; j < 4; ++j) {
        bfrag8 s0v = *(const bfrag8*)&STb[j * 16 + r16][quad * 8];
        bfrag8 s1v = *(const bfrag8*)&STb[j * 16 + r16][quad * 8 + 32];
        acc[j] = __builtin_amdgcn_mfma_f32_16x16x32_bf16(af0, s0v, acc[j], 0, 0, 0);
        acc[j] = __builtin_amdgcn_mfma_f32_16x16x32_bf16(af1, s1v, acc[j], 0, 0, 0);
      }
    }
    float snew[4][4];
#pragma unroll
    for (int j = 0; j < 4; ++j) {
#pragma unroll
      for (int r = 0; r < 4; ++r) {
        int row = m0w + quad * 4 + r;
        int col = j * 16 + r16;
        snew[j][r] = acc[j][r] + bf2f(Qg[bhc * 4096 + (size_t)row * 64 + col]);
      }
    }
    __syncthreads();
#pragma unroll
    for (int j = 0; j < 4; ++j) {
#pragma unroll
      for (int r = 0; r < 4; ++r) {
        int row = m0w + quad * 4 + r;
        int col = j * 16 + r16;
        STb[col][row] = f2bf(snew[j][r]);
        if (c == 15) Sf[(size_t)bh * 4096 + (size_t)row * 64 + col] = snew[j][r];
      }
    }
  }
}

// ---------------------------------------------------------------------------
// Scan phase C: O = diag(a) K S_in + W U -> ACAT col 0. bf16 K from PALL.
// ---------------------------------------------------------------------------
__global__ __launch_bounds__(256) void scan_phaseC(
    const unsigned short* __restrict__ PALL,
    const unsigned short* __restrict__ UFg,
    const unsigned short* __restrict__ Zg,
    const unsigned short* __restrict__ SinTg, const float* __restrict__ Ag,
    unsigned short* __restrict__ ACAT) {
  __shared__ unsigned short Kc[64][72];
  __shared__ unsigned short SvT[64][72];
  __shared__ unsigned short Zl[64][72];
  __shared__ unsigned short Ufl[64][72];
  __shared__ unsigned short Wl[64][72];
  __shared__ unsigned short UTl[64][72];
  __shared__ float aA[64], iaA[64];

  int c = blockIdx.x, bh = blockIdx.y;
  int b = bh >> 4, h = bh & 15;
  int tc = c * 64;
  int tid = threadIdx.x, lane = tid & 63, wave = tid >> 6;
  int r16 = lane & 15, quad = lane >> 4;
  int m0w = wave * 16;
  size_t bhc = (size_t)bh * 16 + c;
  const unsigned short* kbase = PALL + ((size_t)b * TT) * PSA + h * 64;

  if (tid < 64) {
    float av = Ag[bhc * 64 + tid];
    aA[tid] = av;
    iaA[tid] = 1.f / av;
  }
  {
    int r = tid >> 2, q = tid & 3;
    int ts = tc + r;
    *(uint4*)&Kc[r][q * 16] = *(const uint4*)&kbase[(size_t)ts * PSA + q * 16];
    *(uint4*)&Kc[r][q * 16 + 8] =
        *(const uint4*)&kbase[(size_t)ts * PSA + q * 16 + 8];
    uint4 sv0 = *(const uint4*)&SinTg[bhc * 4096 + (size_t)r * 64 + q * 16];
    uint4 sv1 = *(const uint4*)&SinTg[bhc * 4096 + (size_t)r * 64 + q * 16 + 8];
    *(uint4*)&SvT[r][q * 16] = sv0;
    *(uint4*)&SvT[r][q * 16 + 8] = sv1;
    uint4 zv0 = *(const uint4*)&Zg[(bhc * 64 + r) * 64 + q * 16];
    uint4 zv1 = *(const uint4*)&Zg[(bhc * 64 + r) * 64 + q * 16 + 8];
    *(uint4*)&Zl[r][q * 16] = zv0;
    *(uint4*)&Zl[r][q * 16 + 8] = zv1;
    uint4 uv0 = *(const uint4*)&UFg[(bhc * 64 + r) * 64 + q * 16];
    uint4 uv1 = *(const uint4*)&UFg[(bhc * 64 + r) * 64 + q * 16 + 8];
    *(uint4*)&Ufl[r][q * 16] = uv0;
    *(uint4*)&Ufl[r][q * 16 + 8] = uv1;
  }
  __syncthreads();
  float op[4][4];
  {
    bfrag8 af0 = *(const bfrag8*)&Kc[m0w + r16][quad * 8];
    bfrag8 af1 = *(const bfrag8*)&Kc[m0w + r16][quad * 8 + 32];
    bfrag8 zf0 = *(const bfrag8*)&Zl[m0w + r16][quad * 8];
    bfrag8 zf1 = *(const bfrag8*)&Zl[m0w + r16][quad * 8 + 32];
    f32x4 acc1[4], acc2[4], acc3[4];
#pragma unroll
    for (int j = 0; j < 4; ++j) {
      acc1[j] = {0.f, 0.f, 0.f, 0.f};
      acc2[j] = {0.f, 0.f, 0.f, 0.f};
      acc3[j] = {0.f, 0.f, 0.f, 0.f};
    }
#pragma unroll
    for (int j = 0; j < 4; ++j) {
      bfrag8 k0 = *(const bfrag8*)&Kc[j * 16 + r16][quad * 8];
      bfrag8 k1 = *(const bfrag8*)&Kc[j * 16 + r16][quad * 8 + 32];
      acc1[j] = __builtin_amdgcn_mfma_f32_16x16x32_bf16(af0, k0, acc1[j], 0, 0, 0);
      acc1[j] = __builtin_amdgcn_mfma_f32_16x16x32_bf16(af1, k1, acc1[j], 0, 0, 0);
      bfrag8 s0 = *(const bfrag8*)&SvT[j * 16 + r16][quad * 8];
      bfrag8 s1 = *(const bfrag8*)&SvT[j * 16 + r16][quad * 8 + 32];
      acc3[j] = __builtin_amdgcn_mfma_f32_16x16x32_bf16(af0, s0, acc3[j], 0, 0, 0);
      acc3[j] = __builtin_amdgcn_mfma_f32_16x16x32_bf16(af1, s1, acc3[j], 0, 0, 0);
      acc2[j] = __builtin_amdgcn_mfma_f32_16x16x32_bf16(zf0, s0, acc2[j], 0, 0, 0);
      acc2[j] = __builtin_amdgcn_mfma_f32_16x16x32_bf16(zf1, s1, acc2[j], 0, 0, 0);
    }
#pragma unroll
    for (int j = 0; j < 4; ++j) {
#pragma unroll
      for (int r = 0; r < 4; ++r) {
        int row = m0w + quad * 4 + r;
        int col = j * 16 + r16;
        Wl[row][col] = (col <= row) ? f2bf(aA[row] * iaA[col] * acc1[j][r])
                                    : (unsigned short)0;
        float uval = bf2f(Ufl[row][col]) - acc2[j][r];
        UTl[col][row] = f2bf(uval);
        op[j][r] = aA[row] * acc3[j][r];
      }
    }
  }
  __syncthreads();
  {
    bfrag8 wf0 = *(const bfrag8*)&Wl[m0w + r16][quad * 8];
    bfrag8 wf1 = *(const bfrag8*)&Wl[m0w + r16][quad * 8 + 32];
    f32x4 acc4[4];
#pragma unroll
    for (int j = 0; j < 4; ++j) acc4[j] = {0.f, 0.f, 0.f, 0.f};
#pragma unroll
    for (int j = 0; j < 4; ++j) {
      bfrag8 u0 = *(const bfrag8*)&UTl[j * 16 + r16][quad * 8];
      bfrag8 u1 = *(const bfrag8*)&UTl[j * 16 + r16][quad * 8 + 32];
      acc4[j] = __builtin_amdgcn_mfma_f32_16x16x32_bf16(wf0, u0, acc4[j], 0, 0, 0);
      acc4[j] = __builtin_amdgcn_mfma_f32_16x16x32_bf16(wf1, u1, acc4[j], 0, 0, 0);
    }
#pragma unroll
    for (int j = 0; j < 4; ++j) {
#pragma unroll
      for (int r = 0; r < 4; ++r) {
        int row = m0w + quad * 4 + r;
        int col = j * 16 + r16;
        int ts = tc + row;
        if (ts < 1023) {
          ACAT[((size_t)b * TT + ts + 1) * PSB + h * 64 + col] =
              f2bf(op[j][r] + acc4[j][r]);
        }
      }
    }
  }
}

// ---------------------------------------------------------------------------
// retrieved = (k_shared @ Sf) * mg  -> ACAT col 2048 (bf16). bf16 K.
// ---------------------------------------------------------------------------
__global__ __launch_bounds__(256) void retrieve_kernel(
    const unsigned short* __restrict__ PALL, const float* __restrict__ Sf,
    const float* __restrict__ mg, unsigned short* __restrict__ ACAT) {
  int w = blockIdx.x * 4 + (threadIdx.x >> 6);  // (b*T+t)*H + h
  int lane = threadIdx.x & 63;                  // v index
  int bt = w >> 4;
  float kl = bf2f(PALL[(size_t)bt * PSA + (w & 15) * 64 + lane]);
  int b = bt >> 10;
  int bh = b * 16 + (w & 15);
  const float* sfp = Sf + (size_t)bh * 4096;
  float acc = 0.f;
#pragma unroll
  for (int k = 0; k < 64; ++k) {
    float kk = __shfl(kl, k);
    acc = fmaf(kk, sfp[k * 64 + lane], acc);
  }
  ACAT[(size_t)bt * PSB + 2048 + (w & 15) * 64 + lane] = f2bf(acc * mg[bt]);
}

// ---------------------------------------------------------------------------
extern "C" void kernel_launch(void* const* d_in, const int* in_sizes, int n_in,
                              void* d_out, int out_size, void* d_ws,
                              size_t ws_size, hipStream_t stream) {
  (void)in_sizes; (void)n_in; (void)out_size; (void)ws_size;
  const float* x       = (const float*)d_in[0];
  const float* S0      = (const float*)d_in[1];
  const float* W_k     = (const float*)d_in[2];
  const float* W_v     = (const float*)d_in[3];
  const float* W_gdn_o = (const float*)d_in[4];
  const float* W_beta  = (const float*)d_in[5];
  const float* b_beta  = (const float*)d_in[6];
  const float* W_g     = (const float*)d_in[7];
  const float* b_g     = (const float*)d_in[8];
  const float* W_lq    = (const float*)d_in[9];
  const float* W_lk    = (const float*)d_in[10];
  const float* W_lv    = (const float*)d_in[11];
  const float* W_swa_o = (const float*)d_in[12];
  const float* W_ret_o = (const float*)d_in[13];
  const float* W_gate  = (const float*)d_in[14];
  const float* b_gate  = (const float*)d_in[15];
  const float* norm_w  = (const float*)d_in[16];
  const int*   ids     = (const int*)d_in[17];
  float* out = (float*)d_out;

  char* ws = (char*)d_ws;
  size_t off = 0;
  auto allocf = [&](size_t n) {
    float* p = (float*)(ws + off);
    off += n * sizeof(float);
    return p;
  };
  auto allocu = [&](size_t n) {
    unsigned short* p = (unsigned short*)(ws + off);
    off += n * sizeof(unsigned short);
    return p;
  };
  const int M = BB * TT;  // 4096
  unsigned short* XNb    = allocu((size_t)M * DD);
  unsigned short* PALL   = allocu((size_t)M * PSA);   // K|V|Q|KL|VL bf16
  unsigned short* ACAT   = allocu((size_t)M * PSB);   // gdn | local | retr
  float*          SPRJ   = allocf((size_t)M * 128);   // gate logits
  unsigned short* WTcat5 = allocu((size_t)NPROJ * 1024);
  unsigned short* WTcat3 = allocu((size_t)1024 * PSB);
  float* BETA = allocf((size_t)M * HH);
  float* Gg   = allocf((size_t)M * HH);
  float* MG   = allocf((size_t)M);
  float* SF   = allocf((size_t)BB * HH * KK * VV);
  const size_t CH = (size_t)BB * HH * 16 * 64 * 64;
  unsigned short* UFg   = allocu(CH);
  unsigned short* Zg    = allocu(CH);
  unsigned short* Pg    = allocu(CH);
  unsigned short* Qg    = allocu(CH);
  unsigned short* SinTg = allocu(CH);
  float* Ag = allocf((size_t)BB * HH * 16 * 64);

  rmsnorm_kernel<<<M, 256, 0, stream>>>(x, norm_w, XNb);

  convert_wt_kernel<<<dim3(16, 16, 9), 256, 0, stream>>>(
      W_k, W_v, W_lq, W_lk, W_lv, W_gdn_o, W_swa_o, W_ret_o, W_beta, W_g,
      W_gate, WTcat5, WTcat3);

  gemm_proj_kernel<<<dim3(41, 32), 256, 0, stream>>>(XNb, WTcat5, PALL, SPRJ);

  knorm_kernel<<<(M * HH) / 4, 256, 0, stream>>>(PALL);
  gates_kernel<<<M / 4, 256, 0, stream>>>(SPRJ, b_beta, b_g, b_gate, ids, BETA,
                                          Gg, MG);

  scan_phaseA<<<dim3(16, BB * HH), 256, 0, stream>>>(PALL, BETA, Gg, UFg, Zg,
                                                     Pg, Qg, Ag);
  scan_phaseB<<<BB * HH, 256, 0, stream>>>(S0, Pg, Qg, SinTg, SF, ACAT);
  scan_phaseC<<<dim3(16, BB * HH), 256, 0, stream>>>(PALL, UFg, Zg, SinTg, Ag,
                                                     ACAT);

  attn_mfma_kernel<<<dim3(TT / 64, BB * HH), 256, 0, stream>>>(PALL, ACAT);

  retrieve_kernel<<<(M * HH) / 4, 256, 0, stream>>>(PALL, SF, MG, ACAT);

  // out = x + [gdn | local*0.3W | retr*mg] @ WTcat3^T  (K=3072, 512 blocks)
  gemm_out_kernel<<<dim3(16, 32), 256, 0, stream>>>(ACAT, WTcat3, out, x, M, DD,
                                                    3072);
}